// Round 1
// baseline (2536.084 us; speedup 1.0000x reference)
//
#include <hip/hip_runtime.h>
#include <hip/hip_bf16.h>
#include <math.h>

// Problem constants
#define B_  8192
#define IN_ 768
#define D_  128
#define K_  8192
#define L_  3

// ---------------------------------------------------------------------------
// Generic fp32 GEMM: C[M,N] = act(A[M,K] @ W[N,K]^T + bias[N])
// BM=64, BN=64, BK=16, 256 threads, 4x4 micro-tile per thread.
// Thread's 4 output cols are strided by 16 (n = n0 + tx + j*16) to keep LDS
// reads 2-way-conflict-free (free on CDNA4).
// ACT: 0 = none, 1 = silu
// ---------------------------------------------------------------------------
template<int ACT>
__global__ __launch_bounds__(256)
void gemm_kernel(const float* __restrict__ A, const float* __restrict__ W,
                 const float* __restrict__ bias, float* __restrict__ C,
                 int M, int N, int K)
{
    __shared__ float As[64][20];
    __shared__ float Ws[64][20];
    const int tid = threadIdx.x;
    const int tx = tid & 15, ty = tid >> 4;
    const int m0 = blockIdx.y * 64, n0 = blockIdx.x * 64;

    float acc[4][4] = {};

    for (int k0 = 0; k0 < K; k0 += 16) {
        {
            int r  = tid >> 2;
            int c4 = (tid & 3) * 4;
            *(float4*)&As[r][c4] = *(const float4*)&A[(size_t)(m0 + r) * K + k0 + c4];
            *(float4*)&Ws[r][c4] = *(const float4*)&W[(size_t)(n0 + r) * K + k0 + c4];
        }
        __syncthreads();
        #pragma unroll
        for (int kk4 = 0; kk4 < 4; ++kk4) {
            float4 ra[4], wb[4];
            #pragma unroll
            for (int i = 0; i < 4; ++i) ra[i] = *(float4*)&As[ty * 4 + i][kk4 * 4];
            #pragma unroll
            for (int j = 0; j < 4; ++j) wb[j] = *(float4*)&Ws[tx + j * 16][kk4 * 4];
            #pragma unroll
            for (int i = 0; i < 4; ++i)
                #pragma unroll
                for (int j = 0; j < 4; ++j)
                    acc[i][j] += ra[i].x * wb[j].x + ra[i].y * wb[j].y
                               + ra[i].z * wb[j].z + ra[i].w * wb[j].w;
        }
        __syncthreads();
    }

    #pragma unroll
    for (int j = 0; j < 4; ++j) {
        int n = n0 + tx + j * 16;
        float bv = bias[n];
        #pragma unroll
        for (int i = 0; i < 4; ++i) {
            float v = acc[i][j] + bv;
            if (ACT == 1) v = v / (1.0f + expf(-v));
            C[(size_t)(m0 + ty * 4 + i) * N + n] = v;
        }
    }
}

// ---------------------------------------------------------------------------
// Projected codebook: cbp[k,d] = sum_j codebooks[l][k,j] * projs[l][d,j]
// block = 128 threads (one per d), 8 k-rows per block.
// ---------------------------------------------------------------------------
__global__ __launch_bounds__(128)
void proj_kernel(const float* __restrict__ cbl, const float* __restrict__ projl,
                 float* __restrict__ cbp)
{
    __shared__ float cbs[8][128];
    const int tid = threadIdx.x;          // = d
    const int k0 = blockIdx.x * 8;

    #pragma unroll
    for (int i = 0; i < 2; ++i) {
        int idx4 = tid + i * 128;
        int r = idx4 >> 5, c4 = (idx4 & 31) * 4;
        *(float4*)&cbs[r][c4] = *(const float4*)&cbl[(size_t)(k0 + r) * 128 + c4];
    }
    __syncthreads();

    float acc[8] = {};
    for (int j4 = 0; j4 < 32; ++j4) {
        float4 pv = *(const float4*)&projl[(size_t)tid * 128 + j4 * 4];
        #pragma unroll
        for (int r = 0; r < 8; ++r) {
            float4 cv = *(float4*)&cbs[r][j4 * 4];
            acc[r] += pv.x * cv.x + pv.y * cv.y + pv.z * cv.z + pv.w * cv.w;
        }
    }
    #pragma unroll
    for (int r = 0; r < 8; ++r)
        cbp[(size_t)(k0 + r) * 128 + tid] = acc[r];
}

// ---------------------------------------------------------------------------
// cbnorm[k] = ||cbp[k,:]||^2
// ---------------------------------------------------------------------------
__global__ __launch_bounds__(128)
void cbnorm_kernel(const float* __restrict__ cbp, float* __restrict__ cbn)
{
    const int r = blockIdx.x;
    const int tid = threadIdx.x;
    float v = cbp[(size_t)r * 128 + tid];
    float s = v * v;
    for (int off = 32; off > 0; off >>= 1) s += __shfl_down(s, off, 64);
    __shared__ float ws[2];
    if ((tid & 63) == 0) ws[tid >> 6] = s;
    __syncthreads();
    if (tid == 0) cbn[r] = ws[0] + ws[1];
}

// ---------------------------------------------------------------------------
// Distance argmin. score(b,k) = cbnorm[k] - 2 * <res_b, cb_k>  (||res||^2 is
// constant over k, so argmin matches the reference cdist argmin).
// Packed u64 (monotone float key << 32 | k) atomicMin reproduces numpy's
// first-index tie-break.
// Block: 64 rows x 512 k, staged 64-k tiles, dims in 2 chunks of 64.
// ---------------------------------------------------------------------------
__device__ __forceinline__ unsigned int fkey(float s) {
    unsigned int u = __float_as_uint(s);
    return (u & 0x80000000u) ? ~u : (u | 0x80000000u);
}

__global__ __launch_bounds__(256)
void argmin_kernel(const float* __restrict__ res, const float* __restrict__ cbp,
                   const float* __restrict__ cbn,
                   unsigned long long* __restrict__ minkey)
{
    __shared__ float res_s[64][132];
    __shared__ float cb_s[64][68];
    const int tid = threadIdx.x;
    const int tx = tid & 15, ty = tid >> 4;
    const int m0 = blockIdx.y * 64;
    const int kbase = blockIdx.x * 512;

    #pragma unroll
    for (int i = 0; i < 8; ++i) {
        int idx4 = tid + i * 256;
        int r = idx4 >> 5, c4 = (idx4 & 31) * 4;
        *(float4*)&res_s[r][c4] = *(const float4*)&res[(size_t)(m0 + r) * 128 + c4];
    }

    unsigned long long best[4];
    #pragma unroll
    for (int i = 0; i < 4; ++i) best[i] = ~0ULL;

    for (int kt = 0; kt < 8; ++kt) {
        const int k0 = kbase + kt * 64;
        float acc[4][4] = {};
        #pragma unroll
        for (int ch = 0; ch < 2; ++ch) {
            __syncthreads();
            #pragma unroll
            for (int i = 0; i < 4; ++i) {
                int idx4 = tid + i * 256;
                int r = idx4 >> 4, c4 = (idx4 & 15) * 4;
                *(float4*)&cb_s[r][c4] =
                    *(const float4*)&cbp[(size_t)(k0 + r) * 128 + ch * 64 + c4];
            }
            __syncthreads();
            #pragma unroll
            for (int c4 = 0; c4 < 16; ++c4) {
                float4 ra[4], kb[4];
                #pragma unroll
                for (int i = 0; i < 4; ++i)
                    ra[i] = *(float4*)&res_s[ty * 4 + i][ch * 64 + c4 * 4];
                #pragma unroll
                for (int j = 0; j < 4; ++j)
                    kb[j] = *(float4*)&cb_s[tx + j * 16][c4 * 4];
                #pragma unroll
                for (int i = 0; i < 4; ++i)
                    #pragma unroll
                    for (int j = 0; j < 4; ++j)
                        acc[i][j] += ra[i].x * kb[j].x + ra[i].y * kb[j].y
                                   + ra[i].z * kb[j].z + ra[i].w * kb[j].w;
            }
        }
        #pragma unroll
        for (int j = 0; j < 4; ++j) {
            int k = k0 + tx + j * 16;
            float cn = cbn[k];
            #pragma unroll
            for (int i = 0; i < 4; ++i) {
                float s = cn - 2.0f * acc[i][j];
                unsigned long long key =
                    ((unsigned long long)fkey(s) << 32) | (unsigned int)k;
                if (key < best[i]) best[i] = key;
            }
        }
    }

    // reduce over the 16 tx lanes (consecutive lanes within a wave)
    #pragma unroll
    for (int i = 0; i < 4; ++i) {
        unsigned long long b = best[i];
        #pragma unroll
        for (int off = 8; off > 0; off >>= 1) {
            unsigned int lo = (unsigned int)b, hi = (unsigned int)(b >> 32);
            lo = __shfl_down(lo, off, 16);
            hi = __shfl_down(hi, off, 16);
            unsigned long long o = ((unsigned long long)hi << 32) | lo;
            if (o < b) b = o;
        }
        if (tx == 0) atomicMin(&minkey[m0 + ty * 4 + i], b);
    }
}

// ---------------------------------------------------------------------------
// Per-layer epilogue: gather emb, qloss += 1.25*||res-emb||^2, embs_norm out,
// z += emb, res -= emb, ids out (+ packed uniqueness keys at layer 2).
// One block (128 threads) per row.
// ---------------------------------------------------------------------------
__global__ __launch_bounds__(128)
void finalize_kernel(float* __restrict__ res, const float* __restrict__ cbp,
                     const unsigned long long* __restrict__ minkey,
                     float* __restrict__ qloss, float* __restrict__ z,
                     int* __restrict__ ids, float* __restrict__ embs_norm_out,
                     unsigned long long* __restrict__ keys, int layer)
{
    const int b = blockIdx.x;
    const int tid = threadIdx.x;
    const int id = (int)(minkey[b] & 0xFFFFFFFFull);
    float e = cbp[(size_t)id * 128 + tid];
    float r = res[(size_t)b * 128 + tid];
    float d = r - e;
    float v1 = d * d, v2 = e * e;
    for (int off = 32; off > 0; off >>= 1) {
        v1 += __shfl_down(v1, off, 64);
        v2 += __shfl_down(v2, off, 64);
    }
    __shared__ float ws[4];
    if ((tid & 63) == 0) { ws[(tid >> 6) * 2] = v1; ws[(tid >> 6) * 2 + 1] = v2; }
    __syncthreads();
    if (tid == 0) {
        float d2 = ws[0] + ws[2];
        float n2 = ws[1] + ws[3];
        qloss[b] += 1.25f * d2;                 // emb_loss + 0.25*query_loss
        embs_norm_out[b * 3 + layer] = sqrtf(n2);
        ids[b * 3 + layer] = id;
        if (layer == 2) {
            keys[b] = (unsigned long long)ids[b * 3 + 0]
                    | ((unsigned long long)ids[b * 3 + 1] << 13)
                    | ((unsigned long long)id << 26);
        }
    }
    z[(size_t)b * 128 + tid] += e;
    res[(size_t)b * 128 + tid] = r - e;
}

// ---------------------------------------------------------------------------
// Fused decoder layer 3 + sigmoid + L2-normalize + recon partial sums.
// Block: 8 rows x 768 cols, 256 threads, 3 cols/thread (n = tid + c*256).
// ---------------------------------------------------------------------------
__global__ __launch_bounds__(256)
void final_kernel(const float* __restrict__ g2, const float* __restrict__ w3,
                  const float* __restrict__ b3, const float* __restrict__ x,
                  float* __restrict__ recon_partial)
{
    __shared__ float gs[8][512];
    __shared__ float wred[4];
    __shared__ float nrm[8];
    const int tid = threadIdx.x;
    const int m0 = blockIdx.x * 8;

    #pragma unroll
    for (int i = 0; i < 4; ++i) {
        int idx4 = tid + i * 256;
        int r = idx4 >> 7, c4 = (idx4 & 127) * 4;
        *(float4*)&gs[r][c4] = *(const float4*)&g2[(size_t)(m0 + r) * 512 + c4];
    }
    __syncthreads();

    float acc[8][3] = {};
    for (int j4 = 0; j4 < 128; ++j4) {
        float4 w0 = *(const float4*)&w3[(size_t)(tid)       * 512 + j4 * 4];
        float4 w1 = *(const float4*)&w3[(size_t)(tid + 256) * 512 + j4 * 4];
        float4 w2 = *(const float4*)&w3[(size_t)(tid + 512) * 512 + j4 * 4];
        #pragma unroll
        for (int r = 0; r < 8; ++r) {
            float4 g = *(float4*)&gs[r][j4 * 4];
            acc[r][0] += g.x * w0.x + g.y * w0.y + g.z * w0.z + g.w * w0.w;
            acc[r][1] += g.x * w1.x + g.y * w1.y + g.z * w1.z + g.w * w1.w;
            acc[r][2] += g.x * w2.x + g.y * w2.y + g.z * w2.z + g.w * w2.w;
        }
    }

    const float bv0 = b3[tid], bv1 = b3[tid + 256], bv2 = b3[tid + 512];
    #pragma unroll
    for (int r = 0; r < 8; ++r) {
        float s0 = 1.0f / (1.0f + expf(-(acc[r][0] + bv0)));
        float s1 = 1.0f / (1.0f + expf(-(acc[r][1] + bv1)));
        float s2 = 1.0f / (1.0f + expf(-(acc[r][2] + bv2)));
        acc[r][0] = s0; acc[r][1] = s1; acc[r][2] = s2;
        float p = s0 * s0 + s1 * s1 + s2 * s2;
        for (int off = 32; off > 0; off >>= 1) p += __shfl_down(p, off, 64);
        if ((tid & 63) == 0) wred[tid >> 6] = p;
        __syncthreads();
        if (tid == 0) nrm[r] = sqrtf(wred[0] + wred[1] + wred[2] + wred[3]);
        __syncthreads();
    }

    float ra = 0.0f;
    #pragma unroll
    for (int r = 0; r < 8; ++r) {
        float denom = fmaxf(nrm[r], 1e-12f);
        #pragma unroll
        for (int c = 0; c < 3; ++c) {
            float xh = acc[r][c] / denom;
            float dx = xh - x[(size_t)(m0 + r) * 768 + tid + c * 256];
            ra += dx * dx;
        }
    }
    for (int off = 32; off > 0; off >>= 1) ra += __shfl_down(ra, off, 64);
    if ((tid & 63) == 0) wred[tid >> 6] = ra;
    __syncthreads();
    if (tid == 0)
        recon_partial[blockIdx.x] = wred[0] + wred[1] + wred[2] + wred[3];
}

// ---------------------------------------------------------------------------
// Unique-triple count (p_unique numerator). ids < 8192 = 2^13 -> 39-bit key.
// ---------------------------------------------------------------------------
__global__ __launch_bounds__(256)
void uniq_kernel(const unsigned long long* __restrict__ keys, int* __restrict__ count)
{
    __shared__ unsigned long long ks[8192];
    const int tid = threadIdx.x;
    for (int i = tid; i < 8192; i += 256) ks[i] = keys[i];
    __syncthreads();
    const int i = blockIdx.x * 256 + tid;
    const unsigned long long k = ks[i];
    int dup = 0;
    for (int j = i + 1; j < 8192; ++j) dup |= (ks[j] == k);
    if (!dup) atomicAdd(count, 1);
}

// ---------------------------------------------------------------------------
// Final scalars: loss, recon, qloss.mean, p_unique (deterministic reduce).
// ---------------------------------------------------------------------------
__global__ __launch_bounds__(256)
void scalars_kernel(const float* __restrict__ qloss,
                    const float* __restrict__ recon_partial,
                    const int* __restrict__ count, float* __restrict__ out)
{
    const int tid = threadIdx.x;
    float qs = 0.0f, rs = 0.0f;
    for (int i = tid; i < 8192; i += 256) qs += qloss[i];
    for (int i = tid; i < 1024; i += 256) rs += recon_partial[i];
    for (int off = 32; off > 0; off >>= 1) {
        qs += __shfl_down(qs, off, 64);
        rs += __shfl_down(rs, off, 64);
    }
    __shared__ float w[8];
    if ((tid & 63) == 0) { w[(tid >> 6) * 2] = qs; w[(tid >> 6) * 2 + 1] = rs; }
    __syncthreads();
    if (tid == 0) {
        float qsum = w[0] + w[2] + w[4] + w[6];
        float rsum = w[1] + w[3] + w[5] + w[7];
        float qmean = qsum / 8192.0f;
        out[0] = rsum + qmean;        // loss = (recon + qloss).mean()
        out[1] = rsum;                // recon
        out[2] = qmean;               // qloss.mean()
        out[24579] = (float)(*count) / 8192.0f;   // p_unique
    }
}

// ---------------------------------------------------------------------------
extern "C" void kernel_launch(void* const* d_in, const int* in_sizes, int n_in,
                              void* d_out, int out_size, void* d_ws, size_t ws_size,
                              hipStream_t stream)
{
    const float* x      = (const float*)d_in[0];
    const float* enc_w1 = (const float*)d_in[1];
    const float* enc_b1 = (const float*)d_in[2];
    const float* enc_w2 = (const float*)d_in[3];
    const float* enc_b2 = (const float*)d_in[4];
    const float* enc_w3 = (const float*)d_in[5];
    const float* enc_b3 = (const float*)d_in[6];
    const float* dec_w1 = (const float*)d_in[7];
    const float* dec_b1 = (const float*)d_in[8];
    const float* dec_w2 = (const float*)d_in[9];
    const float* dec_b2 = (const float*)d_in[10];
    const float* dec_w3 = (const float*)d_in[11];
    const float* dec_b3 = (const float*)d_in[12];
    const float* codebooks = (const float*)d_in[13];
    const float* projs     = (const float*)d_in[14];
    float* out = (float*)d_out;

    // workspace layout (fp32 elements unless noted); total ~38.1 MB
    float* h1    = (float*)d_ws;               // 8192*512   (also g2)
    float* h2    = h1  + (size_t)8192 * 512;   // 8192*256   (also g1)
    float* res   = h2  + (size_t)8192 * 256;   // 8192*128
    float* cbp   = res + (size_t)8192 * 128;   // 8192*128
    float* z     = cbp + (size_t)8192 * 128;   // 8192*128
    float* cbn   = z   + (size_t)8192 * 128;   // 8192
    float* qloss = cbn + 8192;                 // 8192
    float* reconp = qloss + 8192;              // 1024
    unsigned long long* minkey = (unsigned long long*)(reconp + 1024); // 8192 u64
    unsigned long long* keys   = minkey + 8192;                        // 8192 u64
    int* ids   = (int*)(keys + 8192);          // 8192*3
    int* count = ids + 8192 * 3;               // 1

    float* g1 = h2;
    float* g2 = h1;

    hipMemsetAsync(z, 0, (size_t)8192 * 128 * sizeof(float), stream);
    hipMemsetAsync(qloss, 0, 8192 * sizeof(float), stream);
    hipMemsetAsync(count, 0, sizeof(int), stream);

    // encoder
    gemm_kernel<1><<<dim3(512 / 64, 8192 / 64), 256, 0, stream>>>(x,  enc_w1, enc_b1, h1, 8192, 512, 768);
    gemm_kernel<1><<<dim3(256 / 64, 8192 / 64), 256, 0, stream>>>(h1, enc_w2, enc_b2, h2, 8192, 256, 512);
    gemm_kernel<0><<<dim3(128 / 64, 8192 / 64), 256, 0, stream>>>(h2, enc_w3, enc_b3, res, 8192, 128, 256);

    // residual quantization layers
    for (int l = 0; l < 3; ++l) {
        proj_kernel<<<1024, 128, 0, stream>>>(codebooks + (size_t)l * 8192 * 128,
                                              projs + (size_t)l * 128 * 128, cbp);
        cbnorm_kernel<<<8192, 128, 0, stream>>>(cbp, cbn);
        hipMemsetAsync(minkey, 0xFF, 8192 * sizeof(unsigned long long), stream);
        argmin_kernel<<<dim3(16, 128), 256, 0, stream>>>(res, cbp, cbn, minkey);
        finalize_kernel<<<8192, 128, 0, stream>>>(res, cbp, minkey, qloss, z,
                                                  ids, out + 3, keys, l);
    }

    // decoder
    gemm_kernel<1><<<dim3(256 / 64, 8192 / 64), 256, 0, stream>>>(z,  dec_w1, dec_b1, g1, 8192, 256, 128);
    gemm_kernel<1><<<dim3(512 / 64, 8192 / 64), 256, 0, stream>>>(g1, dec_w2, dec_b2, g2, 8192, 512, 256);
    final_kernel<<<1024, 256, 0, stream>>>(g2, dec_w3, dec_b3, x, reconp);

    // diagnostics
    uniq_kernel<<<32, 256, 0, stream>>>(keys, count);
    scalars_kernel<<<1, 256, 0, stream>>>(qloss, reconp, count, out);
}

// Round 2
// 1486.130 us; speedup vs baseline: 1.7065x; 1.7065x over previous
//
#include <hip/hip_runtime.h>
#include <hip/hip_bf16.h>
#include <math.h>

// Problem constants
#define B_  8192
#define IN_ 768
#define D_  128
#define K_  8192
#define L_  3

typedef __attribute__((ext_vector_type(8))) short bf16x8;
typedef __attribute__((ext_vector_type(4))) float f32x4;

// Split f into hi (bf16 RNE) + lo (bf16 RNE of remainder). hi+lo carries
// ~16 mantissa bits -> 2^-17 relative representation error.
__device__ __forceinline__ void split2(float f, unsigned short& h, unsigned short& l)
{
    unsigned u = __float_as_uint(f);
    unsigned hb = (u + 0x7FFFu + ((u >> 16) & 1u)) & 0xFFFF0000u;
    h = (unsigned short)(hb >> 16);
    float r = f - __uint_as_float(hb);
    unsigned v = __float_as_uint(r);
    l = (unsigned short)((v + 0x7FFFu + ((v >> 16) & 1u)) >> 16);
}

// ---------------------------------------------------------------------------
// Generic fp32 GEMM: C[M,N] = act(A[M,K] @ W[N,K]^T + bias[N])
// BM=64, BN=64, BK=16, 256 threads, 4x4 micro-tile per thread.
// ACT: 0 = none, 1 = silu
// ---------------------------------------------------------------------------
template<int ACT>
__global__ __launch_bounds__(256)
void gemm_kernel(const float* __restrict__ A, const float* __restrict__ W,
                 const float* __restrict__ bias, float* __restrict__ C,
                 int M, int N, int K)
{
    __shared__ float As[64][20];
    __shared__ float Ws[64][20];
    const int tid = threadIdx.x;
    const int tx = tid & 15, ty = tid >> 4;
    const int m0 = blockIdx.y * 64, n0 = blockIdx.x * 64;

    float acc[4][4] = {};

    for (int k0 = 0; k0 < K; k0 += 16) {
        {
            int r  = tid >> 2;
            int c4 = (tid & 3) * 4;
            *(float4*)&As[r][c4] = *(const float4*)&A[(size_t)(m0 + r) * K + k0 + c4];
            *(float4*)&Ws[r][c4] = *(const float4*)&W[(size_t)(n0 + r) * K + k0 + c4];
        }
        __syncthreads();
        #pragma unroll
        for (int kk4 = 0; kk4 < 4; ++kk4) {
            float4 ra[4], wb[4];
            #pragma unroll
            for (int i = 0; i < 4; ++i) ra[i] = *(float4*)&As[ty * 4 + i][kk4 * 4];
            #pragma unroll
            for (int j = 0; j < 4; ++j) wb[j] = *(float4*)&Ws[tx + j * 16][kk4 * 4];
            #pragma unroll
            for (int i = 0; i < 4; ++i)
                #pragma unroll
                for (int j = 0; j < 4; ++j)
                    acc[i][j] += ra[i].x * wb[j].x + ra[i].y * wb[j].y
                               + ra[i].z * wb[j].z + ra[i].w * wb[j].w;
        }
        __syncthreads();
    }

    #pragma unroll
    for (int j = 0; j < 4; ++j) {
        int n = n0 + tx + j * 16;
        float bv = bias[n];
        #pragma unroll
        for (int i = 0; i < 4; ++i) {
            float v = acc[i][j] + bv;
            if (ACT == 1) v = v / (1.0f + expf(-v));
            C[(size_t)(m0 + ty * 4 + i) * N + n] = v;
        }
    }
}

// ---------------------------------------------------------------------------
// Projected codebook: cbp[k,d] = sum_j codebooks[l][k,j] * projs[l][d,j]
// Also emits bf16 hi/lo split and per-row squared norms (cbn).
// block = 128 threads (one per d), 8 k-rows per block.
// ---------------------------------------------------------------------------
__global__ __launch_bounds__(128)
void proj_split_kernel(const float* __restrict__ cbl, const float* __restrict__ projl,
                       float* __restrict__ cbp, unsigned short* __restrict__ cbp_hi,
                       unsigned short* __restrict__ cbp_lo, float* __restrict__ cbn)
{
    __shared__ float cbs[8][128];
    __shared__ float wsum[8][2];
    const int tid = threadIdx.x;          // = d
    const int k0 = blockIdx.x * 8;

    #pragma unroll
    for (int i = 0; i < 2; ++i) {
        int idx4 = tid + i * 128;
        int r = idx4 >> 5, c4 = (idx4 & 31) * 4;
        *(float4*)&cbs[r][c4] = *(const float4*)&cbl[(size_t)(k0 + r) * 128 + c4];
    }
    __syncthreads();

    float acc[8] = {};
    for (int j4 = 0; j4 < 32; ++j4) {
        float4 pv = *(const float4*)&projl[(size_t)tid * 128 + j4 * 4];
        #pragma unroll
        for (int r = 0; r < 8; ++r) {
            float4 cv = *(float4*)&cbs[r][j4 * 4];
            acc[r] += pv.x * cv.x + pv.y * cv.y + pv.z * cv.z + pv.w * cv.w;
        }
    }
    #pragma unroll
    for (int r = 0; r < 8; ++r) {
        size_t idx = (size_t)(k0 + r) * 128 + tid;
        cbp[idx] = acc[r];
        unsigned short h, l;
        split2(acc[r], h, l);
        cbp_hi[idx] = h;
        cbp_lo[idx] = l;
        float v = acc[r] * acc[r];
        #pragma unroll
        for (int off = 32; off > 0; off >>= 1) v += __shfl_down(v, off, 64);
        if ((tid & 63) == 0) wsum[r][tid >> 6] = v;
    }
    __syncthreads();
    if (tid < 8) cbn[k0 + tid] = wsum[tid][0] + wsum[tid][1];
}

// ---------------------------------------------------------------------------
// res -> bf16 hi/lo split (used once after the encoder).
// ---------------------------------------------------------------------------
__global__ __launch_bounds__(256)
void split_kernel(const float* __restrict__ src, unsigned short* __restrict__ hi,
                  unsigned short* __restrict__ lo, int n4)
{
    int i = blockIdx.x * 256 + threadIdx.x;
    if (i >= n4) return;
    float4 v = ((const float4*)src)[i];
    ushort4 h, l;
    split2(v.x, h.x, l.x); split2(v.y, h.y, l.y);
    split2(v.z, h.z, l.z); split2(v.w, h.w, l.w);
    ((ushort4*)hi)[i] = h;
    ((ushort4*)lo)[i] = l;
}

// ---------------------------------------------------------------------------
// MFMA distance argmin. score(b,k) = cbn[k] - 2 * <res_b, cb_k>.
// 3-pass split precision: dot = hi*hi + lo*hi + hi*lo (error ~1e-6).
// Block: 256 thr = 4 waves; BM=128 rows (wave = 2 m-tiles of 16),
// col strip = 256 (4 iters x 4 n-tiles of 16). Fragments from global (L2-hot).
// Packed u64 (monotone float key <<32 | k) atomicMin = numpy tie-break.
// ---------------------------------------------------------------------------
__device__ __forceinline__ unsigned int fkey(float s) {
    unsigned int u = __float_as_uint(s);
    return (u & 0x80000000u) ? ~u : (u | 0x80000000u);
}

__global__ __launch_bounds__(256)
void argmin_mfma_kernel(const unsigned short* __restrict__ res_hi,
                        const unsigned short* __restrict__ res_lo,
                        const unsigned short* __restrict__ cbp_hi,
                        const unsigned short* __restrict__ cbp_lo,
                        const float* __restrict__ cbn,
                        unsigned long long* __restrict__ minkey)
{
    const int tid  = threadIdx.x;
    const int lane = tid & 63;
    const int w    = tid >> 6;
    const int ln   = lane & 15;
    const int grp  = lane >> 4;
    const int m0   = blockIdx.y * 128 + w * 32;
    const int c0b  = blockIdx.x * 256;

    // A fragments (res rows), held for the whole kernel.
    bf16x8 a_hi[2][4], a_lo[2][4];
    #pragma unroll
    for (int mt = 0; mt < 2; ++mt) {
        const size_t base = (size_t)(m0 + mt * 16 + ln) * 128 + grp * 8;
        #pragma unroll
        for (int s = 0; s < 4; ++s) {
            a_hi[mt][s] = *(const bf16x8*)&res_hi[base + s * 32];
            a_lo[mt][s] = *(const bf16x8*)&res_lo[base + s * 32];
        }
    }

    unsigned long long best[2][4];
    #pragma unroll
    for (int mt = 0; mt < 2; ++mt)
        #pragma unroll
        for (int r = 0; r < 4; ++r) best[mt][r] = ~0ULL;

    for (int it = 0; it < 4; ++it) {
        const int c0 = c0b + it * 64;
        f32x4 acc[2][4] = {};
        #pragma unroll
        for (int s = 0; s < 4; ++s) {
            #pragma unroll
            for (int t = 0; t < 4; ++t) {
                const size_t bb = (size_t)(c0 + t * 16 + ln) * 128 + grp * 8 + s * 32;
                bf16x8 bh = *(const bf16x8*)&cbp_hi[bb];
                bf16x8 bl = *(const bf16x8*)&cbp_lo[bb];
                #pragma unroll
                for (int mt = 0; mt < 2; ++mt) {
                    acc[mt][t] = __builtin_amdgcn_mfma_f32_16x16x32_bf16(a_hi[mt][s], bh, acc[mt][t], 0, 0, 0);
                    acc[mt][t] = __builtin_amdgcn_mfma_f32_16x16x32_bf16(a_lo[mt][s], bh, acc[mt][t], 0, 0, 0);
                    acc[mt][t] = __builtin_amdgcn_mfma_f32_16x16x32_bf16(a_hi[mt][s], bl, acc[mt][t], 0, 0, 0);
                }
            }
        }
        #pragma unroll
        for (int t = 0; t < 4; ++t) {
            const int col = c0 + t * 16 + ln;
            const float cn = cbn[col];
            #pragma unroll
            for (int mt = 0; mt < 2; ++mt)
                #pragma unroll
                for (int r = 0; r < 4; ++r) {
                    float sc = cn - 2.0f * acc[mt][t][r];
                    unsigned long long key =
                        ((unsigned long long)fkey(sc) << 32) | (unsigned int)col;
                    if (key < best[mt][r]) best[mt][r] = key;
                }
        }
    }

    // Reduce across the 16 lanes of each group (they share rows), then atomic.
    #pragma unroll
    for (int mt = 0; mt < 2; ++mt)
        #pragma unroll
        for (int r = 0; r < 4; ++r) {
            unsigned long long b = best[mt][r];
            #pragma unroll
            for (int off = 1; off < 16; off <<= 1) {
                unsigned lo32 = (unsigned)b, hi32 = (unsigned)(b >> 32);
                lo32 = __shfl_xor(lo32, off);
                hi32 = __shfl_xor(hi32, off);
                unsigned long long o = ((unsigned long long)hi32 << 32) | lo32;
                if (o < b) b = o;
            }
            if (ln == 0) atomicMin(&minkey[m0 + mt * 16 + grp * 4 + r], b);
        }
}

// ---------------------------------------------------------------------------
// Per-layer epilogue: gather emb, qloss += 1.25*||res-emb||^2, embs_norm out,
// z += emb, res -= emb (fp32 + bf16 hi/lo), ids out (+ packed keys at layer 2).
// One block (128 threads) per row.
// ---------------------------------------------------------------------------
__global__ __launch_bounds__(128)
void finalize_kernel(float* __restrict__ res, const float* __restrict__ cbp,
                     const unsigned long long* __restrict__ minkey,
                     float* __restrict__ qloss, float* __restrict__ z,
                     int* __restrict__ ids, float* __restrict__ embs_norm_out,
                     unsigned long long* __restrict__ keys,
                     unsigned short* __restrict__ res_hi,
                     unsigned short* __restrict__ res_lo, int layer)
{
    const int b = blockIdx.x;
    const int tid = threadIdx.x;
    const int id = (int)(minkey[b] & 0xFFFFFFFFull);
    float e = cbp[(size_t)id * 128 + tid];
    float r = res[(size_t)b * 128 + tid];
    float d = r - e;
    float v1 = d * d, v2 = e * e;
    for (int off = 32; off > 0; off >>= 1) {
        v1 += __shfl_down(v1, off, 64);
        v2 += __shfl_down(v2, off, 64);
    }
    __shared__ float ws[4];
    if ((tid & 63) == 0) { ws[(tid >> 6) * 2] = v1; ws[(tid >> 6) * 2 + 1] = v2; }
    __syncthreads();
    if (tid == 0) {
        float d2 = ws[0] + ws[2];
        float n2 = ws[1] + ws[3];
        qloss[b] += 1.25f * d2;                 // emb_loss + 0.25*query_loss
        embs_norm_out[b * 3 + layer] = sqrtf(n2);
        ids[b * 3 + layer] = id;
        if (layer == 2) {
            keys[b] = (unsigned long long)ids[b * 3 + 0]
                    | ((unsigned long long)ids[b * 3 + 1] << 13)
                    | ((unsigned long long)id << 26);
        }
    }
    z[(size_t)b * 128 + tid] += e;
    float nr = r - e;
    res[(size_t)b * 128 + tid] = nr;
    unsigned short h, l;
    split2(nr, h, l);
    res_hi[(size_t)b * 128 + tid] = h;
    res_lo[(size_t)b * 128 + tid] = l;
}

// ---------------------------------------------------------------------------
// Fused decoder layer 3 + sigmoid + L2-normalize + recon partial sums.
// Block: 8 rows x 768 cols, 256 threads, 3 cols/thread (n = tid + c*256).
// ---------------------------------------------------------------------------
__global__ __launch_bounds__(256)
void final_kernel(const float* __restrict__ g2, const float* __restrict__ w3,
                  const float* __restrict__ b3, const float* __restrict__ x,
                  float* __restrict__ recon_partial)
{
    __shared__ float gs[8][512];
    __shared__ float wred[4];
    __shared__ float nrm[8];
    const int tid = threadIdx.x;
    const int m0 = blockIdx.x * 8;

    #pragma unroll
    for (int i = 0; i < 4; ++i) {
        int idx4 = tid + i * 256;
        int r = idx4 >> 7, c4 = (idx4 & 127) * 4;
        *(float4*)&gs[r][c4] = *(const float4*)&g2[(size_t)(m0 + r) * 512 + c4];
    }
    __syncthreads();

    float acc[8][3] = {};
    for (int j4 = 0; j4 < 128; ++j4) {
        float4 w0 = *(const float4*)&w3[(size_t)(tid)       * 512 + j4 * 4];
        float4 w1 = *(const float4*)&w3[(size_t)(tid + 256) * 512 + j4 * 4];
        float4 w2 = *(const float4*)&w3[(size_t)(tid + 512) * 512 + j4 * 4];
        #pragma unroll
        for (int r = 0; r < 8; ++r) {
            float4 g = *(float4*)&gs[r][j4 * 4];
            acc[r][0] += g.x * w0.x + g.y * w0.y + g.z * w0.z + g.w * w0.w;
            acc[r][1] += g.x * w1.x + g.y * w1.y + g.z * w1.z + g.w * w1.w;
            acc[r][2] += g.x * w2.x + g.y * w2.y + g.z * w2.z + g.w * w2.w;
        }
    }

    const float bv0 = b3[tid], bv1 = b3[tid + 256], bv2 = b3[tid + 512];
    #pragma unroll
    for (int r = 0; r < 8; ++r) {
        float s0 = 1.0f / (1.0f + expf(-(acc[r][0] + bv0)));
        float s1 = 1.0f / (1.0f + expf(-(acc[r][1] + bv1)));
        float s2 = 1.0f / (1.0f + expf(-(acc[r][2] + bv2)));
        acc[r][0] = s0; acc[r][1] = s1; acc[r][2] = s2;
        float p = s0 * s0 + s1 * s1 + s2 * s2;
        for (int off = 32; off > 0; off >>= 1) p += __shfl_down(p, off, 64);
        if ((tid & 63) == 0) wred[tid >> 6] = p;
        __syncthreads();
        if (tid == 0) nrm[r] = sqrtf(wred[0] + wred[1] + wred[2] + wred[3]);
        __syncthreads();
    }

    float ra = 0.0f;
    #pragma unroll
    for (int r = 0; r < 8; ++r) {
        float denom = fmaxf(nrm[r], 1e-12f);
        #pragma unroll
        for (int c = 0; c < 3; ++c) {
            float xh = acc[r][c] / denom;
            float dx = xh - x[(size_t)(m0 + r) * 768 + tid + c * 256];
            ra += dx * dx;
        }
    }
    for (int off = 32; off > 0; off >>= 1) ra += __shfl_down(ra, off, 64);
    if ((tid & 63) == 0) wred[tid >> 6] = ra;
    __syncthreads();
    if (tid == 0)
        recon_partial[blockIdx.x] = wred[0] + wred[1] + wred[2] + wred[3];
}

// ---------------------------------------------------------------------------
// Unique-triple count (p_unique numerator). ids < 8192 = 2^13 -> 39-bit key.
// ---------------------------------------------------------------------------
__global__ __launch_bounds__(256)
void uniq_kernel(const unsigned long long* __restrict__ keys, int* __restrict__ count)
{
    __shared__ unsigned long long ks[8192];
    const int tid = threadIdx.x;
    for (int i = tid; i < 8192; i += 256) ks[i] = keys[i];
    __syncthreads();
    const int i = blockIdx.x * 256 + tid;
    const unsigned long long k = ks[i];
    int dup = 0;
    for (int j = i + 1; j < 8192; ++j) dup |= (ks[j] == k);
    if (!dup) atomicAdd(count, 1);
}

// ---------------------------------------------------------------------------
// Final scalars: loss, recon, qloss.mean, p_unique (deterministic reduce).
// ---------------------------------------------------------------------------
__global__ __launch_bounds__(256)
void scalars_kernel(const float* __restrict__ qloss,
                    const float* __restrict__ recon_partial,
                    const int* __restrict__ count, float* __restrict__ out)
{
    const int tid = threadIdx.x;
    float qs = 0.0f, rs = 0.0f;
    for (int i = tid; i < 8192; i += 256) qs += qloss[i];
    for (int i = tid; i < 1024; i += 256) rs += recon_partial[i];
    for (int off = 32; off > 0; off >>= 1) {
        qs += __shfl_down(qs, off, 64);
        rs += __shfl_down(rs, off, 64);
    }
    __shared__ float w[8];
    if ((tid & 63) == 0) { w[(tid >> 6) * 2] = qs; w[(tid >> 6) * 2 + 1] = rs; }
    __syncthreads();
    if (tid == 0) {
        float qsum = w[0] + w[2] + w[4] + w[6];
        float rsum = w[1] + w[3] + w[5] + w[7];
        float qmean = qsum / 8192.0f;
        out[0] = rsum + qmean;        // loss = (recon + qloss).mean()
        out[1] = rsum;                // recon
        out[2] = qmean;               // qloss.mean()
        out[24579] = (float)(*count) / 8192.0f;   // p_unique
    }
}

// ---------------------------------------------------------------------------
extern "C" void kernel_launch(void* const* d_in, const int* in_sizes, int n_in,
                              void* d_out, int out_size, void* d_ws, size_t ws_size,
                              hipStream_t stream)
{
    const float* x      = (const float*)d_in[0];
    const float* enc_w1 = (const float*)d_in[1];
    const float* enc_b1 = (const float*)d_in[2];
    const float* enc_w2 = (const float*)d_in[3];
    const float* enc_b2 = (const float*)d_in[4];
    const float* enc_w3 = (const float*)d_in[5];
    const float* enc_b3 = (const float*)d_in[6];
    const float* dec_w1 = (const float*)d_in[7];
    const float* dec_b1 = (const float*)d_in[8];
    const float* dec_w2 = (const float*)d_in[9];
    const float* dec_b2 = (const float*)d_in[10];
    const float* dec_w3 = (const float*)d_in[11];
    const float* dec_b3 = (const float*)d_in[12];
    const float* codebooks = (const float*)d_in[13];
    const float* projs     = (const float*)d_in[14];
    float* out = (float*)d_out;

    // workspace layout (same footprint as round 1, ~38 MB):
    float* h1    = (float*)d_ws;               // 8192*512 f32  [enc h1 / dec g2]
    float* h2    = h1  + (size_t)8192 * 512;   // 8192*256 f32  [enc h2 / dec g1]
    float* res   = h2  + (size_t)8192 * 256;   // 8192*128 f32
    float* cbp   = res + (size_t)8192 * 128;   // 8192*128 f32
    float* z     = cbp + (size_t)8192 * 128;   // 8192*128 f32
    float* cbn   = z   + (size_t)8192 * 128;   // 8192
    float* qloss = cbn + 8192;                 // 8192
    float* reconp = qloss + 8192;              // 1024
    unsigned long long* minkey = (unsigned long long*)(reconp + 1024); // 8192 u64
    unsigned long long* keys   = minkey + 8192;                        // 8192 u64
    int* ids   = (int*)(keys + 8192);          // 8192*3
    int* count = ids + 8192 * 3;               // 1

    // bf16 hi/lo splits alias h2 (8 MB region, dead during quantization loop)
    unsigned short* res_hi = (unsigned short*)h2;            // 8192*128 bf16
    unsigned short* res_lo = res_hi + (size_t)8192 * 128;
    unsigned short* cbp_hi = res_lo + (size_t)8192 * 128;
    unsigned short* cbp_lo = cbp_hi + (size_t)8192 * 128;

    float* g1 = h2;
    float* g2 = h1;

    hipMemsetAsync(z, 0, (size_t)8192 * 128 * sizeof(float), stream);
    hipMemsetAsync(qloss, 0, 8192 * sizeof(float), stream);
    hipMemsetAsync(count, 0, sizeof(int), stream);

    // encoder
    gemm_kernel<1><<<dim3(512 / 64, 8192 / 64), 256, 0, stream>>>(x,  enc_w1, enc_b1, h1, 8192, 512, 768);
    gemm_kernel<1><<<dim3(256 / 64, 8192 / 64), 256, 0, stream>>>(h1, enc_w2, enc_b2, h2, 8192, 256, 512);
    gemm_kernel<0><<<dim3(128 / 64, 8192 / 64), 256, 0, stream>>>(h2, enc_w3, enc_b3, res, 8192, 128, 256);
    split_kernel<<<1024, 256, 0, stream>>>(res, res_hi, res_lo, 8192 * 128 / 4);

    // residual quantization layers
    for (int l = 0; l < 3; ++l) {
        proj_split_kernel<<<1024, 128, 0, stream>>>(codebooks + (size_t)l * 8192 * 128,
                                                    projs + (size_t)l * 128 * 128,
                                                    cbp, cbp_hi, cbp_lo, cbn);
        hipMemsetAsync(minkey, 0xFF, 8192 * sizeof(unsigned long long), stream);
        argmin_mfma_kernel<<<dim3(32, 64), 256, 0, stream>>>(res_hi, res_lo,
                                                             cbp_hi, cbp_lo, cbn, minkey);
        finalize_kernel<<<8192, 128, 0, stream>>>(res, cbp, minkey, qloss, z,
                                                  ids, out + 3, keys,
                                                  res_hi, res_lo, l);
    }

    // decoder
    gemm_kernel<1><<<dim3(256 / 64, 8192 / 64), 256, 0, stream>>>(z,  dec_w1, dec_b1, g1, 8192, 256, 128);
    gemm_kernel<1><<<dim3(512 / 64, 8192 / 64), 256, 0, stream>>>(g1, dec_w2, dec_b2, g2, 8192, 512, 256);
    final_kernel<<<1024, 256, 0, stream>>>(g2, dec_w3, dec_b3, x, reconp);

    // diagnostics
    uniq_kernel<<<32, 256, 0, stream>>>(keys, count);
    scalars_kernel<<<1, 256, 0, stream>>>(qloss, reconp, count, out);
}

// Round 3
// 1217.865 us; speedup vs baseline: 2.0824x; 1.2203x over previous
//
#include <hip/hip_runtime.h>
#include <hip/hip_bf16.h>
#include <math.h>

// Problem constants
#define B_  8192
#define IN_ 768
#define D_  128
#define K_  8192
#define L_  3

typedef __attribute__((ext_vector_type(8))) short bf16x8;
typedef __attribute__((ext_vector_type(4))) float f32x4;

// Split f into hi (bf16 RNE) + lo (bf16 RNE of remainder). hi+lo carries
// ~17 mantissa bits -> ~2^-18 relative representation error.
__device__ __forceinline__ void split2(float f, unsigned short& h, unsigned short& l)
{
    unsigned u = __float_as_uint(f);
    unsigned hb = (u + 0x7FFFu + ((u >> 16) & 1u)) & 0xFFFF0000u;
    h = (unsigned short)(hb >> 16);
    float r = f - __uint_as_float(hb);
    unsigned v = __float_as_uint(r);
    l = (unsigned short)((v + 0x7FFFu + ((v >> 16) & 1u)) >> 16);
}

__device__ __forceinline__ unsigned short bf16_rne(float f)
{
    unsigned u = __float_as_uint(f);
    return (unsigned short)((u + 0x7FFFu + ((u >> 16) & 1u)) >> 16);
}

// ---------------------------------------------------------------------------
// Generic fp32 GEMM (encoder only): C[M,N] = act(A[M,K] @ W[N,K]^T + bias[N])
// BM=64, BN=64, BK=16, 256 threads, 4x4 micro-tile. ACT: 0=none, 1=silu.
// Encoder stays fp32: split-precision there perturbs `res` by ~1e-5 relative,
// which risks argmin id flips against the tight embs_norm tolerance.
// ---------------------------------------------------------------------------
template<int ACT>
__global__ __launch_bounds__(256)
void gemm_kernel(const float* __restrict__ A, const float* __restrict__ W,
                 const float* __restrict__ bias, float* __restrict__ C,
                 int M, int N, int K)
{
    __shared__ float As[64][20];
    __shared__ float Ws[64][20];
    const int tid = threadIdx.x;
    const int tx = tid & 15, ty = tid >> 4;
    const int m0 = blockIdx.y * 64, n0 = blockIdx.x * 64;

    float acc[4][4] = {};

    for (int k0 = 0; k0 < K; k0 += 16) {
        {
            int r  = tid >> 2;
            int c4 = (tid & 3) * 4;
            *(float4*)&As[r][c4] = *(const float4*)&A[(size_t)(m0 + r) * K + k0 + c4];
            *(float4*)&Ws[r][c4] = *(const float4*)&W[(size_t)(n0 + r) * K + k0 + c4];
        }
        __syncthreads();
        #pragma unroll
        for (int kk4 = 0; kk4 < 4; ++kk4) {
            float4 ra[4], wb[4];
            #pragma unroll
            for (int i = 0; i < 4; ++i) ra[i] = *(float4*)&As[ty * 4 + i][kk4 * 4];
            #pragma unroll
            for (int j = 0; j < 4; ++j) wb[j] = *(float4*)&Ws[tx + j * 16][kk4 * 4];
            #pragma unroll
            for (int i = 0; i < 4; ++i)
                #pragma unroll
                for (int j = 0; j < 4; ++j)
                    acc[i][j] += ra[i].x * wb[j].x + ra[i].y * wb[j].y
                               + ra[i].z * wb[j].z + ra[i].w * wb[j].w;
        }
        __syncthreads();
    }

    #pragma unroll
    for (int j = 0; j < 4; ++j) {
        int n = n0 + tx + j * 16;
        float bv = bias[n];
        #pragma unroll
        for (int i = 0; i < 4; ++i) {
            float v = acc[i][j] + bv;
            if (ACT == 1) v = v / (1.0f + expf(-v));
            C[(size_t)(m0 + ty * 4 + i) * N + n] = v;
        }
    }
}

// ---------------------------------------------------------------------------
// Split-precision MFMA GEMM (decoder): C = act(A @ W^T + bias), A,W given as
// bf16 hi/lo pairs; dot = hh + lh + hl (error ~2^-17 rel, only affects
// recon/loss which have ~2% tolerance).
// BM=128 (4 waves x 2 m-tiles), BN=128 (8 n-tiles), K-step 32, fragments
// loaded straight from global (W is L2-resident, A streamed).
// ACT: 1=silu, 2=sigmoid. OUT: 0=bf16 hi/lo pair, 1=single bf16.
// ---------------------------------------------------------------------------
template<int N, int K, int ACT, int OUT>
__global__ __launch_bounds__(256)
void mfma_gemm_kernel(const unsigned short* __restrict__ A_hi,
                      const unsigned short* __restrict__ A_lo,
                      const unsigned short* __restrict__ W_hi,
                      const unsigned short* __restrict__ W_lo,
                      const float* __restrict__ bias,
                      unsigned short* __restrict__ C_hi,
                      unsigned short* __restrict__ C_lo)
{
    const int tid  = threadIdx.x;
    const int lane = tid & 63;
    const int w    = tid >> 6;
    const int ln   = lane & 15;
    const int grp  = lane >> 4;
    const int m0   = blockIdx.y * 128 + w * 32;
    const int n0   = blockIdx.x * 128;

    f32x4 acc[2][8] = {};

    for (int ks = 0; ks < K; ks += 32) {
        bf16x8 ah[2], al[2];
        #pragma unroll
        for (int mt = 0; mt < 2; ++mt) {
            const size_t off = (size_t)(m0 + mt * 16 + ln) * K + ks + grp * 8;
            ah[mt] = *(const bf16x8*)&A_hi[off];
            al[mt] = *(const bf16x8*)&A_lo[off];
        }
        #pragma unroll
        for (int nt = 0; nt < 8; ++nt) {
            const size_t off = (size_t)(n0 + nt * 16 + ln) * K + ks + grp * 8;
            bf16x8 bh = *(const bf16x8*)&W_hi[off];
            bf16x8 bl = *(const bf16x8*)&W_lo[off];
            #pragma unroll
            for (int mt = 0; mt < 2; ++mt) {
                acc[mt][nt] = __builtin_amdgcn_mfma_f32_16x16x32_bf16(ah[mt], bh, acc[mt][nt], 0, 0, 0);
                acc[mt][nt] = __builtin_amdgcn_mfma_f32_16x16x32_bf16(al[mt], bh, acc[mt][nt], 0, 0, 0);
                acc[mt][nt] = __builtin_amdgcn_mfma_f32_16x16x32_bf16(ah[mt], bl, acc[mt][nt], 0, 0, 0);
            }
        }
    }

    #pragma unroll
    for (int nt = 0; nt < 8; ++nt) {
        const int col = n0 + nt * 16 + ln;
        const float bv = bias[col];
        #pragma unroll
        for (int mt = 0; mt < 2; ++mt) {
            #pragma unroll
            for (int r = 0; r < 4; ++r) {
                const int row = m0 + mt * 16 + grp * 4 + r;
                float v = acc[mt][nt][r] + bv;
                if (ACT == 1) v = v / (1.0f + expf(-v));
                if (ACT == 2) v = 1.0f / (1.0f + expf(-v));
                if (OUT == 0) {
                    unsigned short h, l;
                    split2(v, h, l);
                    C_hi[(size_t)row * N + col] = h;
                    C_lo[(size_t)row * N + col] = l;
                } else {
                    C_hi[(size_t)row * N + col] = bf16_rne(v);
                }
            }
        }
    }
}

// ---------------------------------------------------------------------------
// Per-row L2 normalize + recon partial: reads x_hat (bf16), x (fp32),
// writes recon_row[b] = sum_d (xhat_norm - x)^2. One 256-thr block per row.
// ---------------------------------------------------------------------------
__global__ __launch_bounds__(256)
void norm_recon_kernel(const unsigned short* __restrict__ xhat,
                       const float* __restrict__ x,
                       float* __restrict__ recon_row)
{
    const int b = blockIdx.x;
    const int tid = threadIdx.x;
    __shared__ float ws[4];
    __shared__ float nrm_s;

    float v[3];
    float ss = 0.0f;
    #pragma unroll
    for (int c = 0; c < 3; ++c) {
        unsigned short u = xhat[(size_t)b * 768 + tid + c * 256];
        v[c] = __uint_as_float((unsigned)u << 16);
        ss += v[c] * v[c];
    }
    for (int off = 32; off > 0; off >>= 1) ss += __shfl_down(ss, off, 64);
    if ((tid & 63) == 0) ws[tid >> 6] = ss;
    __syncthreads();
    if (tid == 0) nrm_s = fmaxf(sqrtf(ws[0] + ws[1] + ws[2] + ws[3]), 1e-12f);
    __syncthreads();
    const float inv = 1.0f / nrm_s;
    float ra = 0.0f;
    #pragma unroll
    for (int c = 0; c < 3; ++c) {
        float dx = v[c] * inv - x[(size_t)b * 768 + tid + c * 256];
        ra += dx * dx;
    }
    for (int off = 32; off > 0; off >>= 1) ra += __shfl_down(ra, off, 64);
    if ((tid & 63) == 0) ws[tid >> 6] = ra;
    __syncthreads();
    if (tid == 0) recon_row[b] = ws[0] + ws[1] + ws[2] + ws[3];
}

// ---------------------------------------------------------------------------
// Projected codebook + bf16 hi/lo split + per-row squared norms.
// ---------------------------------------------------------------------------
__global__ __launch_bounds__(128)
void proj_split_kernel(const float* __restrict__ cbl, const float* __restrict__ projl,
                       float* __restrict__ cbp, unsigned short* __restrict__ cbp_hi,
                       unsigned short* __restrict__ cbp_lo, float* __restrict__ cbn)
{
    __shared__ float cbs[8][128];
    __shared__ float wsum[8][2];
    const int tid = threadIdx.x;          // = d
    const int k0 = blockIdx.x * 8;

    #pragma unroll
    for (int i = 0; i < 2; ++i) {
        int idx4 = tid + i * 128;
        int r = idx4 >> 5, c4 = (idx4 & 31) * 4;
        *(float4*)&cbs[r][c4] = *(const float4*)&cbl[(size_t)(k0 + r) * 128 + c4];
    }
    __syncthreads();

    float acc[8] = {};
    for (int j4 = 0; j4 < 32; ++j4) {
        float4 pv = *(const float4*)&projl[(size_t)tid * 128 + j4 * 4];
        #pragma unroll
        for (int r = 0; r < 8; ++r) {
            float4 cv = *(float4*)&cbs[r][j4 * 4];
            acc[r] += pv.x * cv.x + pv.y * cv.y + pv.z * cv.z + pv.w * cv.w;
        }
    }
    #pragma unroll
    for (int r = 0; r < 8; ++r) {
        size_t idx = (size_t)(k0 + r) * 128 + tid;
        cbp[idx] = acc[r];
        unsigned short h, l;
        split2(acc[r], h, l);
        cbp_hi[idx] = h;
        cbp_lo[idx] = l;
        float v = acc[r] * acc[r];
        #pragma unroll
        for (int off = 32; off > 0; off >>= 1) v += __shfl_down(v, off, 64);
        if ((tid & 63) == 0) wsum[r][tid >> 6] = v;
    }
    __syncthreads();
    if (tid < 8) cbn[k0 + tid] = wsum[tid][0] + wsum[tid][1];
}

// ---------------------------------------------------------------------------
// fp32 -> bf16 hi/lo split (res after encoder, z, decoder weights).
// ---------------------------------------------------------------------------
__global__ __launch_bounds__(256)
void split_kernel(const float* __restrict__ src, unsigned short* __restrict__ hi,
                  unsigned short* __restrict__ lo, int n4)
{
    int i = blockIdx.x * 256 + threadIdx.x;
    if (i >= n4) return;
    float4 v = ((const float4*)src)[i];
    ushort4 h, l;
    split2(v.x, h.x, l.x); split2(v.y, h.y, l.y);
    split2(v.z, h.z, l.z); split2(v.w, h.w, l.w);
    ((ushort4*)hi)[i] = h;
    ((ushort4*)lo)[i] = l;
}

// ---------------------------------------------------------------------------
// MFMA distance argmin (unchanged from round 2 — verified exact ids).
// ---------------------------------------------------------------------------
__device__ __forceinline__ unsigned int fkey(float s) {
    unsigned int u = __float_as_uint(s);
    return (u & 0x80000000u) ? ~u : (u | 0x80000000u);
}

__global__ __launch_bounds__(256)
void argmin_mfma_kernel(const unsigned short* __restrict__ res_hi,
                        const unsigned short* __restrict__ res_lo,
                        const unsigned short* __restrict__ cbp_hi,
                        const unsigned short* __restrict__ cbp_lo,
                        const float* __restrict__ cbn,
                        unsigned long long* __restrict__ minkey)
{
    const int tid  = threadIdx.x;
    const int lane = tid & 63;
    const int w    = tid >> 6;
    const int ln   = lane & 15;
    const int grp  = lane >> 4;
    const int m0   = blockIdx.y * 128 + w * 32;
    const int c0b  = blockIdx.x * 256;

    bf16x8 a_hi[2][4], a_lo[2][4];
    #pragma unroll
    for (int mt = 0; mt < 2; ++mt) {
        const size_t base = (size_t)(m0 + mt * 16 + ln) * 128 + grp * 8;
        #pragma unroll
        for (int s = 0; s < 4; ++s) {
            a_hi[mt][s] = *(const bf16x8*)&res_hi[base + s * 32];
            a_lo[mt][s] = *(const bf16x8*)&res_lo[base + s * 32];
        }
    }

    unsigned long long best[2][4];
    #pragma unroll
    for (int mt = 0; mt < 2; ++mt)
        #pragma unroll
        for (int r = 0; r < 4; ++r) best[mt][r] = ~0ULL;

    for (int it = 0; it < 4; ++it) {
        const int c0 = c0b + it * 64;
        f32x4 acc[2][4] = {};
        #pragma unroll
        for (int s = 0; s < 4; ++s) {
            #pragma unroll
            for (int t = 0; t < 4; ++t) {
                const size_t bb = (size_t)(c0 + t * 16 + ln) * 128 + grp * 8 + s * 32;
                bf16x8 bh = *(const bf16x8*)&cbp_hi[bb];
                bf16x8 bl = *(const bf16x8*)&cbp_lo[bb];
                #pragma unroll
                for (int mt = 0; mt < 2; ++mt) {
                    acc[mt][t] = __builtin_amdgcn_mfma_f32_16x16x32_bf16(a_hi[mt][s], bh, acc[mt][t], 0, 0, 0);
                    acc[mt][t] = __builtin_amdgcn_mfma_f32_16x16x32_bf16(a_lo[mt][s], bh, acc[mt][t], 0, 0, 0);
                    acc[mt][t] = __builtin_amdgcn_mfma_f32_16x16x32_bf16(a_hi[mt][s], bl, acc[mt][t], 0, 0, 0);
                }
            }
        }
        #pragma unroll
        for (int t = 0; t < 4; ++t) {
            const int col = c0 + t * 16 + ln;
            const float cn = cbn[col];
            #pragma unroll
            for (int mt = 0; mt < 2; ++mt)
                #pragma unroll
                for (int r = 0; r < 4; ++r) {
                    float sc = cn - 2.0f * acc[mt][t][r];
                    unsigned long long key =
                        ((unsigned long long)fkey(sc) << 32) | (unsigned int)col;
                    if (key < best[mt][r]) best[mt][r] = key;
                }
        }
    }

    #pragma unroll
    for (int mt = 0; mt < 2; ++mt)
        #pragma unroll
        for (int r = 0; r < 4; ++r) {
            unsigned long long b = best[mt][r];
            #pragma unroll
            for (int off = 1; off < 16; off <<= 1) {
                unsigned lo32 = (unsigned)b, hi32 = (unsigned)(b >> 32);
                lo32 = __shfl_xor(lo32, off);
                hi32 = __shfl_xor(hi32, off);
                unsigned long long o = ((unsigned long long)hi32 << 32) | lo32;
                if (o < b) b = o;
            }
            if (ln == 0) atomicMin(&minkey[m0 + mt * 16 + grp * 4 + r], b);
        }
}

// ---------------------------------------------------------------------------
// Per-layer epilogue (unchanged).
// ---------------------------------------------------------------------------
__global__ __launch_bounds__(128)
void finalize_kernel(float* __restrict__ res, const float* __restrict__ cbp,
                     const unsigned long long* __restrict__ minkey,
                     float* __restrict__ qloss, float* __restrict__ z,
                     int* __restrict__ ids, float* __restrict__ embs_norm_out,
                     unsigned long long* __restrict__ keys,
                     unsigned short* __restrict__ res_hi,
                     unsigned short* __restrict__ res_lo, int layer)
{
    const int b = blockIdx.x;
    const int tid = threadIdx.x;
    const int id = (int)(minkey[b] & 0xFFFFFFFFull);
    float e = cbp[(size_t)id * 128 + tid];
    float r = res[(size_t)b * 128 + tid];
    float d = r - e;
    float v1 = d * d, v2 = e * e;
    for (int off = 32; off > 0; off >>= 1) {
        v1 += __shfl_down(v1, off, 64);
        v2 += __shfl_down(v2, off, 64);
    }
    __shared__ float ws[4];
    if ((tid & 63) == 0) { ws[(tid >> 6) * 2] = v1; ws[(tid >> 6) * 2 + 1] = v2; }
    __syncthreads();
    if (tid == 0) {
        float d2 = ws[0] + ws[2];
        float n2 = ws[1] + ws[3];
        qloss[b] += 1.25f * d2;                 // emb_loss + 0.25*query_loss
        embs_norm_out[b * 3 + layer] = sqrtf(n2);
        ids[b * 3 + layer] = id;
        if (layer == 2) {
            keys[b] = (unsigned long long)ids[b * 3 + 0]
                    | ((unsigned long long)ids[b * 3 + 1] << 13)
                    | ((unsigned long long)id << 26);
        }
    }
    z[(size_t)b * 128 + tid] += e;
    float nr = r - e;
    res[(size_t)b * 128 + tid] = nr;
    unsigned short h, l;
    split2(nr, h, l);
    res_hi[(size_t)b * 128 + tid] = h;
    res_lo[(size_t)b * 128 + tid] = l;
}

// ---------------------------------------------------------------------------
// Unique-triple count.
// ---------------------------------------------------------------------------
__global__ __launch_bounds__(256)
void uniq_kernel(const unsigned long long* __restrict__ keys, int* __restrict__ count)
{
    __shared__ unsigned long long ks[8192];
    const int tid = threadIdx.x;
    for (int i = tid; i < 8192; i += 256) ks[i] = keys[i];
    __syncthreads();
    const int i = blockIdx.x * 256 + tid;
    const unsigned long long k = ks[i];
    int dup = 0;
    for (int j = i + 1; j < 8192; ++j) dup |= (ks[j] == k);
    if (!dup) atomicAdd(count, 1);
}

// ---------------------------------------------------------------------------
// Final scalars.
// ---------------------------------------------------------------------------
__global__ __launch_bounds__(256)
void scalars_kernel(const float* __restrict__ qloss,
                    const float* __restrict__ recon_row,
                    const int* __restrict__ count, float* __restrict__ out)
{
    const int tid = threadIdx.x;
    float qs = 0.0f, rs = 0.0f;
    for (int i = tid; i < 8192; i += 256) qs += qloss[i];
    for (int i = tid; i < 8192; i += 256) rs += recon_row[i];
    for (int off = 32; off > 0; off >>= 1) {
        qs += __shfl_down(qs, off, 64);
        rs += __shfl_down(rs, off, 64);
    }
    __shared__ float w[8];
    if ((tid & 63) == 0) { w[(tid >> 6) * 2] = qs; w[(tid >> 6) * 2 + 1] = rs; }
    __syncthreads();
    if (tid == 0) {
        float qsum = w[0] + w[2] + w[4] + w[6];
        float rsum = w[1] + w[3] + w[5] + w[7];
        float qmean = qsum / 8192.0f;
        out[0] = rsum + qmean;        // loss = (recon + qloss).mean()
        out[1] = rsum;                // recon
        out[2] = qmean;               // qloss.mean()
        out[24579] = (float)(*count) / 8192.0f;   // p_unique
    }
}

// ---------------------------------------------------------------------------
extern "C" void kernel_launch(void* const* d_in, const int* in_sizes, int n_in,
                              void* d_out, int out_size, void* d_ws, size_t ws_size,
                              hipStream_t stream)
{
    const float* x      = (const float*)d_in[0];
    const float* enc_w1 = (const float*)d_in[1];
    const float* enc_b1 = (const float*)d_in[2];
    const float* enc_w2 = (const float*)d_in[3];
    const float* enc_b2 = (const float*)d_in[4];
    const float* enc_w3 = (const float*)d_in[5];
    const float* enc_b3 = (const float*)d_in[6];
    const float* dec_w1 = (const float*)d_in[7];
    const float* dec_b1 = (const float*)d_in[8];
    const float* dec_w2 = (const float*)d_in[9];
    const float* dec_b2 = (const float*)d_in[10];
    const float* dec_w3 = (const float*)d_in[11];
    const float* dec_b3 = (const float*)d_in[12];
    const float* codebooks = (const float*)d_in[13];
    const float* projs     = (const float*)d_in[14];
    float* out = (float*)d_out;

    char* ws = (char*)d_ws;
    const size_t MB = 1024 * 1024;

    // --- region [0, 16M): encoder h1 f32 ; decoder g2_hi/g2_lo
    float* h1 = (float*)ws;                                        // 8192x512 f32
    unsigned short* g2_hi = (unsigned short*)ws;                   // 8192x512 bf16
    unsigned short* g2_lo = (unsigned short*)(ws + 8 * MB);
    // --- region [16M, 24M): encoder h2 f32 ; quant res/cbp splits ; dec g1
    float* h2 = (float*)(ws + 16 * MB);                            // 8192x256 f32
    unsigned short* res_hi = (unsigned short*)(ws + 16 * MB);      // 8192x128
    unsigned short* res_lo = (unsigned short*)(ws + 18 * MB);
    unsigned short* cbp_hi = (unsigned short*)(ws + 20 * MB);
    unsigned short* cbp_lo = (unsigned short*)(ws + 22 * MB);
    unsigned short* g1_hi  = (unsigned short*)(ws + 16 * MB);      // 8192x256 (decoder)
    unsigned short* g1_lo  = (unsigned short*)(ws + 20 * MB);
    // --- region [24M, 28M): res f32
    float* res = (float*)(ws + 24 * MB);                           // 8192x128 f32
    // --- region [28M, 32M): cbp f32 ; decoder z_hi/z_lo
    float* cbp = (float*)(ws + 28 * MB);                           // 8192x128 f32
    unsigned short* z_hi = (unsigned short*)(ws + 28 * MB);        // 8192x128
    unsigned short* z_lo = (unsigned short*)(ws + 30 * MB);
    // --- region [32M, 36M): z f32
    float* z = (float*)(ws + 32 * MB);                             // 8192x128 f32
    // --- region [36M, ...): decoder weight splits + small buffers
    char* p = ws + 36 * MB;
    unsigned short* dw1_hi = (unsigned short*)p; p += 256 * 128 * 2;
    unsigned short* dw1_lo = (unsigned short*)p; p += 256 * 128 * 2;
    unsigned short* dw2_hi = (unsigned short*)p; p += 512 * 256 * 2;
    unsigned short* dw2_lo = (unsigned short*)p; p += 512 * 256 * 2;
    unsigned short* dw3_hi = (unsigned short*)p; p += 768 * 512 * 2;
    unsigned short* dw3_lo = (unsigned short*)p; p += 768 * 512 * 2;
    float* cbn       = (float*)p; p += 8192 * 4;
    float* qloss     = (float*)p; p += 8192 * 4;
    float* recon_row = (float*)p; p += 8192 * 4;
    unsigned long long* minkey = (unsigned long long*)p; p += 8192 * 8;
    unsigned long long* keys   = (unsigned long long*)p; p += 8192 * 8;
    int* ids   = (int*)p; p += 8192 * 3 * 4;
    int* count = (int*)p; p += 256;                      // pad to alignment
    unsigned short* xhat = (unsigned short*)p;           // 8192x768 bf16 (12 MB)

    hipMemsetAsync(z, 0, (size_t)8192 * 128 * sizeof(float), stream);
    hipMemsetAsync(qloss, 0, 8192 * sizeof(float), stream);
    hipMemsetAsync(count, 0, sizeof(int), stream);

    // decoder weight splits (inputs only; do them up front)
    split_kernel<<<32,  256, 0, stream>>>(dec_w1, dw1_hi, dw1_lo, 256 * 128 / 4);
    split_kernel<<<128, 256, 0, stream>>>(dec_w2, dw2_hi, dw2_lo, 512 * 256 / 4);
    split_kernel<<<384, 256, 0, stream>>>(dec_w3, dw3_hi, dw3_lo, 768 * 512 / 4);

    // encoder (fp32 — argmin-id safety)
    gemm_kernel<1><<<dim3(512 / 64, 8192 / 64), 256, 0, stream>>>(x,  enc_w1, enc_b1, h1, 8192, 512, 768);
    gemm_kernel<1><<<dim3(256 / 64, 8192 / 64), 256, 0, stream>>>(h1, enc_w2, enc_b2, h2, 8192, 256, 512);
    gemm_kernel<0><<<dim3(128 / 64, 8192 / 64), 256, 0, stream>>>(h2, enc_w3, enc_b3, res, 8192, 128, 256);
    split_kernel<<<1024, 256, 0, stream>>>(res, res_hi, res_lo, 8192 * 128 / 4);

    // residual quantization layers
    for (int l = 0; l < 3; ++l) {
        proj_split_kernel<<<1024, 128, 0, stream>>>(codebooks + (size_t)l * 8192 * 128,
                                                    projs + (size_t)l * 128 * 128,
                                                    cbp, cbp_hi, cbp_lo, cbn);
        hipMemsetAsync(minkey, 0xFF, 8192 * sizeof(unsigned long long), stream);
        argmin_mfma_kernel<<<dim3(32, 64), 256, 0, stream>>>(res_hi, res_lo,
                                                             cbp_hi, cbp_lo, cbn, minkey);
        finalize_kernel<<<8192, 128, 0, stream>>>(res, cbp, minkey, qloss, z,
                                                  ids, out + 3, keys,
                                                  res_hi, res_lo, l);
    }

    // decoder (split-precision MFMA)
    split_kernel<<<1024, 256, 0, stream>>>(z, z_hi, z_lo, 8192 * 128 / 4);
    mfma_gemm_kernel<256, 128, 1, 0><<<dim3(2, 64), 256, 0, stream>>>(
        z_hi, z_lo, dw1_hi, dw1_lo, dec_b1, g1_hi, g1_lo);
    mfma_gemm_kernel<512, 256, 1, 0><<<dim3(4, 64), 256, 0, stream>>>(
        g1_hi, g1_lo, dw2_hi, dw2_lo, dec_b2, g2_hi, g2_lo);
    mfma_gemm_kernel<768, 512, 2, 1><<<dim3(6, 64), 256, 0, stream>>>(
        g2_hi, g2_lo, dw3_hi, dw3_lo, dec_b3, xhat, nullptr);
    norm_recon_kernel<<<8192, 256, 0, stream>>>(xhat, x, recon_row);

    // diagnostics
    uniq_kernel<<<32, 256, 0, stream>>>(keys, count);
    scalars_kernel<<<1, 256, 0, stream>>>(qloss, recon_row, count, out);
}

// Round 4
// 910.208 us; speedup vs baseline: 2.7863x; 1.3380x over previous
//
#include <hip/hip_runtime.h>
#include <hip/hip_bf16.h>
#include <math.h>

// Problem constants
#define B_  8192
#define IN_ 768
#define D_  128
#define K_  8192
#define L_  3

typedef __attribute__((ext_vector_type(8))) short bf16x8;
typedef __attribute__((ext_vector_type(4))) float f32x4;

// Split f into hi (bf16 RNE) + lo (bf16 RNE of remainder). hi+lo carries
// ~17 mantissa bits -> ~2^-18 relative representation error.
__device__ __forceinline__ void split2(float f, unsigned short& h, unsigned short& l)
{
    unsigned u = __float_as_uint(f);
    unsigned hb = (u + 0x7FFFu + ((u >> 16) & 1u)) & 0xFFFF0000u;
    h = (unsigned short)(hb >> 16);
    float r = f - __uint_as_float(hb);
    unsigned v = __float_as_uint(r);
    l = (unsigned short)((v + 0x7FFFu + ((v >> 16) & 1u)) >> 16);
}

// Triple split: f = h + m + l exactly to ~2^-27 rel (covers all 24 fp32
// mantissa bits). Each stage's subtraction is exact (Sterbenz-style).
__device__ __forceinline__ void split3(float f, unsigned short& h,
                                       unsigned short& m, unsigned short& l)
{
    unsigned u = __float_as_uint(f);
    unsigned hb = (u + 0x7FFFu + ((u >> 16) & 1u)) & 0xFFFF0000u;
    h = (unsigned short)(hb >> 16);
    float r1 = f - __uint_as_float(hb);
    unsigned v = __float_as_uint(r1);
    unsigned mb = (v + 0x7FFFu + ((v >> 16) & 1u)) & 0xFFFF0000u;
    m = (unsigned short)(mb >> 16);
    float r2 = r1 - __uint_as_float(mb);
    unsigned w = __float_as_uint(r2);
    l = (unsigned short)((w + 0x7FFFu + ((w >> 16) & 1u)) >> 16);
}

__device__ __forceinline__ unsigned short bf16_rne(float f)
{
    unsigned u = __float_as_uint(f);
    return (unsigned short)((u + 0x7FFFu + ((u >> 16) & 1u)) >> 16);
}

// ---------------------------------------------------------------------------
// Encoder MFMA GEMM, fp32-faithful: C = act(A @ W^T + bias).
// A is fp32, triple-split in-register per fragment; W is presplit into 3 bf16
// planes. 6 MFMA passes (hh, mh, hm, lh, mm, hl) -> error ~1e-6 rel, same
// order as fp32 summation reorder => argmin-id safe.
// BM=128 (4 waves x 2 m-tiles), BN=64 (4 n-tiles), K-step 32.
// ACT: 0=none, 1=silu. Output fp32.
// ---------------------------------------------------------------------------
template<int N, int K, int ACT>
__global__ __launch_bounds__(256)
void mfma_enc_kernel(const float* __restrict__ A,
                     const unsigned short* __restrict__ Wh,
                     const unsigned short* __restrict__ Wm,
                     const unsigned short* __restrict__ Wl,
                     const float* __restrict__ bias, float* __restrict__ C)
{
    const int tid  = threadIdx.x;
    const int lane = tid & 63;
    const int w    = tid >> 6;
    const int ln   = lane & 15;
    const int grp  = lane >> 4;
    const int m0   = blockIdx.y * 128 + w * 32;
    const int n0   = blockIdx.x * 64;

    f32x4 acc[2][4] = {};

    for (int ks = 0; ks < K; ks += 32) {
        bf16x8 ah[2], am[2], al[2];
        #pragma unroll
        for (int mt = 0; mt < 2; ++mt) {
            const size_t off = (size_t)(m0 + mt * 16 + ln) * K + ks + grp * 8;
            float4 f0 = *(const float4*)&A[off];
            float4 f1 = *(const float4*)&A[off + 4];
            float fv[8] = {f0.x, f0.y, f0.z, f0.w, f1.x, f1.y, f1.z, f1.w};
            #pragma unroll
            for (int e = 0; e < 8; ++e) {
                unsigned short hh, mm, ll;
                split3(fv[e], hh, mm, ll);
                ah[mt][e] = (short)hh;
                am[mt][e] = (short)mm;
                al[mt][e] = (short)ll;
            }
        }
        #pragma unroll
        for (int nt = 0; nt < 4; ++nt) {
            const size_t off = (size_t)(n0 + nt * 16 + ln) * K + ks + grp * 8;
            bf16x8 bh = *(const bf16x8*)&Wh[off];
            bf16x8 bm = *(const bf16x8*)&Wm[off];
            bf16x8 bl = *(const bf16x8*)&Wl[off];
            #pragma unroll
            for (int mt = 0; mt < 2; ++mt) {
                acc[mt][nt] = __builtin_amdgcn_mfma_f32_16x16x32_bf16(ah[mt], bh, acc[mt][nt], 0, 0, 0);
                acc[mt][nt] = __builtin_amdgcn_mfma_f32_16x16x32_bf16(am[mt], bh, acc[mt][nt], 0, 0, 0);
                acc[mt][nt] = __builtin_amdgcn_mfma_f32_16x16x32_bf16(ah[mt], bm, acc[mt][nt], 0, 0, 0);
                acc[mt][nt] = __builtin_amdgcn_mfma_f32_16x16x32_bf16(al[mt], bh, acc[mt][nt], 0, 0, 0);
                acc[mt][nt] = __builtin_amdgcn_mfma_f32_16x16x32_bf16(am[mt], bm, acc[mt][nt], 0, 0, 0);
                acc[mt][nt] = __builtin_amdgcn_mfma_f32_16x16x32_bf16(ah[mt], bl, acc[mt][nt], 0, 0, 0);
            }
        }
    }

    #pragma unroll
    for (int nt = 0; nt < 4; ++nt) {
        const int col = n0 + nt * 16 + ln;
        const float bv = bias[col];
        #pragma unroll
        for (int mt = 0; mt < 2; ++mt) {
            #pragma unroll
            for (int r = 0; r < 4; ++r) {
                const int row = m0 + mt * 16 + grp * 4 + r;
                float v = acc[mt][nt][r] + bv;
                if (ACT == 1) v = v / (1.0f + expf(-v));
                C[(size_t)row * N + col] = v;
            }
        }
    }
}

// ---------------------------------------------------------------------------
// Split-precision MFMA GEMM (decoder): C = act(A @ W^T + bias), A,W given as
// bf16 hi/lo pairs; dot = hh + lh + hl (error ~2^-17 rel, only affects
// recon/loss which have ~2% tolerance).
// BM=128 (4 waves x 2 m-tiles), BN=128 (8 n-tiles), K-step 32.
// ACT: 1=silu, 2=sigmoid. OUT: 0=bf16 hi/lo pair, 1=single bf16.
// ---------------------------------------------------------------------------
template<int N, int K, int ACT, int OUT>
__global__ __launch_bounds__(256)
void mfma_gemm_kernel(const unsigned short* __restrict__ A_hi,
                      const unsigned short* __restrict__ A_lo,
                      const unsigned short* __restrict__ W_hi,
                      const unsigned short* __restrict__ W_lo,
                      const float* __restrict__ bias,
                      unsigned short* __restrict__ C_hi,
                      unsigned short* __restrict__ C_lo)
{
    const int tid  = threadIdx.x;
    const int lane = tid & 63;
    const int w    = tid >> 6;
    const int ln   = lane & 15;
    const int grp  = lane >> 4;
    const int m0   = blockIdx.y * 128 + w * 32;
    const int n0   = blockIdx.x * 128;

    f32x4 acc[2][8] = {};

    for (int ks = 0; ks < K; ks += 32) {
        bf16x8 ah[2], al[2];
        #pragma unroll
        for (int mt = 0; mt < 2; ++mt) {
            const size_t off = (size_t)(m0 + mt * 16 + ln) * K + ks + grp * 8;
            ah[mt] = *(const bf16x8*)&A_hi[off];
            al[mt] = *(const bf16x8*)&A_lo[off];
        }
        #pragma unroll
        for (int nt = 0; nt < 8; ++nt) {
            const size_t off = (size_t)(n0 + nt * 16 + ln) * K + ks + grp * 8;
            bf16x8 bh = *(const bf16x8*)&W_hi[off];
            bf16x8 bl = *(const bf16x8*)&W_lo[off];
            #pragma unroll
            for (int mt = 0; mt < 2; ++mt) {
                acc[mt][nt] = __builtin_amdgcn_mfma_f32_16x16x32_bf16(ah[mt], bh, acc[mt][nt], 0, 0, 0);
                acc[mt][nt] = __builtin_amdgcn_mfma_f32_16x16x32_bf16(al[mt], bh, acc[mt][nt], 0, 0, 0);
                acc[mt][nt] = __builtin_amdgcn_mfma_f32_16x16x32_bf16(ah[mt], bl, acc[mt][nt], 0, 0, 0);
            }
        }
    }

    #pragma unroll
    for (int nt = 0; nt < 8; ++nt) {
        const int col = n0 + nt * 16 + ln;
        const float bv = bias[col];
        #pragma unroll
        for (int mt = 0; mt < 2; ++mt) {
            #pragma unroll
            for (int r = 0; r < 4; ++r) {
                const int row = m0 + mt * 16 + grp * 4 + r;
                float v = acc[mt][nt][r] + bv;
                if (ACT == 1) v = v / (1.0f + expf(-v));
                if (ACT == 2) v = 1.0f / (1.0f + expf(-v));
                if (OUT == 0) {
                    unsigned short h, l;
                    split2(v, h, l);
                    C_hi[(size_t)row * N + col] = h;
                    C_lo[(size_t)row * N + col] = l;
                } else {
                    C_hi[(size_t)row * N + col] = bf16_rne(v);
                }
            }
        }
    }
}

// ---------------------------------------------------------------------------
// Per-row L2 normalize + recon partial.
// ---------------------------------------------------------------------------
__global__ __launch_bounds__(256)
void norm_recon_kernel(const unsigned short* __restrict__ xhat,
                       const float* __restrict__ x,
                       float* __restrict__ recon_row)
{
    const int b = blockIdx.x;
    const int tid = threadIdx.x;
    __shared__ float ws[4];
    __shared__ float nrm_s;

    float v[3];
    float ss = 0.0f;
    #pragma unroll
    for (int c = 0; c < 3; ++c) {
        unsigned short u = xhat[(size_t)b * 768 + tid + c * 256];
        v[c] = __uint_as_float((unsigned)u << 16);
        ss += v[c] * v[c];
    }
    for (int off = 32; off > 0; off >>= 1) ss += __shfl_down(ss, off, 64);
    if ((tid & 63) == 0) ws[tid >> 6] = ss;
    __syncthreads();
    if (tid == 0) nrm_s = fmaxf(sqrtf(ws[0] + ws[1] + ws[2] + ws[3]), 1e-12f);
    __syncthreads();
    const float inv = 1.0f / nrm_s;
    float ra = 0.0f;
    #pragma unroll
    for (int c = 0; c < 3; ++c) {
        float dx = v[c] * inv - x[(size_t)b * 768 + tid + c * 256];
        ra += dx * dx;
    }
    for (int off = 32; off > 0; off >>= 1) ra += __shfl_down(ra, off, 64);
    if ((tid & 63) == 0) ws[tid >> 6] = ra;
    __syncthreads();
    if (tid == 0) recon_row[b] = ws[0] + ws[1] + ws[2] + ws[3];
}

// ---------------------------------------------------------------------------
// Projected codebook + bf16 hi/lo split + per-row squared norms.
// ---------------------------------------------------------------------------
__global__ __launch_bounds__(128)
void proj_split_kernel(const float* __restrict__ cbl, const float* __restrict__ projl,
                       float* __restrict__ cbp, unsigned short* __restrict__ cbp_hi,
                       unsigned short* __restrict__ cbp_lo, float* __restrict__ cbn)
{
    __shared__ float cbs[8][128];
    __shared__ float wsum[8][2];
    const int tid = threadIdx.x;          // = d
    const int k0 = blockIdx.x * 8;

    #pragma unroll
    for (int i = 0; i < 2; ++i) {
        int idx4 = tid + i * 128;
        int r = idx4 >> 5, c4 = (idx4 & 31) * 4;
        *(float4*)&cbs[r][c4] = *(const float4*)&cbl[(size_t)(k0 + r) * 128 + c4];
    }
    __syncthreads();

    float acc[8] = {};
    for (int j4 = 0; j4 < 32; ++j4) {
        float4 pv = *(const float4*)&projl[(size_t)tid * 128 + j4 * 4];
        #pragma unroll
        for (int r = 0; r < 8; ++r) {
            float4 cv = *(float4*)&cbs[r][j4 * 4];
            acc[r] += pv.x * cv.x + pv.y * cv.y + pv.z * cv.z + pv.w * cv.w;
        }
    }
    #pragma unroll
    for (int r = 0; r < 8; ++r) {
        size_t idx = (size_t)(k0 + r) * 128 + tid;
        cbp[idx] = acc[r];
        unsigned short h, l;
        split2(acc[r], h, l);
        cbp_hi[idx] = h;
        cbp_lo[idx] = l;
        float v = acc[r] * acc[r];
        #pragma unroll
        for (int off = 32; off > 0; off >>= 1) v += __shfl_down(v, off, 64);
        if ((tid & 63) == 0) wsum[r][tid >> 6] = v;
    }
    __syncthreads();
    if (tid < 8) cbn[k0 + tid] = wsum[tid][0] + wsum[tid][1];
}

// ---------------------------------------------------------------------------
// fp32 -> bf16 hi/lo split (res, z, decoder weights).
// ---------------------------------------------------------------------------
__global__ __launch_bounds__(256)
void split_kernel(const float* __restrict__ src, unsigned short* __restrict__ hi,
                  unsigned short* __restrict__ lo, int n4)
{
    int i = blockIdx.x * 256 + threadIdx.x;
    if (i >= n4) return;
    float4 v = ((const float4*)src)[i];
    ushort4 h, l;
    split2(v.x, h.x, l.x); split2(v.y, h.y, l.y);
    split2(v.z, h.z, l.z); split2(v.w, h.w, l.w);
    ((ushort4*)hi)[i] = h;
    ((ushort4*)lo)[i] = l;
}

// ---------------------------------------------------------------------------
// fp32 -> bf16 triple split (encoder weights, exact to 2^-27).
// ---------------------------------------------------------------------------
__global__ __launch_bounds__(256)
void split3_kernel(const float* __restrict__ src, unsigned short* __restrict__ hi,
                   unsigned short* __restrict__ mi, unsigned short* __restrict__ lo,
                   int n4)
{
    int i = blockIdx.x * 256 + threadIdx.x;
    if (i >= n4) return;
    float4 v = ((const float4*)src)[i];
    ushort4 h, m, l;
    split3(v.x, h.x, m.x, l.x); split3(v.y, h.y, m.y, l.y);
    split3(v.z, h.z, m.z, l.z); split3(v.w, h.w, m.w, l.w);
    ((ushort4*)hi)[i] = h;
    ((ushort4*)mi)[i] = m;
    ((ushort4*)lo)[i] = l;
}

// ---------------------------------------------------------------------------
// MFMA distance argmin (verified exact ids vs numpy).
// ---------------------------------------------------------------------------
__device__ __forceinline__ unsigned int fkey(float s) {
    unsigned int u = __float_as_uint(s);
    return (u & 0x80000000u) ? ~u : (u | 0x80000000u);
}

__global__ __launch_bounds__(256)
void argmin_mfma_kernel(const unsigned short* __restrict__ res_hi,
                        const unsigned short* __restrict__ res_lo,
                        const unsigned short* __restrict__ cbp_hi,
                        const unsigned short* __restrict__ cbp_lo,
                        const float* __restrict__ cbn,
                        unsigned long long* __restrict__ minkey)
{
    const int tid  = threadIdx.x;
    const int lane = tid & 63;
    const int w    = tid >> 6;
    const int ln   = lane & 15;
    const int grp  = lane >> 4;
    const int m0   = blockIdx.y * 128 + w * 32;
    const int c0b  = blockIdx.x * 256;

    bf16x8 a_hi[2][4], a_lo[2][4];
    #pragma unroll
    for (int mt = 0; mt < 2; ++mt) {
        const size_t base = (size_t)(m0 + mt * 16 + ln) * 128 + grp * 8;
        #pragma unroll
        for (int s = 0; s < 4; ++s) {
            a_hi[mt][s] = *(const bf16x8*)&res_hi[base + s * 32];
            a_lo[mt][s] = *(const bf16x8*)&res_lo[base + s * 32];
        }
    }

    unsigned long long best[2][4];
    #pragma unroll
    for (int mt = 0; mt < 2; ++mt)
        #pragma unroll
        for (int r = 0; r < 4; ++r) best[mt][r] = ~0ULL;

    for (int it = 0; it < 4; ++it) {
        const int c0 = c0b + it * 64;
        f32x4 acc[2][4] = {};
        #pragma unroll
        for (int s = 0; s < 4; ++s) {
            #pragma unroll
            for (int t = 0; t < 4; ++t) {
                const size_t bb = (size_t)(c0 + t * 16 + ln) * 128 + grp * 8 + s * 32;
                bf16x8 bh = *(const bf16x8*)&cbp_hi[bb];
                bf16x8 bl = *(const bf16x8*)&cbp_lo[bb];
                #pragma unroll
                for (int mt = 0; mt < 2; ++mt) {
                    acc[mt][t] = __builtin_amdgcn_mfma_f32_16x16x32_bf16(a_hi[mt][s], bh, acc[mt][t], 0, 0, 0);
                    acc[mt][t] = __builtin_amdgcn_mfma_f32_16x16x32_bf16(a_lo[mt][s], bh, acc[mt][t], 0, 0, 0);
                    acc[mt][t] = __builtin_amdgcn_mfma_f32_16x16x32_bf16(a_hi[mt][s], bl, acc[mt][t], 0, 0, 0);
                }
            }
        }
        #pragma unroll
        for (int t = 0; t < 4; ++t) {
            const int col = c0 + t * 16 + ln;
            const float cn = cbn[col];
            #pragma unroll
            for (int mt = 0; mt < 2; ++mt)
                #pragma unroll
                for (int r = 0; r < 4; ++r) {
                    float sc = cn - 2.0f * acc[mt][t][r];
                    unsigned long long key =
                        ((unsigned long long)fkey(sc) << 32) | (unsigned int)col;
                    if (key < best[mt][r]) best[mt][r] = key;
                }
        }
    }

    #pragma unroll
    for (int mt = 0; mt < 2; ++mt)
        #pragma unroll
        for (int r = 0; r < 4; ++r) {
            unsigned long long b = best[mt][r];
            #pragma unroll
            for (int off = 1; off < 16; off <<= 1) {
                unsigned lo32 = (unsigned)b, hi32 = (unsigned)(b >> 32);
                lo32 = __shfl_xor(lo32, off);
                hi32 = __shfl_xor(hi32, off);
                unsigned long long o = ((unsigned long long)hi32 << 32) | lo32;
                if (o < b) b = o;
            }
            if (ln == 0) atomicMin(&minkey[m0 + mt * 16 + grp * 4 + r], b);
        }
}

// ---------------------------------------------------------------------------
// Per-layer epilogue.
// ---------------------------------------------------------------------------
__global__ __launch_bounds__(128)
void finalize_kernel(float* __restrict__ res, const float* __restrict__ cbp,
                     const unsigned long long* __restrict__ minkey,
                     float* __restrict__ qloss, float* __restrict__ z,
                     int* __restrict__ ids, float* __restrict__ embs_norm_out,
                     unsigned long long* __restrict__ keys,
                     unsigned short* __restrict__ res_hi,
                     unsigned short* __restrict__ res_lo, int layer)
{
    const int b = blockIdx.x;
    const int tid = threadIdx.x;
    const int id = (int)(minkey[b] & 0xFFFFFFFFull);
    float e = cbp[(size_t)id * 128 + tid];
    float r = res[(size_t)b * 128 + tid];
    float d = r - e;
    float v1 = d * d, v2 = e * e;
    for (int off = 32; off > 0; off >>= 1) {
        v1 += __shfl_down(v1, off, 64);
        v2 += __shfl_down(v2, off, 64);
    }
    __shared__ float ws[4];
    if ((tid & 63) == 0) { ws[(tid >> 6) * 2] = v1; ws[(tid >> 6) * 2 + 1] = v2; }
    __syncthreads();
    if (tid == 0) {
        float d2 = ws[0] + ws[2];
        float n2 = ws[1] + ws[3];
        qloss[b] += 1.25f * d2;                 // emb_loss + 0.25*query_loss
        embs_norm_out[b * 3 + layer] = sqrtf(n2);
        ids[b * 3 + layer] = id;
        if (layer == 2) {
            keys[b] = (unsigned long long)ids[b * 3 + 0]
                    | ((unsigned long long)ids[b * 3 + 1] << 13)
                    | ((unsigned long long)id << 26);
        }
    }
    z[(size_t)b * 128 + tid] += e;
    float nr = r - e;
    res[(size_t)b * 128 + tid] = nr;
    unsigned short h, l;
    split2(nr, h, l);
    res_hi[(size_t)b * 128 + tid] = h;
    res_lo[(size_t)b * 128 + tid] = l;
}

// ---------------------------------------------------------------------------
// Distinct-triple count via open-addressing hash set. The reference counts
// rows with no later duplicate == number of DISTINCT keys. atomicCAS insert:
// exactly one thread per distinct key wins -> deterministic count.
// Keys are 39-bit, so ~0ULL is a safe empty marker.
// ---------------------------------------------------------------------------
__global__ __launch_bounds__(256)
void uniq_hash_kernel(const unsigned long long* __restrict__ keys,
                      unsigned long long* __restrict__ table,
                      int* __restrict__ count)
{
    const int i = blockIdx.x * 256 + threadIdx.x;
    const unsigned long long k = keys[i];
    unsigned h = (unsigned)((k * 0x9E3779B97F4A7C15ull) >> 50);   // 14 bits
    while (true) {
        unsigned long long old = atomicCAS(&table[h], ~0ULL, k);
        if (old == ~0ULL) { atomicAdd(count, 1); break; }   // first insert
        if (old == k) break;                                // duplicate
        h = (h + 1) & 16383;
    }
}

// ---------------------------------------------------------------------------
// Final scalars.
// ---------------------------------------------------------------------------
__global__ __launch_bounds__(256)
void scalars_kernel(const float* __restrict__ qloss,
                    const float* __restrict__ recon_row,
                    const int* __restrict__ count, float* __restrict__ out)
{
    const int tid = threadIdx.x;
    float qs = 0.0f, rs = 0.0f;
    for (int i = tid; i < 8192; i += 256) qs += qloss[i];
    for (int i = tid; i < 8192; i += 256) rs += recon_row[i];
    for (int off = 32; off > 0; off >>= 1) {
        qs += __shfl_down(qs, off, 64);
        rs += __shfl_down(rs, off, 64);
    }
    __shared__ float w[8];
    if ((tid & 63) == 0) { w[(tid >> 6) * 2] = qs; w[(tid >> 6) * 2 + 1] = rs; }
    __syncthreads();
    if (tid == 0) {
        float qsum = w[0] + w[2] + w[4] + w[6];
        float rsum = w[1] + w[3] + w[5] + w[7];
        float qmean = qsum / 8192.0f;
        out[0] = rsum + qmean;        // loss = (recon + qloss).mean()
        out[1] = rsum;                // recon
        out[2] = qmean;               // qloss.mean()
        out[24579] = (float)(*count) / 8192.0f;   // p_unique
    }
}

// ---------------------------------------------------------------------------
extern "C" void kernel_launch(void* const* d_in, const int* in_sizes, int n_in,
                              void* d_out, int out_size, void* d_ws, size_t ws_size,
                              hipStream_t stream)
{
    const float* x      = (const float*)d_in[0];
    const float* enc_w1 = (const float*)d_in[1];
    const float* enc_b1 = (const float*)d_in[2];
    const float* enc_w2 = (const float*)d_in[3];
    const float* enc_b2 = (const float*)d_in[4];
    const float* enc_w3 = (const float*)d_in[5];
    const float* enc_b3 = (const float*)d_in[6];
    const float* dec_w1 = (const float*)d_in[7];
    const float* dec_b1 = (const float*)d_in[8];
    const float* dec_w2 = (const float*)d_in[9];
    const float* dec_b2 = (const float*)d_in[10];
    const float* dec_w3 = (const float*)d_in[11];
    const float* dec_b3 = (const float*)d_in[12];
    const float* codebooks = (const float*)d_in[13];
    const float* projs     = (const float*)d_in[14];
    float* out = (float*)d_out;

    char* ws = (char*)d_ws;
    const size_t MB = 1024 * 1024;

    // --- region [0, 16M): encoder h1 f32 ; decoder g2_hi/g2_lo
    float* h1 = (float*)ws;                                        // 8192x512 f32
    unsigned short* g2_hi = (unsigned short*)ws;                   // 8192x512 bf16
    unsigned short* g2_lo = (unsigned short*)(ws + 8 * MB);
    // --- region [16M, 24M): encoder h2 f32 ; quant res/cbp splits ; dec g1
    float* h2 = (float*)(ws + 16 * MB);                            // 8192x256 f32
    unsigned short* res_hi = (unsigned short*)(ws + 16 * MB);      // 8192x128
    unsigned short* res_lo = (unsigned short*)(ws + 18 * MB);
    unsigned short* cbp_hi = (unsigned short*)(ws + 20 * MB);
    unsigned short* cbp_lo = (unsigned short*)(ws + 22 * MB);
    unsigned short* g1_hi  = (unsigned short*)(ws + 16 * MB);      // 8192x256 (decoder)
    unsigned short* g1_lo  = (unsigned short*)(ws + 20 * MB);
    // --- region [24M, 28M): res f32
    float* res = (float*)(ws + 24 * MB);                           // 8192x128 f32
    // --- region [28M, 32M): cbp f32 ; decoder z_hi/z_lo
    float* cbp = (float*)(ws + 28 * MB);                           // 8192x128 f32
    unsigned short* z_hi = (unsigned short*)(ws + 28 * MB);        // 8192x128
    unsigned short* z_lo = (unsigned short*)(ws + 30 * MB);
    // --- region [32M, 36M): z f32
    float* z = (float*)(ws + 32 * MB);                             // 8192x128 f32
    // --- region [36M, ...): weight splits + small buffers
    char* p = ws + 36 * MB;
    unsigned short* dw1_hi = (unsigned short*)p; p += 256 * 128 * 2;
    unsigned short* dw1_lo = (unsigned short*)p; p += 256 * 128 * 2;
    unsigned short* dw2_hi = (unsigned short*)p; p += 512 * 256 * 2;
    unsigned short* dw2_lo = (unsigned short*)p; p += 512 * 256 * 2;
    unsigned short* dw3_hi = (unsigned short*)p; p += 768 * 512 * 2;
    unsigned short* dw3_lo = (unsigned short*)p; p += 768 * 512 * 2;
    unsigned short* ew1_h  = (unsigned short*)p; p += 512 * 768 * 2;
    unsigned short* ew1_m  = (unsigned short*)p; p += 512 * 768 * 2;
    unsigned short* ew1_l  = (unsigned short*)p; p += 512 * 768 * 2;
    unsigned short* ew2_h  = (unsigned short*)p; p += 256 * 512 * 2;
    unsigned short* ew2_m  = (unsigned short*)p; p += 256 * 512 * 2;
    unsigned short* ew2_l  = (unsigned short*)p; p += 256 * 512 * 2;
    unsigned short* ew3_h  = (unsigned short*)p; p += 128 * 256 * 2;
    unsigned short* ew3_m  = (unsigned short*)p; p += 128 * 256 * 2;
    unsigned short* ew3_l  = (unsigned short*)p; p += 128 * 256 * 2;
    float* cbn       = (float*)p; p += 8192 * 4;
    float* qloss     = (float*)p; p += 8192 * 4;
    float* recon_row = (float*)p; p += 8192 * 4;
    unsigned long long* minkey = (unsigned long long*)p; p += 8192 * 8;
    unsigned long long* keys   = (unsigned long long*)p; p += 8192 * 8;
    unsigned long long* table  = (unsigned long long*)p; p += 16384 * 8;
    int* ids   = (int*)p; p += 8192 * 3 * 4;
    int* count = (int*)p; p += 256;                      // pad to alignment
    unsigned short* xhat = (unsigned short*)p;           // 8192x768 bf16 (12 MB)

    hipMemsetAsync(z, 0, (size_t)8192 * 128 * sizeof(float), stream);
    hipMemsetAsync(qloss, 0, 8192 * sizeof(float), stream);
    hipMemsetAsync(count, 0, sizeof(int), stream);
    hipMemsetAsync(table, 0xFF, 16384 * sizeof(unsigned long long), stream);

    // weight splits (inputs only; up front)
    split_kernel<<<32,  256, 0, stream>>>(dec_w1, dw1_hi, dw1_lo, 256 * 128 / 4);
    split_kernel<<<128, 256, 0, stream>>>(dec_w2, dw2_hi, dw2_lo, 512 * 256 / 4);
    split_kernel<<<384, 256, 0, stream>>>(dec_w3, dw3_hi, dw3_lo, 768 * 512 / 4);
    split3_kernel<<<384, 256, 0, stream>>>(enc_w1, ew1_h, ew1_m, ew1_l, 512 * 768 / 4);
    split3_kernel<<<128, 256, 0, stream>>>(enc_w2, ew2_h, ew2_m, ew2_l, 256 * 512 / 4);
    split3_kernel<<<32,  256, 0, stream>>>(enc_w3, ew3_h, ew3_m, ew3_l, 128 * 256 / 4);

    // encoder (exact-split MFMA, fp32-faithful)
    mfma_enc_kernel<512, 768, 1><<<dim3(8, 64), 256, 0, stream>>>(
        x, ew1_h, ew1_m, ew1_l, enc_b1, h1);
    mfma_enc_kernel<256, 512, 1><<<dim3(4, 64), 256, 0, stream>>>(
        h1, ew2_h, ew2_m, ew2_l, enc_b2, h2);
    mfma_enc_kernel<128, 256, 0><<<dim3(2, 64), 256, 0, stream>>>(
        h2, ew3_h, ew3_m, ew3_l, enc_b3, res);
    split_kernel<<<1024, 256, 0, stream>>>(res, res_hi, res_lo, 8192 * 128 / 4);

    // residual quantization layers
    for (int l = 0; l < 3; ++l) {
        proj_split_kernel<<<1024, 128, 0, stream>>>(codebooks + (size_t)l * 8192 * 128,
                                                    projs + (size_t)l * 128 * 128,
                                                    cbp, cbp_hi, cbp_lo, cbn);
        hipMemsetAsync(minkey, 0xFF, 8192 * sizeof(unsigned long long), stream);
        argmin_mfma_kernel<<<dim3(32, 64), 256, 0, stream>>>(res_hi, res_lo,
                                                             cbp_hi, cbp_lo, cbn, minkey);
        finalize_kernel<<<8192, 128, 0, stream>>>(res, cbp, minkey, qloss, z,
                                                  ids, out + 3, keys,
                                                  res_hi, res_lo, l);
    }

    // decoder (split-precision MFMA)
    split_kernel<<<1024, 256, 0, stream>>>(z, z_hi, z_lo, 8192 * 128 / 4);
    mfma_gemm_kernel<256, 128, 1, 0><<<dim3(2, 64), 256, 0, stream>>>(
        z_hi, z_lo, dw1_hi, dw1_lo, dec_b1, g1_hi, g1_lo);
    mfma_gemm_kernel<512, 256, 1, 0><<<dim3(4, 64), 256, 0, stream>>>(
        g1_hi, g1_lo, dw2_hi, dw2_lo, dec_b2, g2_hi, g2_lo);
    mfma_gemm_kernel<768, 512, 2, 1><<<dim3(6, 64), 256, 0, stream>>>(
        g2_hi, g2_lo, dw3_hi, dw3_lo, dec_b3, xhat, nullptr);
    norm_recon_kernel<<<8192, 256, 0, stream>>>(xhat, x, recon_row);

    // diagnostics
    uniq_hash_kernel<<<32, 256, 0, stream>>>(keys, table, count);
    scalars_kernel<<<1, 256, 0, stream>>>(qloss, recon_row, count, out);
}

// Round 5
// 615.318 us; speedup vs baseline: 4.1216x; 1.4792x over previous
//
#include <hip/hip_runtime.h>
#include <hip/hip_bf16.h>
#include <math.h>

// Problem constants
#define B_  8192
#define IN_ 768
#define D_  128
#define K_  8192
#define L_  3

typedef __attribute__((ext_vector_type(8))) short bf16x8;
typedef __attribute__((ext_vector_type(4))) float f32x4;

// ---------------------------------------------------------------------------
// Fragment-major swizzled layout for a [R][C] matrix (R%16==0, C%32==0):
//   off(row,k) = ((row>>4)*(C/32) + (k>>5))*512 + ((k>>3)&3)*128 + (row&15)*8 + (k&7)
// MFMA fragment load (row-tile rt, k-slice s) for lane l is then
//   plane + ((rt*(C/32)+s)<<9) + l*8   -> fully coalesced 16B/lane (bf16)
// Works identically for fp32 planes (element-indexed, 32B/lane in 2x float4).
// ---------------------------------------------------------------------------
__device__ __forceinline__ size_t swz(int row, int col, int C)
{
    return ((size_t)((row >> 4) * (C >> 5) + (col >> 5)) << 9)
         + (((col >> 3) & 3) << 7) + ((row & 15) << 3) + (col & 7);
}

// Split f into hi (bf16 RNE) + lo (bf16 RNE of remainder). ~2^-18 rel error.
__device__ __forceinline__ void split2(float f, unsigned short& h, unsigned short& l)
{
    unsigned u = __float_as_uint(f);
    unsigned hb = (u + 0x7FFFu + ((u >> 16) & 1u)) & 0xFFFF0000u;
    h = (unsigned short)(hb >> 16);
    float r = f - __uint_as_float(hb);
    unsigned v = __float_as_uint(r);
    l = (unsigned short)((v + 0x7FFFu + ((v >> 16) & 1u)) >> 16);
}

// Triple split: f = h + m + l, covers all 24 fp32 mantissa bits (~2^-27).
__device__ __forceinline__ void split3(float f, unsigned short& h,
                                       unsigned short& m, unsigned short& l)
{
    unsigned u = __float_as_uint(f);
    unsigned hb = (u + 0x7FFFu + ((u >> 16) & 1u)) & 0xFFFF0000u;
    h = (unsigned short)(hb >> 16);
    float r1 = f - __uint_as_float(hb);
    unsigned v = __float_as_uint(r1);
    unsigned mb = (v + 0x7FFFu + ((v >> 16) & 1u)) & 0xFFFF0000u;
    m = (unsigned short)(mb >> 16);
    float r2 = r1 - __uint_as_float(mb);
    unsigned w = __float_as_uint(r2);
    l = (unsigned short)((w + 0x7FFFu + ((w >> 16) & 1u)) >> 16);
}

__device__ __forceinline__ unsigned short bf16_rne(float f)
{
    unsigned u = __float_as_uint(f);
    return (unsigned short)((u + 0x7FFFu + ((u >> 16) & 1u)) >> 16);
}

// ---------------------------------------------------------------------------
// Encoder MFMA GEMM, fp32-faithful: C = act(A @ W^T + bias).
// A fp32 (linear if ASWZ=0, swizzled if 1), triple-split in-register; W in 3
// swizzled bf16 planes. 6 MFMA passes -> ~1e-6 rel error (argmin-id safe).
// BM=128 (4 waves x 2 m-tiles), BN=64 (4 n-tiles), K-step 32.
// ACT: 0=none, 1=silu. CSWZ: output fp32 linear(0) / swizzled(1).
// ---------------------------------------------------------------------------
template<int N, int K, int ACT, int ASWZ, int CSWZ>
__global__ __launch_bounds__(256)
void mfma_enc_kernel(const float* __restrict__ A,
                     const unsigned short* __restrict__ Wh,
                     const unsigned short* __restrict__ Wm,
                     const unsigned short* __restrict__ Wl,
                     const float* __restrict__ bias, float* __restrict__ C)
{
    const int tid  = threadIdx.x;
    const int lane = tid & 63;
    const int w    = tid >> 6;
    const int ln   = lane & 15;
    const int grp  = lane >> 4;
    const int m0   = blockIdx.y * 128 + w * 32;
    const int n0   = blockIdx.x * 64;

    f32x4 acc[2][4] = {};

    for (int ks = 0; ks < K; ks += 32) {
        const int s = ks >> 5;
        bf16x8 ah[2], am[2], al[2];
        #pragma unroll
        for (int mt = 0; mt < 2; ++mt) {
            float4 f0, f1;
            if (ASWZ) {
                const size_t base =
                    ((size_t)(((m0 >> 4) + mt) * (K >> 5) + s) << 9) + lane * 8;
                f0 = *(const float4*)&A[base];
                f1 = *(const float4*)&A[base + 4];
            } else {
                const size_t off = (size_t)(m0 + mt * 16 + ln) * K + ks + grp * 8;
                f0 = *(const float4*)&A[off];
                f1 = *(const float4*)&A[off + 4];
            }
            float fv[8] = {f0.x, f0.y, f0.z, f0.w, f1.x, f1.y, f1.z, f1.w};
            #pragma unroll
            for (int e = 0; e < 8; ++e) {
                unsigned short hh, mm, ll;
                split3(fv[e], hh, mm, ll);
                ah[mt][e] = (short)hh;
                am[mt][e] = (short)mm;
                al[mt][e] = (short)ll;
            }
        }
        #pragma unroll
        for (int nt = 0; nt < 4; ++nt) {
            const size_t off =
                ((size_t)(((n0 >> 4) + nt) * (K >> 5) + s) << 9) + lane * 8;
            bf16x8 bh = *(const bf16x8*)&Wh[off];
            bf16x8 bm = *(const bf16x8*)&Wm[off];
            bf16x8 bl = *(const bf16x8*)&Wl[off];
            #pragma unroll
            for (int mt = 0; mt < 2; ++mt) {
                acc[mt][nt] = __builtin_amdgcn_mfma_f32_16x16x32_bf16(ah[mt], bh, acc[mt][nt], 0, 0, 0);
                acc[mt][nt] = __builtin_amdgcn_mfma_f32_16x16x32_bf16(am[mt], bh, acc[mt][nt], 0, 0, 0);
                acc[mt][nt] = __builtin_amdgcn_mfma_f32_16x16x32_bf16(ah[mt], bm, acc[mt][nt], 0, 0, 0);
                acc[mt][nt] = __builtin_amdgcn_mfma_f32_16x16x32_bf16(al[mt], bh, acc[mt][nt], 0, 0, 0);
                acc[mt][nt] = __builtin_amdgcn_mfma_f32_16x16x32_bf16(am[mt], bm, acc[mt][nt], 0, 0, 0);
                acc[mt][nt] = __builtin_amdgcn_mfma_f32_16x16x32_bf16(ah[mt], bl, acc[mt][nt], 0, 0, 0);
            }
        }
    }

    #pragma unroll
    for (int nt = 0; nt < 4; ++nt) {
        const int col = n0 + nt * 16 + ln;
        const float bv = bias[col];
        #pragma unroll
        for (int mt = 0; mt < 2; ++mt) {
            #pragma unroll
            for (int r = 0; r < 4; ++r) {
                const int row = m0 + mt * 16 + grp * 4 + r;
                float v = acc[mt][nt][r] + bv;
                if (ACT == 1) v = v / (1.0f + expf(-v));
                if (CSWZ) C[swz(row, col, N)] = v;
                else      C[(size_t)row * N + col] = v;
            }
        }
    }
}

// ---------------------------------------------------------------------------
// Split-precision MFMA GEMM (decoder): A,W as swizzled bf16 hi/lo planes;
// dot = hh + lh + hl (~2^-17 rel, only affects recon/loss, ~2% tolerance).
// BM=128, BN=128, K-step 32. ACT: 1=silu, 2=sigmoid.
// OUT: 0=swizzled bf16 hi/lo pair, 1=linear single bf16.
// ---------------------------------------------------------------------------
template<int N, int K, int ACT, int OUT>
__global__ __launch_bounds__(256)
void mfma_gemm_kernel(const unsigned short* __restrict__ A_hi,
                      const unsigned short* __restrict__ A_lo,
                      const unsigned short* __restrict__ W_hi,
                      const unsigned short* __restrict__ W_lo,
                      const float* __restrict__ bias,
                      unsigned short* __restrict__ C_hi,
                      unsigned short* __restrict__ C_lo)
{
    const int tid  = threadIdx.x;
    const int lane = tid & 63;
    const int w    = tid >> 6;
    const int ln   = lane & 15;
    const int grp  = lane >> 4;
    const int m0   = blockIdx.y * 128 + w * 32;
    const int n0   = blockIdx.x * 128;

    f32x4 acc[2][8] = {};

    for (int ks = 0; ks < K; ks += 32) {
        const int s = ks >> 5;
        bf16x8 ah[2], al[2];
        #pragma unroll
        for (int mt = 0; mt < 2; ++mt) {
            const size_t off =
                ((size_t)(((m0 >> 4) + mt) * (K >> 5) + s) << 9) + lane * 8;
            ah[mt] = *(const bf16x8*)&A_hi[off];
            al[mt] = *(const bf16x8*)&A_lo[off];
        }
        #pragma unroll
        for (int nt = 0; nt < 8; ++nt) {
            const size_t off =
                ((size_t)(((n0 >> 4) + nt) * (K >> 5) + s) << 9) + lane * 8;
            bf16x8 bh = *(const bf16x8*)&W_hi[off];
            bf16x8 bl = *(const bf16x8*)&W_lo[off];
            #pragma unroll
            for (int mt = 0; mt < 2; ++mt) {
                acc[mt][nt] = __builtin_amdgcn_mfma_f32_16x16x32_bf16(ah[mt], bh, acc[mt][nt], 0, 0, 0);
                acc[mt][nt] = __builtin_amdgcn_mfma_f32_16x16x32_bf16(al[mt], bh, acc[mt][nt], 0, 0, 0);
                acc[mt][nt] = __builtin_amdgcn_mfma_f32_16x16x32_bf16(ah[mt], bl, acc[mt][nt], 0, 0, 0);
            }
        }
    }

    #pragma unroll
    for (int nt = 0; nt < 8; ++nt) {
        const int col = n0 + nt * 16 + ln;
        const float bv = bias[col];
        #pragma unroll
        for (int mt = 0; mt < 2; ++mt) {
            #pragma unroll
            for (int r = 0; r < 4; ++r) {
                const int row = m0 + mt * 16 + grp * 4 + r;
                float v = acc[mt][nt][r] + bv;
                if (ACT == 1) v = v / (1.0f + expf(-v));
                if (ACT == 2) v = 1.0f / (1.0f + expf(-v));
                if (OUT == 0) {
                    unsigned short h, l;
                    split2(v, h, l);
                    const size_t o = swz(row, col, N);
                    C_hi[o] = h;
                    C_lo[o] = l;
                } else {
                    C_hi[(size_t)row * N + col] = bf16_rne(v);
                }
            }
        }
    }
}

// ---------------------------------------------------------------------------
// Per-row L2 normalize + recon partial.
// ---------------------------------------------------------------------------
__global__ __launch_bounds__(256)
void norm_recon_kernel(const unsigned short* __restrict__ xhat,
                       const float* __restrict__ x,
                       float* __restrict__ recon_row)
{
    const int b = blockIdx.x;
    const int tid = threadIdx.x;
    __shared__ float ws[4];
    __shared__ float nrm_s;

    float v[3];
    float ss = 0.0f;
    #pragma unroll
    for (int c = 0; c < 3; ++c) {
        unsigned short u = xhat[(size_t)b * 768 + tid + c * 256];
        v[c] = __uint_as_float((unsigned)u << 16);
        ss += v[c] * v[c];
    }
    for (int off = 32; off > 0; off >>= 1) ss += __shfl_down(ss, off, 64);
    if ((tid & 63) == 0) ws[tid >> 6] = ss;
    __syncthreads();
    if (tid == 0) nrm_s = fmaxf(sqrtf(ws[0] + ws[1] + ws[2] + ws[3]), 1e-12f);
    __syncthreads();
    const float inv = 1.0f / nrm_s;
    float ra = 0.0f;
    #pragma unroll
    for (int c = 0; c < 3; ++c) {
        float dx = v[c] * inv - x[(size_t)b * 768 + tid + c * 256];
        ra += dx * dx;
    }
    for (int off = 32; off > 0; off >>= 1) ra += __shfl_down(ra, off, 64);
    if ((tid & 63) == 0) ws[tid >> 6] = ra;
    __syncthreads();
    if (tid == 0) recon_row[b] = ws[0] + ws[1] + ws[2] + ws[3];
}

// ---------------------------------------------------------------------------
// Projected codebook: cbp fp32 linear + swizzled bf16 hi/lo planes + norms.
// ---------------------------------------------------------------------------
__global__ __launch_bounds__(128)
void proj_split_kernel(const float* __restrict__ cbl, const float* __restrict__ projl,
                       float* __restrict__ cbp, unsigned short* __restrict__ cbp_hi,
                       unsigned short* __restrict__ cbp_lo, float* __restrict__ cbn)
{
    __shared__ float cbs[8][128];
    __shared__ float wsum[8][2];
    const int tid = threadIdx.x;          // = d
    const int k0 = blockIdx.x * 8;

    #pragma unroll
    for (int i = 0; i < 2; ++i) {
        int idx4 = tid + i * 128;
        int r = idx4 >> 5, c4 = (idx4 & 31) * 4;
        *(float4*)&cbs[r][c4] = *(const float4*)&cbl[(size_t)(k0 + r) * 128 + c4];
    }
    __syncthreads();

    float acc[8] = {};
    for (int j4 = 0; j4 < 32; ++j4) {
        float4 pv = *(const float4*)&projl[(size_t)tid * 128 + j4 * 4];
        #pragma unroll
        for (int r = 0; r < 8; ++r) {
            float4 cv = *(float4*)&cbs[r][j4 * 4];
            acc[r] += pv.x * cv.x + pv.y * cv.y + pv.z * cv.z + pv.w * cv.w;
        }
    }
    #pragma unroll
    for (int r = 0; r < 8; ++r) {
        cbp[(size_t)(k0 + r) * 128 + tid] = acc[r];
        unsigned short h, l;
        split2(acc[r], h, l);
        const size_t o = swz(k0 + r, tid, 128);
        cbp_hi[o] = h;
        cbp_lo[o] = l;
        float v = acc[r] * acc[r];
        #pragma unroll
        for (int off = 32; off > 0; off >>= 1) v += __shfl_down(v, off, 64);
        if ((tid & 63) == 0) wsum[r][tid >> 6] = v;
    }
    __syncthreads();
    if (tid < 8) cbn[k0 + tid] = wsum[tid][0] + wsum[tid][1];
}

// ---------------------------------------------------------------------------
// [8192][128] fp32 (linear) -> swizzled bf16 hi/lo planes (res, z).
// ---------------------------------------------------------------------------
__global__ __launch_bounds__(128)
void split_swz_kernel(const float* __restrict__ src,
                      unsigned short* __restrict__ hi,
                      unsigned short* __restrict__ lo)
{
    const int b = blockIdx.x;
    const int tid = threadIdx.x;
    unsigned short h, l;
    split2(src[(size_t)b * 128 + tid], h, l);
    const size_t o = swz(b, tid, 128);
    hi[o] = h;
    lo[o] = l;
}

// ---------------------------------------------------------------------------
// Weight [NR][KC] fp32 -> 2 or 3 swizzled bf16 planes.
// ---------------------------------------------------------------------------
template<int NR, int KC>
__global__ __launch_bounds__(256)
void splitw2_swz_kernel(const float* __restrict__ src,
                        unsigned short* __restrict__ hi,
                        unsigned short* __restrict__ lo)
{
    const int idx = blockIdx.x * 256 + threadIdx.x;
    if (idx >= NR * KC) return;
    unsigned short h, l;
    split2(src[idx], h, l);
    const size_t o = swz(idx / KC, idx % KC, KC);
    hi[o] = h;
    lo[o] = l;
}

template<int NR, int KC>
__global__ __launch_bounds__(256)
void splitw3_swz_kernel(const float* __restrict__ src,
                        unsigned short* __restrict__ hi,
                        unsigned short* __restrict__ mi,
                        unsigned short* __restrict__ lo)
{
    const int idx = blockIdx.x * 256 + threadIdx.x;
    if (idx >= NR * KC) return;
    unsigned short h, m, l;
    split3(src[idx], h, m, l);
    const size_t o = swz(idx / KC, idx % KC, KC);
    hi[o] = h;
    mi[o] = m;
    lo[o] = l;
}

// ---------------------------------------------------------------------------
// MFMA distance argmin (swizzled planes; ids bit-identical to numpy).
// ---------------------------------------------------------------------------
__device__ __forceinline__ unsigned int fkey(float s) {
    unsigned int u = __float_as_uint(s);
    return (u & 0x80000000u) ? ~u : (u | 0x80000000u);
}

__global__ __launch_bounds__(256)
void argmin_mfma_kernel(const unsigned short* __restrict__ res_hi,
                        const unsigned short* __restrict__ res_lo,
                        const unsigned short* __restrict__ cbp_hi,
                        const unsigned short* __restrict__ cbp_lo,
                        const float* __restrict__ cbn,
                        unsigned long long* __restrict__ minkey)
{
    const int tid  = threadIdx.x;
    const int lane = tid & 63;
    const int w    = tid >> 6;
    const int ln   = lane & 15;
    const int grp  = lane >> 4;
    const int m0   = blockIdx.y * 128 + w * 32;
    const int c0b  = blockIdx.x * 256;

    bf16x8 a_hi[2][4], a_lo[2][4];
    #pragma unroll
    for (int mt = 0; mt < 2; ++mt) {
        #pragma unroll
        for (int s = 0; s < 4; ++s) {
            const size_t off =
                ((size_t)(((m0 >> 4) + mt) * 4 + s) << 9) + lane * 8;
            a_hi[mt][s] = *(const bf16x8*)&res_hi[off];
            a_lo[mt][s] = *(const bf16x8*)&res_lo[off];
        }
    }

    unsigned long long best[2][4];
    #pragma unroll
    for (int mt = 0; mt < 2; ++mt)
        #pragma unroll
        for (int r = 0; r < 4; ++r) best[mt][r] = ~0ULL;

    for (int it = 0; it < 4; ++it) {
        const int c0 = c0b + it * 64;
        f32x4 acc[2][4] = {};
        #pragma unroll
        for (int s = 0; s < 4; ++s) {
            #pragma unroll
            for (int t = 0; t < 4; ++t) {
                const size_t off =
                    ((size_t)(((c0 >> 4) + t) * 4 + s) << 9) + lane * 8;
                bf16x8 bh = *(const bf16x8*)&cbp_hi[off];
                bf16x8 bl = *(const bf16x8*)&cbp_lo[off];
                #pragma unroll
                for (int mt = 0; mt < 2; ++mt) {
                    acc[mt][t] = __builtin_amdgcn_mfma_f32_16x16x32_bf16(a_hi[mt][s], bh, acc[mt][t], 0, 0, 0);
                    acc[mt][t] = __builtin_amdgcn_mfma_f32_16x16x32_bf16(a_lo[mt][s], bh, acc[mt][t], 0, 0, 0);
                    acc[mt][t] = __builtin_amdgcn_mfma_f32_16x16x32_bf16(a_hi[mt][s], bl, acc[mt][t], 0, 0, 0);
                }
            }
        }
        #pragma unroll
        for (int t = 0; t < 4; ++t) {
            const int col = c0 + t * 16 + ln;
            const float cn = cbn[col];
            #pragma unroll
            for (int mt = 0; mt < 2; ++mt)
                #pragma unroll
                for (int r = 0; r < 4; ++r) {
                    float sc = cn - 2.0f * acc[mt][t][r];
                    unsigned long long key =
                        ((unsigned long long)fkey(sc) << 32) | (unsigned int)col;
                    if (key < best[mt][r]) best[mt][r] = key;
                }
        }
    }

    #pragma unroll
    for (int mt = 0; mt < 2; ++mt)
        #pragma unroll
        for (int r = 0; r < 4; ++r) {
            unsigned long long b = best[mt][r];
            #pragma unroll
            for (int off = 1; off < 16; off <<= 1) {
                unsigned lo32 = (unsigned)b, hi32 = (unsigned)(b >> 32);
                lo32 = __shfl_xor(lo32, off);
                hi32 = __shfl_xor(hi32, off);
                unsigned long long o = ((unsigned long long)hi32 << 32) | lo32;
                if (o < b) b = o;
            }
            if (ln == 0) atomicMin(&minkey[m0 + mt * 16 + grp * 4 + r], b);
        }
}

// ---------------------------------------------------------------------------
// Per-layer epilogue (res_hi/res_lo written swizzled).
// ---------------------------------------------------------------------------
__global__ __launch_bounds__(128)
void finalize_kernel(float* __restrict__ res, const float* __restrict__ cbp,
                     const unsigned long long* __restrict__ minkey,
                     float* __restrict__ qloss, float* __restrict__ z,
                     int* __restrict__ ids, float* __restrict__ embs_norm_out,
                     unsigned long long* __restrict__ keys,
                     unsigned short* __restrict__ res_hi,
                     unsigned short* __restrict__ res_lo, int layer)
{
    const int b = blockIdx.x;
    const int tid = threadIdx.x;
    const int id = (int)(minkey[b] & 0xFFFFFFFFull);
    float e = cbp[(size_t)id * 128 + tid];
    float r = res[(size_t)b * 128 + tid];
    float d = r - e;
    float v1 = d * d, v2 = e * e;
    for (int off = 32; off > 0; off >>= 1) {
        v1 += __shfl_down(v1, off, 64);
        v2 += __shfl_down(v2, off, 64);
    }
    __shared__ float ws[4];
    if ((tid & 63) == 0) { ws[(tid >> 6) * 2] = v1; ws[(tid >> 6) * 2 + 1] = v2; }
    __syncthreads();
    if (tid == 0) {
        float d2 = ws[0] + ws[2];
        float n2 = ws[1] + ws[3];
        qloss[b] += 1.25f * d2;                 // emb_loss + 0.25*query_loss
        embs_norm_out[b * 3 + layer] = sqrtf(n2);
        ids[b * 3 + layer] = id;
        if (layer == 2) {
            keys[b] = (unsigned long long)ids[b * 3 + 0]
                    | ((unsigned long long)ids[b * 3 + 1] << 13)
                    | ((unsigned long long)id << 26);
        }
    }
    z[(size_t)b * 128 + tid] += e;
    float nr = r - e;
    res[(size_t)b * 128 + tid] = nr;
    unsigned short h, l;
    split2(nr, h, l);
    const size_t o = swz(b, tid, 128);
    res_hi[o] = h;
    res_lo[o] = l;
}

// ---------------------------------------------------------------------------
// Distinct-triple count via open-addressing hash set (= reference's count of
// rows with no later duplicate). atomicCAS insert, deterministic.
// ---------------------------------------------------------------------------
__global__ __launch_bounds__(256)
void uniq_hash_kernel(const unsigned long long* __restrict__ keys,
                      unsigned long long* __restrict__ table,
                      int* __restrict__ count)
{
    const int i = blockIdx.x * 256 + threadIdx.x;
    const unsigned long long k = keys[i];
    unsigned h = (unsigned)((k * 0x9E3779B97F4A7C15ull) >> 50);   // 14 bits
    while (true) {
        unsigned long long old = atomicCAS(&table[h], ~0ULL, k);
        if (old == ~0ULL) { atomicAdd(count, 1); break; }   // first insert
        if (old == k) break;                                // duplicate
        h = (h + 1) & 16383;
    }
}

// ---------------------------------------------------------------------------
// Final scalars.
// ---------------------------------------------------------------------------
__global__ __launch_bounds__(256)
void scalars_kernel(const float* __restrict__ qloss,
                    const float* __restrict__ recon_row,
                    const int* __restrict__ count, float* __restrict__ out)
{
    const int tid = threadIdx.x;
    float qs = 0.0f, rs = 0.0f;
    for (int i = tid; i < 8192; i += 256) qs += qloss[i];
    for (int i = tid; i < 8192; i += 256) rs += recon_row[i];
    for (int off = 32; off > 0; off >>= 1) {
        qs += __shfl_down(qs, off, 64);
        rs += __shfl_down(rs, off, 64);
    }
    __shared__ float w[8];
    if ((tid & 63) == 0) { w[(tid >> 6) * 2] = qs; w[(tid >> 6) * 2 + 1] = rs; }
    __syncthreads();
    if (tid == 0) {
        float qsum = w[0] + w[2] + w[4] + w[6];
        float rsum = w[1] + w[3] + w[5] + w[7];
        float qmean = qsum / 8192.0f;
        out[0] = rsum + qmean;        // loss = (recon + qloss).mean()
        out[1] = rsum;                // recon
        out[2] = qmean;               // qloss.mean()
        out[24579] = (float)(*count) / 8192.0f;   // p_unique
    }
}

// ---------------------------------------------------------------------------
extern "C" void kernel_launch(void* const* d_in, const int* in_sizes, int n_in,
                              void* d_out, int out_size, void* d_ws, size_t ws_size,
                              hipStream_t stream)
{
    const float* x      = (const float*)d_in[0];
    const float* enc_w1 = (const float*)d_in[1];
    const float* enc_b1 = (const float*)d_in[2];
    const float* enc_w2 = (const float*)d_in[3];
    const float* enc_b2 = (const float*)d_in[4];
    const float* enc_w3 = (const float*)d_in[5];
    const float* enc_b3 = (const float*)d_in[6];
    const float* dec_w1 = (const float*)d_in[7];
    const float* dec_b1 = (const float*)d_in[8];
    const float* dec_w2 = (const float*)d_in[9];
    const float* dec_b2 = (const float*)d_in[10];
    const float* dec_w3 = (const float*)d_in[11];
    const float* dec_b3 = (const float*)d_in[12];
    const float* codebooks = (const float*)d_in[13];
    const float* projs     = (const float*)d_in[14];
    float* out = (float*)d_out;

    char* ws = (char*)d_ws;
    const size_t MB = 1024 * 1024;

    // --- region [0, 16M): encoder h1 f32 (swz) ; decoder g2_hi/g2_lo (swz)
    float* h1 = (float*)ws;                                        // 8192x512 f32
    unsigned short* g2_hi = (unsigned short*)ws;                   // 8192x512 bf16
    unsigned short* g2_lo = (unsigned short*)(ws + 8 * MB);
    // --- region [16M, 24M): encoder h2 f32 (swz) ; quant splits ; dec g1 (swz)
    float* h2 = (float*)(ws + 16 * MB);                            // 8192x256 f32
    unsigned short* res_hi = (unsigned short*)(ws + 16 * MB);      // 8192x128
    unsigned short* res_lo = (unsigned short*)(ws + 18 * MB);
    unsigned short* cbp_hi = (unsigned short*)(ws + 20 * MB);
    unsigned short* cbp_lo = (unsigned short*)(ws + 22 * MB);
    unsigned short* g1_hi  = (unsigned short*)(ws + 16 * MB);      // 8192x256 (decoder)
    unsigned short* g1_lo  = (unsigned short*)(ws + 20 * MB);
    // --- region [24M, 28M): res f32 (linear)
    float* res = (float*)(ws + 24 * MB);                           // 8192x128 f32
    // --- region [28M, 32M): cbp f32 (linear) ; decoder z_hi/z_lo (swz)
    float* cbp = (float*)(ws + 28 * MB);                           // 8192x128 f32
    unsigned short* z_hi = (unsigned short*)(ws + 28 * MB);        // 8192x128
    unsigned short* z_lo = (unsigned short*)(ws + 30 * MB);
    // --- region [32M, 36M): z f32 (linear)
    float* z = (float*)(ws + 32 * MB);                             // 8192x128 f32
    // --- region [36M, ...): weight splits (all swz) + small buffers
    char* p = ws + 36 * MB;
    unsigned short* dw1_hi = (unsigned short*)p; p += 256 * 128 * 2;
    unsigned short* dw1_lo = (unsigned short*)p; p += 256 * 128 * 2;
    unsigned short* dw2_hi = (unsigned short*)p; p += 512 * 256 * 2;
    unsigned short* dw2_lo = (unsigned short*)p; p += 512 * 256 * 2;
    unsigned short* dw3_hi = (unsigned short*)p; p += 768 * 512 * 2;
    unsigned short* dw3_lo = (unsigned short*)p; p += 768 * 512 * 2;
    unsigned short* ew1_h  = (unsigned short*)p; p += 512 * 768 * 2;
    unsigned short* ew1_m  = (unsigned short*)p; p += 512 * 768 * 2;
    unsigned short* ew1_l  = (unsigned short*)p; p += 512 * 768 * 2;
    unsigned short* ew2_h  = (unsigned short*)p; p += 256 * 512 * 2;
    unsigned short* ew2_m  = (unsigned short*)p; p += 256 * 512 * 2;
    unsigned short* ew2_l  = (unsigned short*)p; p += 256 * 512 * 2;
    unsigned short* ew3_h  = (unsigned short*)p; p += 128 * 256 * 2;
    unsigned short* ew3_m  = (unsigned short*)p; p += 128 * 256 * 2;
    unsigned short* ew3_l  = (unsigned short*)p; p += 128 * 256 * 2;
    float* cbn       = (float*)p; p += 8192 * 4;
    float* qloss     = (float*)p; p += 8192 * 4;
    float* recon_row = (float*)p; p += 8192 * 4;
    unsigned long long* minkey = (unsigned long long*)p; p += 8192 * 8;
    unsigned long long* keys   = (unsigned long long*)p; p += 8192 * 8;
    unsigned long long* table  = (unsigned long long*)p; p += 16384 * 8;
    int* ids   = (int*)p; p += 8192 * 3 * 4;
    int* count = (int*)p; p += 256;                      // pad to alignment
    unsigned short* xhat = (unsigned short*)p;           // 8192x768 bf16 (12 MB)

    hipMemsetAsync(z, 0, (size_t)8192 * 128 * sizeof(float), stream);
    hipMemsetAsync(qloss, 0, 8192 * sizeof(float), stream);
    hipMemsetAsync(count, 0, sizeof(int), stream);
    hipMemsetAsync(table, 0xFF, 16384 * sizeof(unsigned long long), stream);

    // weight splits (inputs only; up front)
    splitw2_swz_kernel<256, 128><<<128, 256, 0, stream>>>(dec_w1, dw1_hi, dw1_lo);
    splitw2_swz_kernel<512, 256><<<512, 256, 0, stream>>>(dec_w2, dw2_hi, dw2_lo);
    splitw2_swz_kernel<768, 512><<<1536, 256, 0, stream>>>(dec_w3, dw3_hi, dw3_lo);
    splitw3_swz_kernel<512, 768><<<1536, 256, 0, stream>>>(enc_w1, ew1_h, ew1_m, ew1_l);
    splitw3_swz_kernel<256, 512><<<512, 256, 0, stream>>>(enc_w2, ew2_h, ew2_m, ew2_l);
    splitw3_swz_kernel<128, 256><<<128, 256, 0, stream>>>(enc_w3, ew3_h, ew3_m, ew3_l);

    // encoder (exact-split MFMA, fp32-faithful); h1/h2 kept in swizzled layout
    mfma_enc_kernel<512, 768, 1, 0, 1><<<dim3(8, 64), 256, 0, stream>>>(
        x, ew1_h, ew1_m, ew1_l, enc_b1, h1);
    mfma_enc_kernel<256, 512, 1, 1, 1><<<dim3(4, 64), 256, 0, stream>>>(
        h1, ew2_h, ew2_m, ew2_l, enc_b2, h2);
    mfma_enc_kernel<128, 256, 0, 1, 0><<<dim3(2, 64), 256, 0, stream>>>(
        h2, ew3_h, ew3_m, ew3_l, enc_b3, res);
    split_swz_kernel<<<8192, 128, 0, stream>>>(res, res_hi, res_lo);

    // residual quantization layers
    for (int l = 0; l < 3; ++l) {
        proj_split_kernel<<<1024, 128, 0, stream>>>(codebooks + (size_t)l * 8192 * 128,
                                                    projs + (size_t)l * 128 * 128,
                                                    cbp, cbp_hi, cbp_lo, cbn);
        hipMemsetAsync(minkey, 0xFF, 8192 * sizeof(unsigned long long), stream);
        argmin_mfma_kernel<<<dim3(32, 64), 256, 0, stream>>>(res_hi, res_lo,
                                                             cbp_hi, cbp_lo, cbn, minkey);
        finalize_kernel<<<8192, 128, 0, stream>>>(res, cbp, minkey, qloss, z,
                                                  ids, out + 3, keys,
                                                  res_hi, res_lo, l);
    }

    // decoder (split-precision MFMA, swizzled planes)
    split_swz_kernel<<<8192, 128, 0, stream>>>(z, z_hi, z_lo);
    mfma_gemm_kernel<256, 128, 1, 0><<<dim3(2, 64), 256, 0, stream>>>(
        z_hi, z_lo, dw1_hi, dw1_lo, dec_b1, g1_hi, g1_lo);
    mfma_gemm_kernel<512, 256, 1, 0><<<dim3(4, 64), 256, 0, stream>>>(
        g1_hi, g1_lo, dw2_hi, dw2_lo, dec_b2, g2_hi, g2_lo);
    mfma_gemm_kernel<768, 512, 2, 1><<<dim3(6, 64), 256, 0, stream>>>(
        g2_hi, g2_lo, dw3_hi, dw3_lo, dec_b3, xhat, nullptr);
    norm_recon_kernel<<<8192, 256, 0, stream>>>(xhat, x, recon_row);

    // diagnostics
    uniq_hash_kernel<<<32, 256, 0, stream>>>(keys, table, count);
    scalars_kernel<<<1, 256, 0, stream>>>(qloss, recon_row, count, out);
}

// Round 6
// 588.903 us; speedup vs baseline: 4.3065x; 1.0449x over previous
//
#include <hip/hip_runtime.h>
#include <hip/hip_bf16.h>
#include <math.h>

// Problem constants
#define B_  8192
#define IN_ 768
#define D_  128
#define K_  8192
#define L_  3

typedef __attribute__((ext_vector_type(8))) short bf16x8;
typedef __attribute__((ext_vector_type(4))) float f32x4;

// ---------------------------------------------------------------------------
// Fragment-major swizzled layout for a [R][C] matrix (R%16==0, C%32==0):
//   off(row,k) = ((row>>4)*(C/32) + (k>>5))*512 + ((k>>3)&3)*128 + (row&15)*8 + (k&7)
// MFMA fragment load (row-tile rt, k-slice s) for lane l is then
//   plane + ((rt*(C/32)+s)<<9) + l*8   -> fully coalesced 16B/lane (bf16).
// ---------------------------------------------------------------------------
__device__ __forceinline__ size_t swz(int row, int col, int C)
{
    return ((size_t)((row >> 4) * (C >> 5) + (col >> 5)) << 9)
         + (((col >> 3) & 3) << 7) + ((row & 15) << 3) + (col & 7);
}

// Split f into hi (bf16 RNE) + lo (bf16 RNE of remainder). ~2^-18 rel error.
__device__ __forceinline__ void split2(float f, unsigned short& h, unsigned short& l)
{
    unsigned u = __float_as_uint(f);
    unsigned hb = (u + 0x7FFFu + ((u >> 16) & 1u)) & 0xFFFF0000u;
    h = (unsigned short)(hb >> 16);
    float r = f - __uint_as_float(hb);
    unsigned v = __float_as_uint(r);
    l = (unsigned short)((v + 0x7FFFu + ((v >> 16) & 1u)) >> 16);
}

// Triple split: f = h + m + l, covers all 24 fp32 mantissa bits (~2^-27).
__device__ __forceinline__ void split3(float f, unsigned short& h,
                                       unsigned short& m, unsigned short& l)
{
    unsigned u = __float_as_uint(f);
    unsigned hb = (u + 0x7FFFu + ((u >> 16) & 1u)) & 0xFFFF0000u;
    h = (unsigned short)(hb >> 16);
    float r1 = f - __uint_as_float(hb);
    unsigned v = __float_as_uint(r1);
    unsigned mb = (v + 0x7FFFu + ((v >> 16) & 1u)) & 0xFFFF0000u;
    m = (unsigned short)(mb >> 16);
    float r2 = r1 - __uint_as_float(mb);
    unsigned w = __float_as_uint(r2);
    l = (unsigned short)((w + 0x7FFFu + ((w >> 16) & 1u)) >> 16);
}

__device__ __forceinline__ unsigned short bf16_rne(float f)
{
    unsigned u = __float_as_uint(f);
    return (unsigned short)((u + 0x7FFFu + ((u >> 16) & 1u)) >> 16);
}

// ---------------------------------------------------------------------------
// Encoder MFMA GEMM, fp32-faithful: C = act(A @ W^T + bias).
// A fp32 (linear if ASWZ=0, swizzled if 1), triple-split in-register; W in 3
// swizzled bf16 planes. 6 MFMA passes -> ~1e-6 rel error (argmin-id safe).
// BM=128 (4 waves x 2 m-tiles), BN=64 (4 n-tiles), K-step 32.
// ACT: 0=none, 1=silu. CSWZ: fp32 out linear(0)/swizzled(1).
// OUT2: additionally write split2 bf16 planes (swz) of the output (enc3).
// ---------------------------------------------------------------------------
template<int N, int K, int ACT, int ASWZ, int CSWZ, int OUT2>
__global__ __launch_bounds__(256)
void mfma_enc_kernel(const float* __restrict__ A,
                     const unsigned short* __restrict__ Wh,
                     const unsigned short* __restrict__ Wm,
                     const unsigned short* __restrict__ Wl,
                     const float* __restrict__ bias, float* __restrict__ C,
                     unsigned short* __restrict__ Rh,
                     unsigned short* __restrict__ Rl)
{
    const int tid  = threadIdx.x;
    const int lane = tid & 63;
    const int w    = tid >> 6;
    const int ln   = lane & 15;
    const int grp  = lane >> 4;
    const int m0   = blockIdx.y * 128 + w * 32;
    const int n0   = blockIdx.x * 64;

    f32x4 acc[2][4] = {};

    for (int ks = 0; ks < K; ks += 32) {
        const int s = ks >> 5;
        bf16x8 ah[2], am[2], al[2];
        #pragma unroll
        for (int mt = 0; mt < 2; ++mt) {
            float4 f0, f1;
            if (ASWZ) {
                const size_t base =
                    ((size_t)(((m0 >> 4) + mt) * (K >> 5) + s) << 9) + lane * 8;
                f0 = *(const float4*)&A[base];
                f1 = *(const float4*)&A[base + 4];
            } else {
                const size_t off = (size_t)(m0 + mt * 16 + ln) * K + ks + grp * 8;
                f0 = *(const float4*)&A[off];
                f1 = *(const float4*)&A[off + 4];
            }
            float fv[8] = {f0.x, f0.y, f0.z, f0.w, f1.x, f1.y, f1.z, f1.w};
            #pragma unroll
            for (int e = 0; e < 8; ++e) {
                unsigned short hh, mm, ll;
                split3(fv[e], hh, mm, ll);
                ah[mt][e] = (short)hh;
                am[mt][e] = (short)mm;
                al[mt][e] = (short)ll;
            }
        }
        #pragma unroll
        for (int nt = 0; nt < 4; ++nt) {
            const size_t off =
                ((size_t)(((n0 >> 4) + nt) * (K >> 5) + s) << 9) + lane * 8;
            bf16x8 bh = *(const bf16x8*)&Wh[off];
            bf16x8 bm = *(const bf16x8*)&Wm[off];
            bf16x8 bl = *(const bf16x8*)&Wl[off];
            #pragma unroll
            for (int mt = 0; mt < 2; ++mt) {
                acc[mt][nt] = __builtin_amdgcn_mfma_f32_16x16x32_bf16(ah[mt], bh, acc[mt][nt], 0, 0, 0);
                acc[mt][nt] = __builtin_amdgcn_mfma_f32_16x16x32_bf16(am[mt], bh, acc[mt][nt], 0, 0, 0);
                acc[mt][nt] = __builtin_amdgcn_mfma_f32_16x16x32_bf16(ah[mt], bm, acc[mt][nt], 0, 0, 0);
                acc[mt][nt] = __builtin_amdgcn_mfma_f32_16x16x32_bf16(al[mt], bh, acc[mt][nt], 0, 0, 0);
                acc[mt][nt] = __builtin_amdgcn_mfma_f32_16x16x32_bf16(am[mt], bm, acc[mt][nt], 0, 0, 0);
                acc[mt][nt] = __builtin_amdgcn_mfma_f32_16x16x32_bf16(ah[mt], bl, acc[mt][nt], 0, 0, 0);
            }
        }
    }

    #pragma unroll
    for (int nt = 0; nt < 4; ++nt) {
        const int col = n0 + nt * 16 + ln;
        const float bv = bias[col];
        #pragma unroll
        for (int mt = 0; mt < 2; ++mt) {
            #pragma unroll
            for (int r = 0; r < 4; ++r) {
                const int row = m0 + mt * 16 + grp * 4 + r;
                float v = acc[mt][nt][r] + bv;
                if (ACT == 1) v = v / (1.0f + expf(-v));
                if (CSWZ) C[swz(row, col, N)] = v;
                else      C[(size_t)row * N + col] = v;
                if (OUT2) {
                    unsigned short h, l;
                    split2(v, h, l);
                    const size_t o = swz(row, col, N);
                    Rh[o] = h;
                    Rl[o] = l;
                }
            }
        }
    }
}

// ---------------------------------------------------------------------------
// Split-precision MFMA GEMM (decoder): A,W as swizzled bf16 hi/lo planes;
// dot = hh + lh + hl (~2^-17 rel, only affects recon/loss, ~2% tolerance).
// BM=128, BN=128, K-step 32. ACT: 1=silu, 2=sigmoid.
// OUT: 0=swizzled bf16 hi/lo pair, 1=linear single bf16.
// ---------------------------------------------------------------------------
template<int N, int K, int ACT, int OUT>
__global__ __launch_bounds__(256)
void mfma_gemm_kernel(const unsigned short* __restrict__ A_hi,
                      const unsigned short* __restrict__ A_lo,
                      const unsigned short* __restrict__ W_hi,
                      const unsigned short* __restrict__ W_lo,
                      const float* __restrict__ bias,
                      unsigned short* __restrict__ C_hi,
                      unsigned short* __restrict__ C_lo)
{
    const int tid  = threadIdx.x;
    const int lane = tid & 63;
    const int w    = tid >> 6;
    const int ln   = lane & 15;
    const int grp  = lane >> 4;
    const int m0   = blockIdx.y * 128 + w * 32;
    const int n0   = blockIdx.x * 128;

    f32x4 acc[2][8] = {};

    for (int ks = 0; ks < K; ks += 32) {
        const int s = ks >> 5;
        bf16x8 ah[2], al[2];
        #pragma unroll
        for (int mt = 0; mt < 2; ++mt) {
            const size_t off =
                ((size_t)(((m0 >> 4) + mt) * (K >> 5) + s) << 9) + lane * 8;
            ah[mt] = *(const bf16x8*)&A_hi[off];
            al[mt] = *(const bf16x8*)&A_lo[off];
        }
        #pragma unroll
        for (int nt = 0; nt < 8; ++nt) {
            const size_t off =
                ((size_t)(((n0 >> 4) + nt) * (K >> 5) + s) << 9) + lane * 8;
            bf16x8 bh = *(const bf16x8*)&W_hi[off];
            bf16x8 bl = *(const bf16x8*)&W_lo[off];
            #pragma unroll
            for (int mt = 0; mt < 2; ++mt) {
                acc[mt][nt] = __builtin_amdgcn_mfma_f32_16x16x32_bf16(ah[mt], bh, acc[mt][nt], 0, 0, 0);
                acc[mt][nt] = __builtin_amdgcn_mfma_f32_16x16x32_bf16(al[mt], bh, acc[mt][nt], 0, 0, 0);
                acc[mt][nt] = __builtin_amdgcn_mfma_f32_16x16x32_bf16(ah[mt], bl, acc[mt][nt], 0, 0, 0);
            }
        }
    }

    #pragma unroll
    for (int nt = 0; nt < 8; ++nt) {
        const int col = n0 + nt * 16 + ln;
        const float bv = bias[col];
        #pragma unroll
        for (int mt = 0; mt < 2; ++mt) {
            #pragma unroll
            for (int r = 0; r < 4; ++r) {
                const int row = m0 + mt * 16 + grp * 4 + r;
                float v = acc[mt][nt][r] + bv;
                if (ACT == 1) v = v / (1.0f + expf(-v));
                if (ACT == 2) v = 1.0f / (1.0f + expf(-v));
                if (OUT == 0) {
                    unsigned short h, l;
                    split2(v, h, l);
                    const size_t o = swz(row, col, N);
                    C_hi[o] = h;
                    C_lo[o] = l;
                } else {
                    C_hi[(size_t)row * N + col] = bf16_rne(v);
                }
            }
        }
    }
}

// ---------------------------------------------------------------------------
// Per-row L2 normalize + recon partial.
// ---------------------------------------------------------------------------
__global__ __launch_bounds__(256)
void norm_recon_kernel(const unsigned short* __restrict__ xhat,
                       const float* __restrict__ x,
                       float* __restrict__ recon_row)
{
    const int b = blockIdx.x;
    const int tid = threadIdx.x;
    __shared__ float ws[4];
    __shared__ float nrm_s;

    float v[3];
    float ss = 0.0f;
    #pragma unroll
    for (int c = 0; c < 3; ++c) {
        unsigned short u = xhat[(size_t)b * 768 + tid + c * 256];
        v[c] = __uint_as_float((unsigned)u << 16);
        ss += v[c] * v[c];
    }
    for (int off = 32; off > 0; off >>= 1) ss += __shfl_down(ss, off, 64);
    if ((tid & 63) == 0) ws[tid >> 6] = ss;
    __syncthreads();
    if (tid == 0) nrm_s = fmaxf(sqrtf(ws[0] + ws[1] + ws[2] + ws[3]), 1e-12f);
    __syncthreads();
    const float inv = 1.0f / nrm_s;
    float ra = 0.0f;
    #pragma unroll
    for (int c = 0; c < 3; ++c) {
        float dx = v[c] * inv - x[(size_t)b * 768 + tid + c * 256];
        ra += dx * dx;
    }
    for (int off = 32; off > 0; off >>= 1) ra += __shfl_down(ra, off, 64);
    if ((tid & 63) == 0) ws[tid >> 6] = ra;
    __syncthreads();
    if (tid == 0) recon_row[b] = ws[0] + ws[1] + ws[2] + ws[3];
}

// ---------------------------------------------------------------------------
// Projected codebook: cbp fp32 linear + swizzled bf16 hi/lo planes + norms.
// ---------------------------------------------------------------------------
__global__ __launch_bounds__(128)
void proj_split_kernel(const float* __restrict__ cbl, const float* __restrict__ projl,
                       float* __restrict__ cbp, unsigned short* __restrict__ cbp_hi,
                       unsigned short* __restrict__ cbp_lo, float* __restrict__ cbn)
{
    __shared__ float cbs[8][128];
    __shared__ float wsum[8][2];
    const int tid = threadIdx.x;          // = d
    const int k0 = blockIdx.x * 8;

    #pragma unroll
    for (int i = 0; i < 2; ++i) {
        int idx4 = tid + i * 128;
        int r = idx4 >> 5, c4 = (idx4 & 31) * 4;
        *(float4*)&cbs[r][c4] = *(const float4*)&cbl[(size_t)(k0 + r) * 128 + c4];
    }
    __syncthreads();

    float acc[8] = {};
    for (int j4 = 0; j4 < 32; ++j4) {
        float4 pv = *(const float4*)&projl[(size_t)tid * 128 + j4 * 4];
        #pragma unroll
        for (int r = 0; r < 8; ++r) {
            float4 cv = *(float4*)&cbs[r][j4 * 4];
            acc[r] += pv.x * cv.x + pv.y * cv.y + pv.z * cv.z + pv.w * cv.w;
        }
    }
    #pragma unroll
    for (int r = 0; r < 8; ++r) {
        cbp[(size_t)(k0 + r) * 128 + tid] = acc[r];
        unsigned short h, l;
        split2(acc[r], h, l);
        const size_t o = swz(k0 + r, tid, 128);
        cbp_hi[o] = h;
        cbp_lo[o] = l;
        float v = acc[r] * acc[r];
        #pragma unroll
        for (int off = 32; off > 0; off >>= 1) v += __shfl_down(v, off, 64);
        if ((tid & 63) == 0) wsum[r][tid >> 6] = v;
    }
    __syncthreads();
    if (tid < 8) cbn[k0 + tid] = wsum[tid][0] + wsum[tid][1];
}

// ---------------------------------------------------------------------------
// Weight [NR][KC] fp32 -> 2 or 3 swizzled bf16 planes.
// ---------------------------------------------------------------------------
template<int NR, int KC>
__global__ __launch_bounds__(256)
void splitw2_swz_kernel(const float* __restrict__ src,
                        unsigned short* __restrict__ hi,
                        unsigned short* __restrict__ lo)
{
    const int idx = blockIdx.x * 256 + threadIdx.x;
    if (idx >= NR * KC) return;
    unsigned short h, l;
    split2(src[idx], h, l);
    const size_t o = swz(idx / KC, idx % KC, KC);
    hi[o] = h;
    lo[o] = l;
}

template<int NR, int KC>
__global__ __launch_bounds__(256)
void splitw3_swz_kernel(const float* __restrict__ src,
                        unsigned short* __restrict__ hi,
                        unsigned short* __restrict__ mi,
                        unsigned short* __restrict__ lo)
{
    const int idx = blockIdx.x * 256 + threadIdx.x;
    if (idx >= NR * KC) return;
    unsigned short h, m, l;
    split3(src[idx], h, m, l);
    const size_t o = swz(idx / KC, idx % KC, KC);
    hi[o] = h;
    mi[o] = m;
    lo[o] = l;
}

// ---------------------------------------------------------------------------
// MFMA distance argmin (swizzled planes; ids bit-identical to numpy).
// Per-lane running (best_s, best_c) with STRICT < compare: each lane visits
// its columns in increasing order, so strict < == numpy first-index
// tie-break. The fkey/u64 pack happens once per result at the end (cross-lane
// and cross-block tie-break via packed key, as before).
// ---------------------------------------------------------------------------
__device__ __forceinline__ unsigned int fkey(float s) {
    unsigned int u = __float_as_uint(s);
    return (u & 0x80000000u) ? ~u : (u | 0x80000000u);
}

__global__ __launch_bounds__(256)
void argmin_mfma_kernel(const unsigned short* __restrict__ res_hi,
                        const unsigned short* __restrict__ res_lo,
                        const unsigned short* __restrict__ cbp_hi,
                        const unsigned short* __restrict__ cbp_lo,
                        const float* __restrict__ cbn,
                        unsigned long long* __restrict__ minkey)
{
    const int tid  = threadIdx.x;
    const int lane = tid & 63;
    const int w    = tid >> 6;
    const int ln   = lane & 15;
    const int grp  = lane >> 4;
    const int m0   = blockIdx.y * 128 + w * 32;
    const int c0b  = blockIdx.x * 256;

    bf16x8 a_hi[2][4], a_lo[2][4];
    #pragma unroll
    for (int mt = 0; mt < 2; ++mt) {
        #pragma unroll
        for (int s = 0; s < 4; ++s) {
            const size_t off =
                ((size_t)(((m0 >> 4) + mt) * 4 + s) << 9) + lane * 8;
            a_hi[mt][s] = *(const bf16x8*)&res_hi[off];
            a_lo[mt][s] = *(const bf16x8*)&res_lo[off];
        }
    }

    float best_s[2][4];
    int   best_c[2][4];
    #pragma unroll
    for (int mt = 0; mt < 2; ++mt)
        #pragma unroll
        for (int r = 0; r < 4; ++r) { best_s[mt][r] = 3.4e38f; best_c[mt][r] = 0; }

    for (int it = 0; it < 4; ++it) {
        const int c0 = c0b + it * 64;
        f32x4 acc[2][4] = {};
        #pragma unroll
        for (int s = 0; s < 4; ++s) {
            #pragma unroll
            for (int t = 0; t < 4; ++t) {
                const size_t off =
                    ((size_t)(((c0 >> 4) + t) * 4 + s) << 9) + lane * 8;
                bf16x8 bh = *(const bf16x8*)&cbp_hi[off];
                bf16x8 bl = *(const bf16x8*)&cbp_lo[off];
                #pragma unroll
                for (int mt = 0; mt < 2; ++mt) {
                    acc[mt][t] = __builtin_amdgcn_mfma_f32_16x16x32_bf16(a_hi[mt][s], bh, acc[mt][t], 0, 0, 0);
                    acc[mt][t] = __builtin_amdgcn_mfma_f32_16x16x32_bf16(a_lo[mt][s], bh, acc[mt][t], 0, 0, 0);
                    acc[mt][t] = __builtin_amdgcn_mfma_f32_16x16x32_bf16(a_hi[mt][s], bl, acc[mt][t], 0, 0, 0);
                }
            }
        }
        #pragma unroll
        for (int t = 0; t < 4; ++t) {
            const int col = c0 + t * 16 + ln;
            const float cn = cbn[col];
            #pragma unroll
            for (int mt = 0; mt < 2; ++mt)
                #pragma unroll
                for (int r = 0; r < 4; ++r) {
                    // == cn - 2*acc exactly (x2 is exact), matches prior rounds
                    float sc = fmaf(-2.0f, acc[mt][t][r], cn);
                    if (sc < best_s[mt][r]) {        // strict <: first col wins ties
                        best_s[mt][r] = sc;
                        best_c[mt][r] = col;
                    }
                }
        }
    }

    #pragma unroll
    for (int mt = 0; mt < 2; ++mt)
        #pragma unroll
        for (int r = 0; r < 4; ++r) {
            unsigned long long b =
                ((unsigned long long)fkey(best_s[mt][r]) << 32)
                | (unsigned int)best_c[mt][r];
            #pragma unroll
            for (int off = 1; off < 16; off <<= 1) {
                unsigned lo32 = (unsigned)b, hi32 = (unsigned)(b >> 32);
                lo32 = __shfl_xor(lo32, off);
                hi32 = __shfl_xor(hi32, off);
                unsigned long long o = ((unsigned long long)hi32 << 32) | lo32;
                if (o < b) b = o;
            }
            if (ln == 0) atomicMin(&minkey[m0 + mt * 16 + grp * 4 + r], b);
        }
}

// ---------------------------------------------------------------------------
// Per-layer epilogue (res planes written swizzled; layer 2 also emits z planes).
// ---------------------------------------------------------------------------
__global__ __launch_bounds__(128)
void finalize_kernel(float* __restrict__ res, const float* __restrict__ cbp,
                     const unsigned long long* __restrict__ minkey,
                     float* __restrict__ qloss, float* __restrict__ z,
                     int* __restrict__ ids, float* __restrict__ embs_norm_out,
                     unsigned long long* __restrict__ keys,
                     unsigned short* __restrict__ res_hi,
                     unsigned short* __restrict__ res_lo,
                     unsigned short* __restrict__ z_hi,
                     unsigned short* __restrict__ z_lo, int layer)
{
    const int b = blockIdx.x;
    const int tid = threadIdx.x;
    const int id = (int)(minkey[b] & 0xFFFFFFFFull);
    float e = cbp[(size_t)id * 128 + tid];
    float r = res[(size_t)b * 128 + tid];
    float d = r - e;
    float v1 = d * d, v2 = e * e;
    for (int off = 32; off > 0; off >>= 1) {
        v1 += __shfl_down(v1, off, 64);
        v2 += __shfl_down(v2, off, 64);
    }
    __shared__ float ws[4];
    if ((tid & 63) == 0) { ws[(tid >> 6) * 2] = v1; ws[(tid >> 6) * 2 + 1] = v2; }
    __syncthreads();
    if (tid == 0) {
        float d2 = ws[0] + ws[2];
        float n2 = ws[1] + ws[3];
        qloss[b] += 1.25f * d2;                 // emb_loss + 0.25*query_loss
        embs_norm_out[b * 3 + layer] = sqrtf(n2);
        ids[b * 3 + layer] = id;
        if (layer == 2) {
            keys[b] = (unsigned long long)ids[b * 3 + 0]
                    | ((unsigned long long)ids[b * 3 + 1] << 13)
                    | ((unsigned long long)id << 26);
        }
    }
    float nz = z[(size_t)b * 128 + tid] + e;
    z[(size_t)b * 128 + tid] = nz;
    const size_t o = swz(b, tid, 128);
    if (layer == 2) {
        unsigned short zh, zl;
        split2(nz, zh, zl);
        z_hi[o] = zh;
        z_lo[o] = zl;
    }
    float nr = r - e;
    res[(size_t)b * 128 + tid] = nr;
    unsigned short h, l;
    split2(nr, h, l);
    res_hi[o] = h;
    res_lo[o] = l;
}

// ---------------------------------------------------------------------------
// Distinct-triple count via open-addressing hash set (= reference's count of
// rows with no later duplicate). atomicCAS insert, deterministic.
// ---------------------------------------------------------------------------
__global__ __launch_bounds__(256)
void uniq_hash_kernel(const unsigned long long* __restrict__ keys,
                      unsigned long long* __restrict__ table,
                      int* __restrict__ count)
{
    const int i = blockIdx.x * 256 + threadIdx.x;
    const unsigned long long k = keys[i];
    unsigned h = (unsigned)((k * 0x9E3779B97F4A7C15ull) >> 50);   // 14 bits
    while (true) {
        unsigned long long old = atomicCAS(&table[h], ~0ULL, k);
        if (old == ~0ULL) { atomicAdd(count, 1); break; }   // first insert
        if (old == k) break;                                // duplicate
        h = (h + 1) & 16383;
    }
}

// ---------------------------------------------------------------------------
// Final scalars.
// ---------------------------------------------------------------------------
__global__ __launch_bounds__(256)
void scalars_kernel(const float* __restrict__ qloss,
                    const float* __restrict__ recon_row,
                    const int* __restrict__ count, float* __restrict__ out)
{
    const int tid = threadIdx.x;
    float qs = 0.0f, rs = 0.0f;
    for (int i = tid; i < 8192; i += 256) qs += qloss[i];
    for (int i = tid; i < 8192; i += 256) rs += recon_row[i];
    for (int off = 32; off > 0; off >>= 1) {
        qs += __shfl_down(qs, off, 64);
        rs += __shfl_down(rs, off, 64);
    }
    __shared__ float w[8];
    if ((tid & 63) == 0) { w[(tid >> 6) * 2] = qs; w[(tid >> 6) * 2 + 1] = rs; }
    __syncthreads();
    if (tid == 0) {
        float qsum = w[0] + w[2] + w[4] + w[6];
        float rsum = w[1] + w[3] + w[5] + w[7];
        float qmean = qsum / 8192.0f;
        out[0] = rsum + qmean;        // loss = (recon + qloss).mean()
        out[1] = rsum;                // recon
        out[2] = qmean;               // qloss.mean()
        out[24579] = (float)(*count) / 8192.0f;   // p_unique
    }
}

// ---------------------------------------------------------------------------
extern "C" void kernel_launch(void* const* d_in, const int* in_sizes, int n_in,
                              void* d_out, int out_size, void* d_ws, size_t ws_size,
                              hipStream_t stream)
{
    const float* x      = (const float*)d_in[0];
    const float* enc_w1 = (const float*)d_in[1];
    const float* enc_b1 = (const float*)d_in[2];
    const float* enc_w2 = (const float*)d_in[3];
    const float* enc_b2 = (const float*)d_in[4];
    const float* enc_w3 = (const float*)d_in[5];
    const float* enc_b3 = (const float*)d_in[6];
    const float* dec_w1 = (const float*)d_in[7];
    const float* dec_b1 = (const float*)d_in[8];
    const float* dec_w2 = (const float*)d_in[9];
    const float* dec_b2 = (const float*)d_in[10];
    const float* dec_w3 = (const float*)d_in[11];
    const float* dec_b3 = (const float*)d_in[12];
    const float* codebooks = (const float*)d_in[13];
    const float* projs     = (const float*)d_in[14];
    float* out = (float*)d_out;

    char* ws = (char*)d_ws;
    const size_t MB = 1024 * 1024;

    // --- region [0, 16M): encoder h1 f32 (swz) ; decoder g2_hi/g2_lo (swz)
    float* h1 = (float*)ws;                                        // 8192x512 f32
    unsigned short* g2_hi = (unsigned short*)ws;                   // 8192x512 bf16
    unsigned short* g2_lo = (unsigned short*)(ws + 8 * MB);
    // --- region [16M, 24M): encoder h2 f32 (swz) ; quant splits ; dec g1 (swz)
    float* h2 = (float*)(ws + 16 * MB);                            // 8192x256 f32
    unsigned short* res_hi = (unsigned short*)(ws + 16 * MB);      // 8192x128
    unsigned short* res_lo = (unsigned short*)(ws + 18 * MB);
    unsigned short* cbp_hi = (unsigned short*)(ws + 20 * MB);
    unsigned short* cbp_lo = (unsigned short*)(ws + 22 * MB);
    unsigned short* g1_hi  = (unsigned short*)(ws + 16 * MB);      // 8192x256 (decoder)
    unsigned short* g1_lo  = (unsigned short*)(ws + 20 * MB);
    // --- region [24M, 28M): res f32 (linear)
    float* res = (float*)(ws + 24 * MB);                           // 8192x128 f32
    // --- region [28M, 32M): cbp f32 (linear) ; decoder z_hi/z_lo (swz)
    float* cbp = (float*)(ws + 28 * MB);                           // 8192x128 f32
    unsigned short* z_hi = (unsigned short*)(ws + 28 * MB);        // 8192x128
    unsigned short* z_lo = (unsigned short*)(ws + 30 * MB);
    // --- region [32M, 36M): z f32 (linear)
    float* z = (float*)(ws + 32 * MB);                             // 8192x128 f32
    // --- region [36M, ...): weight splits (all swz) + small buffers
    char* p = ws + 36 * MB;
    unsigned short* dw1_hi = (unsigned short*)p; p += 256 * 128 * 2;
    unsigned short* dw1_lo = (unsigned short*)p; p += 256 * 128 * 2;
    unsigned short* dw2_hi = (unsigned short*)p; p += 512 * 256 * 2;
    unsigned short* dw2_lo = (unsigned short*)p; p += 512 * 256 * 2;
    unsigned short* dw3_hi = (unsigned short*)p; p += 768 * 512 * 2;
    unsigned short* dw3_lo = (unsigned short*)p; p += 768 * 512 * 2;
    unsigned short* ew1_h  = (unsigned short*)p; p += 512 * 768 * 2;
    unsigned short* ew1_m  = (unsigned short*)p; p += 512 * 768 * 2;
    unsigned short* ew1_l  = (unsigned short*)p; p += 512 * 768 * 2;
    unsigned short* ew2_h  = (unsigned short*)p; p += 256 * 512 * 2;
    unsigned short* ew2_m  = (unsigned short*)p; p += 256 * 512 * 2;
    unsigned short* ew2_l  = (unsigned short*)p; p += 256 * 512 * 2;
    unsigned short* ew3_h  = (unsigned short*)p; p += 128 * 256 * 2;
    unsigned short* ew3_m  = (unsigned short*)p; p += 128 * 256 * 2;
    unsigned short* ew3_l  = (unsigned short*)p; p += 128 * 256 * 2;
    float* cbn       = (float*)p; p += 8192 * 4;
    float* qloss     = (float*)p; p += 8192 * 4;
    float* recon_row = (float*)p; p += 8192 * 4;
    unsigned long long* minkey = (unsigned long long*)p; p += 8192 * 8;
    unsigned long long* keys   = (unsigned long long*)p; p += 8192 * 8;
    unsigned long long* table  = (unsigned long long*)p; p += 16384 * 8;
    int* ids   = (int*)p; p += 8192 * 3 * 4;
    int* count = (int*)p; p += 256;                      // pad to alignment
    unsigned short* xhat = (unsigned short*)p;           // 8192x768 bf16 (12 MB)

    hipMemsetAsync(z, 0, (size_t)8192 * 128 * sizeof(float), stream);
    hipMemsetAsync(qloss, 0, 8192 * sizeof(float), stream);
    hipMemsetAsync(count, 0, sizeof(int), stream);
    hipMemsetAsync(table, 0xFF, 16384 * sizeof(unsigned long long), stream);

    // weight splits (inputs only; up front)
    splitw2_swz_kernel<256, 128><<<128, 256, 0, stream>>>(dec_w1, dw1_hi, dw1_lo);
    splitw2_swz_kernel<512, 256><<<512, 256, 0, stream>>>(dec_w2, dw2_hi, dw2_lo);
    splitw2_swz_kernel<768, 512><<<1536, 256, 0, stream>>>(dec_w3, dw3_hi, dw3_lo);
    splitw3_swz_kernel<512, 768><<<1536, 256, 0, stream>>>(enc_w1, ew1_h, ew1_m, ew1_l);
    splitw3_swz_kernel<256, 512><<<512, 256, 0, stream>>>(enc_w2, ew2_h, ew2_m, ew2_l);
    splitw3_swz_kernel<128, 256><<<128, 256, 0, stream>>>(enc_w3, ew3_h, ew3_m, ew3_l);

    // encoder (exact-split MFMA, fp32-faithful); h1/h2 swizzled fp32;
    // enc3 epilogue also emits res_hi/res_lo (swz split2) directly
    mfma_enc_kernel<512, 768, 1, 0, 1, 0><<<dim3(8, 64), 256, 0, stream>>>(
        x, ew1_h, ew1_m, ew1_l, enc_b1, h1, nullptr, nullptr);
    mfma_enc_kernel<256, 512, 1, 1, 1, 0><<<dim3(4, 64), 256, 0, stream>>>(
        h1, ew2_h, ew2_m, ew2_l, enc_b2, h2, nullptr, nullptr);
    mfma_enc_kernel<128, 256, 0, 1, 0, 1><<<dim3(2, 64), 256, 0, stream>>>(
        h2, ew3_h, ew3_m, ew3_l, enc_b3, res, res_hi, res_lo);

    // residual quantization layers
    for (int l = 0; l < 3; ++l) {
        proj_split_kernel<<<1024, 128, 0, stream>>>(codebooks + (size_t)l * 8192 * 128,
                                                    projs + (size_t)l * 128 * 128,
                                                    cbp, cbp_hi, cbp_lo, cbn);
        hipMemsetAsync(minkey, 0xFF, 8192 * sizeof(unsigned long long), stream);
        argmin_mfma_kernel<<<dim3(32, 64), 256, 0, stream>>>(res_hi, res_lo,
                                                             cbp_hi, cbp_lo, cbn, minkey);
        finalize_kernel<<<8192, 128, 0, stream>>>(res, cbp, minkey, qloss, z,
                                                  ids, out + 3, keys,
                                                  res_hi, res_lo, z_hi, z_lo, l);
    }

    // decoder (split-precision MFMA, swizzled planes; z planes from finalize)
    mfma_gemm_kernel<256, 128, 1, 0><<<dim3(2, 64), 256, 0, stream>>>(
        z_hi, z_lo, dw1_hi, dw1_lo, dec_b1, g1_hi, g1_lo);
    mfma_gemm_kernel<512, 256, 1, 0><<<dim3(4, 64), 256, 0, stream>>>(
        g1_hi, g1_lo, dw2_hi, dw2_lo, dec_b2, g2_hi, g2_lo);
    mfma_gemm_kernel<768, 512, 2, 1><<<dim3(6, 64), 256, 0, stream>>>(
        g2_hi, g2_lo, dw3_hi, dw3_lo, dec_b3, xhat, nullptr);
    norm_recon_kernel<<<8192, 256, 0, stream>>>(xhat, x, recon_row);

    // diagnostics
    uniq_hash_kernel<<<32, 256, 0, stream>>>(keys, table, count);
    scalars_kernel<<<1, 256, 0, stream>>>(qloss, recon_row, count, out);
}

// Round 7
// 522.073 us; speedup vs baseline: 4.8577x; 1.1280x over previous
//
#include <hip/hip_runtime.h>
#include <hip/hip_bf16.h>
#include <math.h>

// Problem constants
#define B_  8192
#define IN_ 768
#define D_  128
#define K_  8192
#define L_  3

typedef __attribute__((ext_vector_type(8))) short bf16x8;
typedef __attribute__((ext_vector_type(4))) float f32x4;

// ---------------------------------------------------------------------------
// Fragment-major swizzled layout for a [R][C] matrix (R%16==0, C%32==0):
//   off(row,k) = ((row>>4)*(C/32) + (k>>5))*512 + ((k>>3)&3)*128 + (row&15)*8 + (k&7)
// MFMA fragment load (row-tile rt, k-slice s) for lane l is then
//   plane + ((rt*(C/32)+s)<<9) + l*8   -> fully coalesced 16B/lane (bf16).
// Fragments are contiguous 1 KB chunks -> ideal for global_load_lds staging.
// ---------------------------------------------------------------------------
__device__ __forceinline__ size_t swz(int row, int col, int C)
{
    return ((size_t)((row >> 4) * (C >> 5) + (col >> 5)) << 9)
         + (((col >> 3) & 3) << 7) + ((row & 15) << 3) + (col & 7);
}

// Split f into hi (bf16 RNE) + lo (bf16 RNE of remainder). ~2^-18 rel error.
__device__ __forceinline__ void split2(float f, unsigned short& h, unsigned short& l)
{
    unsigned u = __float_as_uint(f);
    unsigned hb = (u + 0x7FFFu + ((u >> 16) & 1u)) & 0xFFFF0000u;
    h = (unsigned short)(hb >> 16);
    float r = f - __uint_as_float(hb);
    unsigned v = __float_as_uint(r);
    l = (unsigned short)((v + 0x7FFFu + ((v >> 16) & 1u)) >> 16);
}

// Triple split: f = h + m + l, covers all 24 fp32 mantissa bits (~2^-27).
__device__ __forceinline__ void split3(float f, unsigned short& h,
                                       unsigned short& m, unsigned short& l)
{
    unsigned u = __float_as_uint(f);
    unsigned hb = (u + 0x7FFFu + ((u >> 16) & 1u)) & 0xFFFF0000u;
    h = (unsigned short)(hb >> 16);
    float r1 = f - __uint_as_float(hb);
    unsigned v = __float_as_uint(r1);
    unsigned mb = (v + 0x7FFFu + ((v >> 16) & 1u)) & 0xFFFF0000u;
    m = (unsigned short)(mb >> 16);
    float r2 = r1 - __uint_as_float(mb);
    unsigned w = __float_as_uint(r2);
    l = (unsigned short)((w + 0x7FFFu + ((w >> 16) & 1u)) >> 16);
}

__device__ __forceinline__ unsigned short bf16_rne(float f)
{
    unsigned u = __float_as_uint(f);
    return (unsigned short)((u + 0x7FFFu + ((u >> 16) & 1u)) >> 16);
}

// ---------------------------------------------------------------------------
// fp32 [R][C] linear -> swizzled permutation (pure layout; values identical).
// One thread per 8-col group (the 8 cols are contiguous in swz).
// ---------------------------------------------------------------------------
template<int C>
__global__ __launch_bounds__(256)
void swzf32_kernel(const float* __restrict__ src, float* __restrict__ dst)
{
    const int i = blockIdx.x * 256 + threadIdx.x;
    const int row = i / (C / 8);
    const int col = (i - row * (C / 8)) * 8;
    float4 a = *(const float4*)&src[(size_t)row * C + col];
    float4 b = *(const float4*)&src[(size_t)row * C + col + 4];
    const size_t o = swz(row, col, C);
    *(float4*)&dst[o] = a;
    *(float4*)&dst[o + 4] = b;
}

// ---------------------------------------------------------------------------
// Encoder MFMA GEMM, fp32-faithful: C = act(A @ W^T + bias).
// A fp32 (linear if ASWZ=0, swizzled if 1), triple-split in-register; W in 3
// swizzled bf16 planes. 6 MFMA passes -> ~1e-6 rel error (argmin-id safe).
// BM=128 (4 waves x 2 m-tiles), BN=64 (4 n-tiles), K-step 32.
// ACT: 0=none, 1=silu. CSWZ: fp32 out linear(0)/swizzled(1).
// OUT2: additionally write split2 bf16 planes (swz) of the output (enc3).
// ---------------------------------------------------------------------------
template<int N, int K, int ACT, int ASWZ, int CSWZ, int OUT2>
__global__ __launch_bounds__(256)
void mfma_enc_kernel(const float* __restrict__ A,
                     const unsigned short* __restrict__ Wh,
                     const unsigned short* __restrict__ Wm,
                     const unsigned short* __restrict__ Wl,
                     const float* __restrict__ bias, float* __restrict__ C,
                     unsigned short* __restrict__ Rh,
                     unsigned short* __restrict__ Rl)
{
    const int tid  = threadIdx.x;
    const int lane = tid & 63;
    const int w    = tid >> 6;
    const int ln   = lane & 15;
    const int grp  = lane >> 4;
    const int m0   = blockIdx.y * 128 + w * 32;
    const int n0   = blockIdx.x * 64;

    f32x4 acc[2][4] = {};

    for (int ks = 0; ks < K; ks += 32) {
        const int s = ks >> 5;
        bf16x8 ah[2], am[2], al[2];
        #pragma unroll
        for (int mt = 0; mt < 2; ++mt) {
            float4 f0, f1;
            if (ASWZ) {
                const size_t base =
                    ((size_t)(((m0 >> 4) + mt) * (K >> 5) + s) << 9) + lane * 8;
                f0 = *(const float4*)&A[base];
                f1 = *(const float4*)&A[base + 4];
            } else {
                const size_t off = (size_t)(m0 + mt * 16 + ln) * K + ks + grp * 8;
                f0 = *(const float4*)&A[off];
                f1 = *(const float4*)&A[off + 4];
            }
            float fv[8] = {f0.x, f0.y, f0.z, f0.w, f1.x, f1.y, f1.z, f1.w};
            #pragma unroll
            for (int e = 0; e < 8; ++e) {
                unsigned short hh, mm, ll;
                split3(fv[e], hh, mm, ll);
                ah[mt][e] = (short)hh;
                am[mt][e] = (short)mm;
                al[mt][e] = (short)ll;
            }
        }
        #pragma unroll
        for (int nt = 0; nt < 4; ++nt) {
            const size_t off =
                ((size_t)(((n0 >> 4) + nt) * (K >> 5) + s) << 9) + lane * 8;
            bf16x8 bh = *(const bf16x8*)&Wh[off];
            bf16x8 bm = *(const bf16x8*)&Wm[off];
            bf16x8 bl = *(const bf16x8*)&Wl[off];
            #pragma unroll
            for (int mt = 0; mt < 2; ++mt) {
                acc[mt][nt] = __builtin_amdgcn_mfma_f32_16x16x32_bf16(ah[mt], bh, acc[mt][nt], 0, 0, 0);
                acc[mt][nt] = __builtin_amdgcn_mfma_f32_16x16x32_bf16(am[mt], bh, acc[mt][nt], 0, 0, 0);
                acc[mt][nt] = __builtin_amdgcn_mfma_f32_16x16x32_bf16(ah[mt], bm, acc[mt][nt], 0, 0, 0);
                acc[mt][nt] = __builtin_amdgcn_mfma_f32_16x16x32_bf16(al[mt], bh, acc[mt][nt], 0, 0, 0);
                acc[mt][nt] = __builtin_amdgcn_mfma_f32_16x16x32_bf16(am[mt], bm, acc[mt][nt], 0, 0, 0);
                acc[mt][nt] = __builtin_amdgcn_mfma_f32_16x16x32_bf16(ah[mt], bl, acc[mt][nt], 0, 0, 0);
            }
        }
    }

    #pragma unroll
    for (int nt = 0; nt < 4; ++nt) {
        const int col = n0 + nt * 16 + ln;
        const float bv = bias[col];
        #pragma unroll
        for (int mt = 0; mt < 2; ++mt) {
            #pragma unroll
            for (int r = 0; r < 4; ++r) {
                const int row = m0 + mt * 16 + grp * 4 + r;
                float v = acc[mt][nt][r] + bv;
                if (ACT == 1) v = v / (1.0f + expf(-v));
                if (CSWZ) C[swz(row, col, N)] = v;
                else      C[(size_t)row * N + col] = v;
                if (OUT2) {
                    unsigned short h, l;
                    split2(v, h, l);
                    const size_t o = swz(row, col, N);
                    Rh[o] = h;
                    Rl[o] = l;
                }
            }
        }
    }
}

// ---------------------------------------------------------------------------
// Split-precision MFMA GEMM (decoder): A,W as swizzled bf16 hi/lo planes;
// dot = hh + lh + hl (~2^-17 rel, only affects recon/loss, ~2% tolerance).
// BM=128, BN=128, K-step 32. ACT: 1=silu, 2=sigmoid.
// OUT: 0=swizzled bf16 hi/lo pair, 1=linear single bf16.
// ---------------------------------------------------------------------------
template<int N, int K, int ACT, int OUT>
__global__ __launch_bounds__(256)
void mfma_gemm_kernel(const unsigned short* __restrict__ A_hi,
                      const unsigned short* __restrict__ A_lo,
                      const unsigned short* __restrict__ W_hi,
                      const unsigned short* __restrict__ W_lo,
                      const float* __restrict__ bias,
                      unsigned short* __restrict__ C_hi,
                      unsigned short* __restrict__ C_lo)
{
    const int tid  = threadIdx.x;
    const int lane = tid & 63;
    const int w    = tid >> 6;
    const int ln   = lane & 15;
    const int grp  = lane >> 4;
    const int m0   = blockIdx.y * 128 + w * 32;
    const int n0   = blockIdx.x * 128;

    f32x4 acc[2][8] = {};

    for (int ks = 0; ks < K; ks += 32) {
        const int s = ks >> 5;
        bf16x8 ah[2], al[2];
        #pragma unroll
        for (int mt = 0; mt < 2; ++mt) {
            const size_t off =
                ((size_t)(((m0 >> 4) + mt) * (K >> 5) + s) << 9) + lane * 8;
            ah[mt] = *(const bf16x8*)&A_hi[off];
            al[mt] = *(const bf16x8*)&A_lo[off];
        }
        #pragma unroll
        for (int nt = 0; nt < 8; ++nt) {
            const size_t off =
                ((size_t)(((n0 >> 4) + nt) * (K >> 5) + s) << 9) + lane * 8;
            bf16x8 bh = *(const bf16x8*)&W_hi[off];
            bf16x8 bl = *(const bf16x8*)&W_lo[off];
            #pragma unroll
            for (int mt = 0; mt < 2; ++mt) {
                acc[mt][nt] = __builtin_amdgcn_mfma_f32_16x16x32_bf16(ah[mt], bh, acc[mt][nt], 0, 0, 0);
                acc[mt][nt] = __builtin_amdgcn_mfma_f32_16x16x32_bf16(al[mt], bh, acc[mt][nt], 0, 0, 0);
                acc[mt][nt] = __builtin_amdgcn_mfma_f32_16x16x32_bf16(ah[mt], bl, acc[mt][nt], 0, 0, 0);
            }
        }
    }

    #pragma unroll
    for (int nt = 0; nt < 8; ++nt) {
        const int col = n0 + nt * 16 + ln;
        const float bv = bias[col];
        #pragma unroll
        for (int mt = 0; mt < 2; ++mt) {
            #pragma unroll
            for (int r = 0; r < 4; ++r) {
                const int row = m0 + mt * 16 + grp * 4 + r;
                float v = acc[mt][nt][r] + bv;
                if (ACT == 1) v = v / (1.0f + expf(-v));
                if (ACT == 2) v = 1.0f / (1.0f + expf(-v));
                if (OUT == 0) {
                    unsigned short h, l;
                    split2(v, h, l);
                    const size_t o = swz(row, col, N);
                    C_hi[o] = h;
                    C_lo[o] = l;
                } else {
                    C_hi[(size_t)row * N + col] = bf16_rne(v);
                }
            }
        }
    }
}

// ---------------------------------------------------------------------------
// Per-row L2 normalize + recon partial.
// ---------------------------------------------------------------------------
__global__ __launch_bounds__(256)
void norm_recon_kernel(const unsigned short* __restrict__ xhat,
                       const float* __restrict__ x,
                       float* __restrict__ recon_row)
{
    const int b = blockIdx.x;
    const int tid = threadIdx.x;
    __shared__ float ws[4];
    __shared__ float nrm_s;

    float v[3];
    float ss = 0.0f;
    #pragma unroll
    for (int c = 0; c < 3; ++c) {
        unsigned short u = xhat[(size_t)b * 768 + tid + c * 256];
        v[c] = __uint_as_float((unsigned)u << 16);
        ss += v[c] * v[c];
    }
    for (int off = 32; off > 0; off >>= 1) ss += __shfl_down(ss, off, 64);
    if ((tid & 63) == 0) ws[tid >> 6] = ss;
    __syncthreads();
    if (tid == 0) nrm_s = fmaxf(sqrtf(ws[0] + ws[1] + ws[2] + ws[3]), 1e-12f);
    __syncthreads();
    const float inv = 1.0f / nrm_s;
    float ra = 0.0f;
    #pragma unroll
    for (int c = 0; c < 3; ++c) {
        float dx = v[c] * inv - x[(size_t)b * 768 + tid + c * 256];
        ra += dx * dx;
    }
    for (int off = 32; off > 0; off >>= 1) ra += __shfl_down(ra, off, 64);
    if ((tid & 63) == 0) ws[tid >> 6] = ra;
    __syncthreads();
    if (tid == 0) recon_row[b] = ws[0] + ws[1] + ws[2] + ws[3];
}

// ---------------------------------------------------------------------------
// Projected codebook: cbp fp32 linear + swizzled bf16 hi/lo planes + norms.
// ---------------------------------------------------------------------------
__global__ __launch_bounds__(128)
void proj_split_kernel(const float* __restrict__ cbl, const float* __restrict__ projl,
                       float* __restrict__ cbp, unsigned short* __restrict__ cbp_hi,
                       unsigned short* __restrict__ cbp_lo, float* __restrict__ cbn)
{
    __shared__ float cbs[8][128];
    __shared__ float wsum[8][2];
    const int tid = threadIdx.x;          // = d
    const int k0 = blockIdx.x * 8;

    #pragma unroll
    for (int i = 0; i < 2; ++i) {
        int idx4 = tid + i * 128;
        int r = idx4 >> 5, c4 = (idx4 & 31) * 4;
        *(float4*)&cbs[r][c4] = *(const float4*)&cbl[(size_t)(k0 + r) * 128 + c4];
    }
    __syncthreads();

    float acc[8] = {};
    for (int j4 = 0; j4 < 32; ++j4) {
        float4 pv = *(const float4*)&projl[(size_t)tid * 128 + j4 * 4];
        #pragma unroll
        for (int r = 0; r < 8; ++r) {
            float4 cv = *(float4*)&cbs[r][j4 * 4];
            acc[r] += pv.x * cv.x + pv.y * cv.y + pv.z * cv.z + pv.w * cv.w;
        }
    }
    #pragma unroll
    for (int r = 0; r < 8; ++r) {
        cbp[(size_t)(k0 + r) * 128 + tid] = acc[r];
        unsigned short h, l;
        split2(acc[r], h, l);
        const size_t o = swz(k0 + r, tid, 128);
        cbp_hi[o] = h;
        cbp_lo[o] = l;
        float v = acc[r] * acc[r];
        #pragma unroll
        for (int off = 32; off > 0; off >>= 1) v += __shfl_down(v, off, 64);
        if ((tid & 63) == 0) wsum[r][tid >> 6] = v;
    }
    __syncthreads();
    if (tid < 8) cbn[k0 + tid] = wsum[tid][0] + wsum[tid][1];
}

// ---------------------------------------------------------------------------
// Weight [NR][KC] fp32 -> 2 or 3 swizzled bf16 planes.
// ---------------------------------------------------------------------------
template<int NR, int KC>
__global__ __launch_bounds__(256)
void splitw2_swz_kernel(const float* __restrict__ src,
                        unsigned short* __restrict__ hi,
                        unsigned short* __restrict__ lo)
{
    const int idx = blockIdx.x * 256 + threadIdx.x;
    if (idx >= NR * KC) return;
    unsigned short h, l;
    split2(src[idx], h, l);
    const size_t o = swz(idx / KC, idx % KC, KC);
    hi[o] = h;
    lo[o] = l;
}

template<int NR, int KC>
__global__ __launch_bounds__(256)
void splitw3_swz_kernel(const float* __restrict__ src,
                        unsigned short* __restrict__ hi,
                        unsigned short* __restrict__ mi,
                        unsigned short* __restrict__ lo)
{
    const int idx = blockIdx.x * 256 + threadIdx.x;
    if (idx >= NR * KC) return;
    unsigned short h, m, l;
    split3(src[idx], h, m, l);
    const size_t o = swz(idx / KC, idx % KC, KC);
    hi[o] = h;
    mi[o] = m;
    lo[o] = l;
}

// ---------------------------------------------------------------------------
// MFMA distance argmin (swizzled planes; ids bit-identical to numpy).
// B (cbp hi/lo fragments) staged once per BLOCK into LDS via global_load_lds
// (double-buffered 2x32KB) -> removes the 4x per-wave L2 re-read that
// dominated round 6. STAGE(next) is issued before compute(cur); the
// __syncthreads() at iteration end drains vmcnt (T3-minimal pattern), so
// staging latency hides under the 192 MFMAs.
// ---------------------------------------------------------------------------
__device__ __forceinline__ unsigned int fkey(float s) {
    unsigned int u = __float_as_uint(s);
    return (u & 0x80000000u) ? ~u : (u | 0x80000000u);
}

__global__ __launch_bounds__(256, 2)
void argmin_mfma_kernel(const unsigned short* __restrict__ res_hi,
                        const unsigned short* __restrict__ res_lo,
                        const unsigned short* __restrict__ cbp_hi,
                        const unsigned short* __restrict__ cbp_lo,
                        const float* __restrict__ cbn,
                        unsigned long long* __restrict__ minkey)
{
    __shared__ unsigned short lds[32768];   // 2 buffers x 32 KB
    const int tid  = threadIdx.x;
    const int lane = tid & 63;
    const int w    = tid >> 6;
    const int ln   = lane & 15;
    const int grp  = lane >> 4;
    const int m0   = blockIdx.y * 128 + w * 32;
    const int c0b  = blockIdx.x * 256;

    // A fragments (held in registers for the whole kernel)
    bf16x8 a_hi[2][4], a_lo[2][4];
    #pragma unroll
    for (int mt = 0; mt < 2; ++mt) {
        #pragma unroll
        for (int s = 0; s < 4; ++s) {
            const size_t off =
                ((size_t)(((m0 >> 4) + mt) * 4 + s) << 9) + lane * 8;
            a_hi[mt][s] = *(const bf16x8*)&res_hi[off];
            a_lo[mt][s] = *(const bf16x8*)&res_lo[off];
        }
    }

    // Staging: per it, B data = 16 fragments x 1KB per plane (16KB hi + 16KB lo,
    // both contiguous in global). Wave w stages 8KB: waves 0,1 -> hi halves,
    // waves 2,3 -> lo halves. 8 x global_load_lds(16B) per wave.
    const unsigned short* splane = (w < 2) ? cbp_hi : cbp_lo;
    const unsigned lbase0 = (unsigned)((w >> 1) * 16384 + (w & 1) * 8192); // bytes

    auto STAGE = [&](int buf, int it) {
        const size_t g0 = (((size_t)(c0b >> 4) + it * 4) << 11)
                        + (w & 1) * 4096 + lane * 8;       // shorts
        const unsigned l0 = (unsigned)buf * 32768u + lbase0;  // bytes
        #pragma unroll
        for (int i = 0; i < 8; ++i) {
            __builtin_amdgcn_global_load_lds(
                (const __attribute__((address_space(1))) unsigned int*)(splane + g0 + i * 512),
                (__attribute__((address_space(3))) unsigned int*)((char*)lds + l0 + i * 1024),
                16, 0, 0);
        }
    };

    float best_s[2][4];
    int   best_c[2][4];
    #pragma unroll
    for (int mt = 0; mt < 2; ++mt)
        #pragma unroll
        for (int r = 0; r < 4; ++r) { best_s[mt][r] = 3.4e38f; best_c[mt][r] = 0; }

    STAGE(0, 0);
    __syncthreads();                        // drains vmcnt -> buf0 ready

    for (int it = 0; it < 4; ++it) {
        const int buf = it & 1;
        if (it < 3) STAGE(buf ^ 1, it + 1); // async prefetch into other buffer
        const unsigned short* lb = lds + buf * 16384;   // shorts
        const int c0 = c0b + it * 64;
        f32x4 acc[2][4] = {};
        #pragma unroll
        for (int s = 0; s < 4; ++s) {
            #pragma unroll
            for (int t = 0; t < 4; ++t) {
                const int fo = (t * 4 + s) * 512 + lane * 8;
                bf16x8 bh = *(const bf16x8*)&lb[fo];
                bf16x8 bl = *(const bf16x8*)&lb[fo + 8192];
                #pragma unroll
                for (int mt = 0; mt < 2; ++mt) {
                    acc[mt][t] = __builtin_amdgcn_mfma_f32_16x16x32_bf16(a_hi[mt][s], bh, acc[mt][t], 0, 0, 0);
                    acc[mt][t] = __builtin_amdgcn_mfma_f32_16x16x32_bf16(a_lo[mt][s], bh, acc[mt][t], 0, 0, 0);
                    acc[mt][t] = __builtin_amdgcn_mfma_f32_16x16x32_bf16(a_hi[mt][s], bl, acc[mt][t], 0, 0, 0);
                }
            }
        }
        #pragma unroll
        for (int t = 0; t < 4; ++t) {
            const int col = c0 + t * 16 + ln;
            const float cn = cbn[col];
            #pragma unroll
            for (int mt = 0; mt < 2; ++mt)
                #pragma unroll
                for (int r = 0; r < 4; ++r) {
                    float sc = fmaf(-2.0f, acc[mt][t][r], cn);
                    if (sc < best_s[mt][r]) {   // strict <: first col wins ties
                        best_s[mt][r] = sc;
                        best_c[mt][r] = col;
                    }
                }
        }
        if (it < 3) __syncthreads();        // drains vmcnt -> next buf ready,
                                            // and all waves done with cur buf
    }

    #pragma unroll
    for (int mt = 0; mt < 2; ++mt)
        #pragma unroll
        for (int r = 0; r < 4; ++r) {
            unsigned long long b =
                ((unsigned long long)fkey(best_s[mt][r]) << 32)
                | (unsigned int)best_c[mt][r];
            #pragma unroll
            for (int off = 1; off < 16; off <<= 1) {
                unsigned lo32 = (unsigned)b, hi32 = (unsigned)(b >> 32);
                lo32 = __shfl_xor(lo32, off);
                hi32 = __shfl_xor(hi32, off);
                unsigned long long o = ((unsigned long long)hi32 << 32) | lo32;
                if (o < b) b = o;
            }
            if (ln == 0) atomicMin(&minkey[m0 + mt * 16 + grp * 4 + r], b);
        }
}

// ---------------------------------------------------------------------------
// Per-layer epilogue (res planes written swizzled; layer 2 also emits z planes).
// ---------------------------------------------------------------------------
__global__ __launch_bounds__(128)
void finalize_kernel(float* __restrict__ res, const float* __restrict__ cbp,
                     const unsigned long long* __restrict__ minkey,
                     float* __restrict__ qloss, float* __restrict__ z,
                     int* __restrict__ ids, float* __restrict__ embs_norm_out,
                     unsigned long long* __restrict__ keys,
                     unsigned short* __restrict__ res_hi,
                     unsigned short* __restrict__ res_lo,
                     unsigned short* __restrict__ z_hi,
                     unsigned short* __restrict__ z_lo, int layer)
{
    const int b = blockIdx.x;
    const int tid = threadIdx.x;
    const int id = (int)(minkey[b] & 0xFFFFFFFFull);
    float e = cbp[(size_t)id * 128 + tid];
    float r = res[(size_t)b * 128 + tid];
    float d = r - e;
    float v1 = d * d, v2 = e * e;
    for (int off = 32; off > 0; off >>= 1) {
        v1 += __shfl_down(v1, off, 64);
        v2 += __shfl_down(v2, off, 64);
    }
    __shared__ float ws[4];
    if ((tid & 63) == 0) { ws[(tid >> 6) * 2] = v1; ws[(tid >> 6) * 2 + 1] = v2; }
    __syncthreads();
    if (tid == 0) {
        float d2 = ws[0] + ws[2];
        float n2 = ws[1] + ws[3];
        qloss[b] += 1.25f * d2;                 // emb_loss + 0.25*query_loss
        embs_norm_out[b * 3 + layer] = sqrtf(n2);
        ids[b * 3 + layer] = id;
        if (layer == 2) {
            keys[b] = (unsigned long long)ids[b * 3 + 0]
                    | ((unsigned long long)ids[b * 3 + 1] << 13)
                    | ((unsigned long long)id << 26);
        }
    }
    float nz = z[(size_t)b * 128 + tid] + e;
    z[(size_t)b * 128 + tid] = nz;
    const size_t o = swz(b, tid, 128);
    if (layer == 2) {
        unsigned short zh, zl;
        split2(nz, zh, zl);
        z_hi[o] = zh;
        z_lo[o] = zl;
    }
    float nr = r - e;
    res[(size_t)b * 128 + tid] = nr;
    unsigned short h, l;
    split2(nr, h, l);
    res_hi[o] = h;
    res_lo[o] = l;
}

// ---------------------------------------------------------------------------
// Distinct-triple count via open-addressing hash set (= reference's count of
// rows with no later duplicate). atomicCAS insert, deterministic.
// ---------------------------------------------------------------------------
__global__ __launch_bounds__(256)
void uniq_hash_kernel(const unsigned long long* __restrict__ keys,
                      unsigned long long* __restrict__ table,
                      int* __restrict__ count)
{
    const int i = blockIdx.x * 256 + threadIdx.x;
    const unsigned long long k = keys[i];
    unsigned h = (unsigned)((k * 0x9E3779B97F4A7C15ull) >> 50);   // 14 bits
    while (true) {
        unsigned long long old = atomicCAS(&table[h], ~0ULL, k);
        if (old == ~0ULL) { atomicAdd(count, 1); break; }   // first insert
        if (old == k) break;                                // duplicate
        h = (h + 1) & 16383;
    }
}

// ---------------------------------------------------------------------------
// Final scalars.
// ---------------------------------------------------------------------------
__global__ __launch_bounds__(256)
void scalars_kernel(const float* __restrict__ qloss,
                    const float* __restrict__ recon_row,
                    const int* __restrict__ count, float* __restrict__ out)
{
    const int tid = threadIdx.x;
    float qs = 0.0f, rs = 0.0f;
    for (int i = tid; i < 8192; i += 256) qs += qloss[i];
    for (int i = tid; i < 8192; i += 256) rs += recon_row[i];
    for (int off = 32; off > 0; off >>= 1) {
        qs += __shfl_down(qs, off, 64);
        rs += __shfl_down(rs, off, 64);
    }
    __shared__ float w[8];
    if ((tid & 63) == 0) { w[(tid >> 6) * 2] = qs; w[(tid >> 6) * 2 + 1] = rs; }
    __syncthreads();
    if (tid == 0) {
        float qsum = w[0] + w[2] + w[4] + w[6];
        float rsum = w[1] + w[3] + w[5] + w[7];
        float qmean = qsum / 8192.0f;
        out[0] = rsum + qmean;        // loss = (recon + qloss).mean()
        out[1] = rsum;                // recon
        out[2] = qmean;               // qloss.mean()
        out[24579] = (float)(*count) / 8192.0f;   // p_unique
    }
}

// ---------------------------------------------------------------------------
extern "C" void kernel_launch(void* const* d_in, const int* in_sizes, int n_in,
                              void* d_out, int out_size, void* d_ws, size_t ws_size,
                              hipStream_t stream)
{
    const float* x      = (const float*)d_in[0];
    const float* enc_w1 = (const float*)d_in[1];
    const float* enc_b1 = (const float*)d_in[2];
    const float* enc_w2 = (const float*)d_in[3];
    const float* enc_b2 = (const float*)d_in[4];
    const float* enc_w3 = (const float*)d_in[5];
    const float* enc_b3 = (const float*)d_in[6];
    const float* dec_w1 = (const float*)d_in[7];
    const float* dec_b1 = (const float*)d_in[8];
    const float* dec_w2 = (const float*)d_in[9];
    const float* dec_b2 = (const float*)d_in[10];
    const float* dec_w3 = (const float*)d_in[11];
    const float* dec_b3 = (const float*)d_in[12];
    const float* codebooks = (const float*)d_in[13];
    const float* projs     = (const float*)d_in[14];
    float* out = (float*)d_out;

    char* ws = (char*)d_ws;
    const size_t MB = 1024 * 1024;

    // --- region [0, 16M): encoder h1 f32 (swz) ; decoder g2_hi/g2_lo (swz)
    float* h1 = (float*)ws;                                        // 8192x512 f32
    unsigned short* g2_hi = (unsigned short*)ws;                   // 8192x512 bf16
    unsigned short* g2_lo = (unsigned short*)(ws + 8 * MB);
    // --- region [16M, 24M): encoder h2 f32 (swz) ; quant splits ; dec g1 (swz)
    float* h2 = (float*)(ws + 16 * MB);                            // 8192x256 f32
    unsigned short* res_hi = (unsigned short*)(ws + 16 * MB);      // 8192x128
    unsigned short* res_lo = (unsigned short*)(ws + 18 * MB);
    unsigned short* cbp_hi = (unsigned short*)(ws + 20 * MB);
    unsigned short* cbp_lo = (unsigned short*)(ws + 22 * MB);
    unsigned short* g1_hi  = (unsigned short*)(ws + 16 * MB);      // 8192x256 (decoder)
    unsigned short* g1_lo  = (unsigned short*)(ws + 20 * MB);
    // --- region [24M, 28M): res f32 (linear)
    float* res = (float*)(ws + 24 * MB);                           // 8192x128 f32
    // --- region [28M, 32M): cbp f32 (linear) ; decoder z_hi/z_lo (swz)
    float* cbp = (float*)(ws + 28 * MB);                           // 8192x128 f32
    unsigned short* z_hi = (unsigned short*)(ws + 28 * MB);        // 8192x128
    unsigned short* z_lo = (unsigned short*)(ws + 30 * MB);
    // --- region [32M, 36M): z f32 (linear)
    float* z = (float*)(ws + 32 * MB);                             // 8192x128 f32
    // --- region [36M, ...): weight splits (all swz) + small buffers
    char* p = ws + 36 * MB;
    unsigned short* dw1_hi = (unsigned short*)p; p += 256 * 128 * 2;
    unsigned short* dw1_lo = (unsigned short*)p; p += 256 * 128 * 2;
    unsigned short* dw2_hi = (unsigned short*)p; p += 512 * 256 * 2;
    unsigned short* dw2_lo = (unsigned short*)p; p += 512 * 256 * 2;
    unsigned short* dw3_hi = (unsigned short*)p; p += 768 * 512 * 2;
    unsigned short* dw3_lo = (unsigned short*)p; p += 768 * 512 * 2;
    unsigned short* ew1_h  = (unsigned short*)p; p += 512 * 768 * 2;
    unsigned short* ew1_m  = (unsigned short*)p; p += 512 * 768 * 2;
    unsigned short* ew1_l  = (unsigned short*)p; p += 512 * 768 * 2;
    unsigned short* ew2_h  = (unsigned short*)p; p += 256 * 512 * 2;
    unsigned short* ew2_m  = (unsigned short*)p; p += 256 * 512 * 2;
    unsigned short* ew2_l  = (unsigned short*)p; p += 256 * 512 * 2;
    unsigned short* ew3_h  = (unsigned short*)p; p += 128 * 256 * 2;
    unsigned short* ew3_m  = (unsigned short*)p; p += 128 * 256 * 2;
    unsigned short* ew3_l  = (unsigned short*)p; p += 128 * 256 * 2;
    float* cbn       = (float*)p; p += 8192 * 4;
    float* qloss     = (float*)p; p += 8192 * 4;
    float* recon_row = (float*)p; p += 8192 * 4;
    unsigned long long* minkey = (unsigned long long*)p; p += 8192 * 8;
    unsigned long long* keys   = (unsigned long long*)p; p += 8192 * 8;
    unsigned long long* table  = (unsigned long long*)p; p += 16384 * 8;
    int* ids   = (int*)p; p += 8192 * 3 * 4;
    int* count = (int*)p; p += 256;                      // pad to alignment
    unsigned short* xhat = (unsigned short*)p; p += (size_t)8192 * 768 * 2;
    // optional x swizzle buffer (24 MB) — only if workspace is big enough
    float* xs = (float*)p;
    const bool use_xs =
        ((size_t)(p - ws) + (size_t)8192 * 768 * 4) <= ws_size;

    hipMemsetAsync(z, 0, (size_t)8192 * 128 * sizeof(float), stream);
    hipMemsetAsync(qloss, 0, 8192 * sizeof(float), stream);
    hipMemsetAsync(count, 0, sizeof(int), stream);
    hipMemsetAsync(table, 0xFF, 16384 * sizeof(unsigned long long), stream);

    // weight splits (inputs only; up front)
    splitw2_swz_kernel<256, 128><<<128, 256, 0, stream>>>(dec_w1, dw1_hi, dw1_lo);
    splitw2_swz_kernel<512, 256><<<512, 256, 0, stream>>>(dec_w2, dw2_hi, dw2_lo);
    splitw2_swz_kernel<768, 512><<<1536, 256, 0, stream>>>(dec_w3, dw3_hi, dw3_lo);
    splitw3_swz_kernel<512, 768><<<1536, 256, 0, stream>>>(enc_w1, ew1_h, ew1_m, ew1_l);
    splitw3_swz_kernel<256, 512><<<512, 256, 0, stream>>>(enc_w2, ew2_h, ew2_m, ew2_l);
    splitw3_swz_kernel<128, 256><<<128, 256, 0, stream>>>(enc_w3, ew3_h, ew3_m, ew3_l);

    // encoder (exact-split MFMA, fp32-faithful); h1/h2 swizzled fp32;
    // enc3 epilogue also emits res_hi/res_lo (swz split2) directly
    if (use_xs) {
        swzf32_kernel<768><<<3072, 256, 0, stream>>>(x, xs);
        mfma_enc_kernel<512, 768, 1, 1, 1, 0><<<dim3(8, 64), 256, 0, stream>>>(
            xs, ew1_h, ew1_m, ew1_l, enc_b1, h1, nullptr, nullptr);
    } else {
        mfma_enc_kernel<512, 768, 1, 0, 1, 0><<<dim3(8, 64), 256, 0, stream>>>(
            x, ew1_h, ew1_m, ew1_l, enc_b1, h1, nullptr, nullptr);
    }
    mfma_enc_kernel<256, 512, 1, 1, 1, 0><<<dim3(4, 64), 256, 0, stream>>>(
        h1, ew2_h, ew2_m, ew2_l, enc_b2, h2, nullptr, nullptr);
    mfma_enc_kernel<128, 256, 0, 1, 0, 1><<<dim3(2, 64), 256, 0, stream>>>(
        h2, ew3_h, ew3_m, ew3_l, enc_b3, res, res_hi, res_lo);

    // residual quantization layers
    for (int l = 0; l < 3; ++l) {
        proj_split_kernel<<<1024, 128, 0, stream>>>(codebooks + (size_t)l * 8192 * 128,
                                                    projs + (size_t)l * 128 * 128,
                                                    cbp, cbp_hi, cbp_lo, cbn);
        hipMemsetAsync(minkey, 0xFF, 8192 * sizeof(unsigned long long), stream);
        argmin_mfma_kernel<<<dim3(32, 64), 256, 0, stream>>>(res_hi, res_lo,
                                                             cbp_hi, cbp_lo, cbn, minkey);
        finalize_kernel<<<8192, 128, 0, stream>>>(res, cbp, minkey, qloss, z,
                                                  ids, out + 3, keys,
                                                  res_hi, res_lo, z_hi, z_lo, l);
    }

    // decoder (split-precision MFMA, swizzled planes; z planes from finalize)
    mfma_gemm_kernel<256, 128, 1, 0><<<dim3(2, 64), 256, 0, stream>>>(
        z_hi, z_lo, dw1_hi, dw1_lo, dec_b1, g1_hi, g1_lo);
    mfma_gemm_kernel<512, 256, 1, 0><<<dim3(4, 64), 256, 0, stream>>>(
        g1_hi, g1_lo, dw2_hi, dw2_lo, dec_b2, g2_hi, g2_lo);
    mfma_gemm_kernel<768, 512, 2, 1><<<dim3(6, 64), 256, 0, stream>>>(
        g2_hi, g2_lo, dw3_hi, dw3_lo, dec_b3, xhat, nullptr);
    norm_recon_kernel<<<8192, 256, 0, stream>>>(xhat, x, recon_row);

    // diagnostics
    uniq_hash_kernel<<<32, 256, 0, stream>>>(keys, table, count);
    scalars_kernel<<<1, 256, 0, stream>>>(qloss, recon_row, count, out);
}

// Round 8
// 513.928 us; speedup vs baseline: 4.9347x; 1.0158x over previous
//
#include <hip/hip_runtime.h>
#include <hip/hip_bf16.h>
#include <math.h>

// Problem constants
#define B_  8192
#define IN_ 768
#define D_  128
#define K_  8192
#define L_  3

typedef __attribute__((ext_vector_type(8))) short bf16x8;
typedef __attribute__((ext_vector_type(4))) float f32x4;

// ---------------------------------------------------------------------------
// Fragment-major swizzled layout for a [R][C] matrix (R%16==0, C%32==0):
//   off(row,k) = ((row>>4)*(C/32) + (k>>5))*512 + ((k>>3)&3)*128 + (row&15)*8 + (k&7)
// MFMA fragment load (row-tile rt, k-slice s) for lane l is then
//   plane + ((rt*(C/32)+s)<<9) + l*8   -> fully coalesced 16B/lane (bf16).
// Fragments are contiguous 1 KB chunks -> ideal for global_load_lds staging.
// ---------------------------------------------------------------------------
__device__ __forceinline__ size_t swz(int row, int col, int C)
{
    return ((size_t)((row >> 4) * (C >> 5) + (col >> 5)) << 9)
         + (((col >> 3) & 3) << 7) + ((row & 15) << 3) + (col & 7);
}

// Split f into hi (bf16 RNE) + lo (bf16 RNE of remainder). ~2^-18 rel error.
__device__ __forceinline__ void split2(float f, unsigned short& h, unsigned short& l)
{
    unsigned u = __float_as_uint(f);
    unsigned hb = (u + 0x7FFFu + ((u >> 16) & 1u)) & 0xFFFF0000u;
    h = (unsigned short)(hb >> 16);
    float r = f - __uint_as_float(hb);
    unsigned v = __float_as_uint(r);
    l = (unsigned short)((v + 0x7FFFu + ((v >> 16) & 1u)) >> 16);
}

// Triple split: f = h + m + l, covers all 24 fp32 mantissa bits (~2^-27).
__device__ __forceinline__ void split3(float f, unsigned short& h,
                                       unsigned short& m, unsigned short& l)
{
    unsigned u = __float_as_uint(f);
    unsigned hb = (u + 0x7FFFu + ((u >> 16) & 1u)) & 0xFFFF0000u;
    h = (unsigned short)(hb >> 16);
    float r1 = f - __uint_as_float(hb);
    unsigned v = __float_as_uint(r1);
    unsigned mb = (v + 0x7FFFu + ((v >> 16) & 1u)) & 0xFFFF0000u;
    m = (unsigned short)(mb >> 16);
    float r2 = r1 - __uint_as_float(mb);
    unsigned w = __float_as_uint(r2);
    l = (unsigned short)((w + 0x7FFFu + ((w >> 16) & 1u)) >> 16);
}

__device__ __forceinline__ unsigned short bf16_rne(float f)
{
    unsigned u = __float_as_uint(f);
    return (unsigned short)((u + 0x7FFFu + ((u >> 16) & 1u)) >> 16);
}

// ---------------------------------------------------------------------------
// fp32 [R][C] linear -> swizzled permutation (pure layout; values identical).
// ---------------------------------------------------------------------------
template<int C>
__global__ __launch_bounds__(256)
void swzf32_kernel(const float* __restrict__ src, float* __restrict__ dst)
{
    const int i = blockIdx.x * 256 + threadIdx.x;
    const int row = i / (C / 8);
    const int col = (i - row * (C / 8)) * 8;
    float4 a = *(const float4*)&src[(size_t)row * C + col];
    float4 b = *(const float4*)&src[(size_t)row * C + col + 4];
    const size_t o = swz(row, col, C);
    *(float4*)&dst[o] = a;
    *(float4*)&dst[o + 4] = b;
}

// ---------------------------------------------------------------------------
// Fused weight prep: all 6 weight matrices -> swizzled bf16 planes in ONE
// dispatch (block-range segmented; saves 5 launch slots).
// dec weights: split2 (2 planes); enc weights: split3 (3 planes).
// ---------------------------------------------------------------------------
__global__ __launch_bounds__(256)
void prep_weights_kernel(const float* __restrict__ dw1, const float* __restrict__ dw2,
                         const float* __restrict__ dw3, const float* __restrict__ ew1,
                         const float* __restrict__ ew2, const float* __restrict__ ew3,
                         unsigned short* __restrict__ dw1h, unsigned short* __restrict__ dw1l,
                         unsigned short* __restrict__ dw2h, unsigned short* __restrict__ dw2l,
                         unsigned short* __restrict__ dw3h, unsigned short* __restrict__ dw3l,
                         unsigned short* __restrict__ e1h, unsigned short* __restrict__ e1m,
                         unsigned short* __restrict__ e1l,
                         unsigned short* __restrict__ e2h, unsigned short* __restrict__ e2m,
                         unsigned short* __restrict__ e2l,
                         unsigned short* __restrict__ e3h, unsigned short* __restrict__ e3m,
                         unsigned short* __restrict__ e3l)
{
    const int b = blockIdx.x;
    const float* src;
    unsigned short *H, *M = nullptr, *L;
    int kc, idx0;
    bool three;
    if (b < 128)       { src = dw1; H = dw1h; L = dw1l; kc = 128; three = false; idx0 = b * 256; }
    else if (b < 640)  { src = dw2; H = dw2h; L = dw2l; kc = 256; three = false; idx0 = (b - 128) * 256; }
    else if (b < 2176) { src = dw3; H = dw3h; L = dw3l; kc = 512; three = false; idx0 = (b - 640) * 256; }
    else if (b < 3712) { src = ew1; H = e1h; M = e1m; L = e1l; kc = 768; three = true; idx0 = (b - 2176) * 256; }
    else if (b < 4224) { src = ew2; H = e2h; M = e2m; L = e2l; kc = 512; three = true; idx0 = (b - 3712) * 256; }
    else               { src = ew3; H = e3h; M = e3m; L = e3l; kc = 256; three = true; idx0 = (b - 4224) * 256; }

    const int idx = idx0 + threadIdx.x;
    const int row = idx / kc, col = idx - row * kc;
    const size_t o = swz(row, col, kc);
    const float f = src[idx];
    if (three) {
        unsigned short h, m, l;
        split3(f, h, m, l);
        H[o] = h; M[o] = m; L[o] = l;
    } else {
        unsigned short h, l;
        split2(f, h, l);
        H[o] = h; L[o] = l;
    }
}

// ---------------------------------------------------------------------------
// Encoder MFMA GEMM, fp32-faithful: C = act(A @ W^T + bias).
// A fp32 (linear if ASWZ=0, swizzled if 1), triple-split in-register; W in 3
// swizzled bf16 planes. 6 MFMA passes -> ~1e-6 rel error (argmin-id safe).
// BM=128 (4 waves x 2 m-tiles), BN=64 (4 n-tiles), K-step 32.
// ACT: 0=none, 1=silu. CSWZ: fp32 out linear(0)/swizzled(1).
// OUT2: additionally write split2 bf16 planes (swz) of the output (enc3).
// ---------------------------------------------------------------------------
template<int N, int K, int ACT, int ASWZ, int CSWZ, int OUT2>
__global__ __launch_bounds__(256)
void mfma_enc_kernel(const float* __restrict__ A,
                     const unsigned short* __restrict__ Wh,
                     const unsigned short* __restrict__ Wm,
                     const unsigned short* __restrict__ Wl,
                     const float* __restrict__ bias, float* __restrict__ C,
                     unsigned short* __restrict__ Rh,
                     unsigned short* __restrict__ Rl)
{
    const int tid  = threadIdx.x;
    const int lane = tid & 63;
    const int w    = tid >> 6;
    const int ln   = lane & 15;
    const int grp  = lane >> 4;
    const int m0   = blockIdx.y * 128 + w * 32;
    const int n0   = blockIdx.x * 64;

    f32x4 acc[2][4] = {};

    for (int ks = 0; ks < K; ks += 32) {
        const int s = ks >> 5;
        bf16x8 ah[2], am[2], al[2];
        #pragma unroll
        for (int mt = 0; mt < 2; ++mt) {
            float4 f0, f1;
            if (ASWZ) {
                const size_t base =
                    ((size_t)(((m0 >> 4) + mt) * (K >> 5) + s) << 9) + lane * 8;
                f0 = *(const float4*)&A[base];
                f1 = *(const float4*)&A[base + 4];
            } else {
                const size_t off = (size_t)(m0 + mt * 16 + ln) * K + ks + grp * 8;
                f0 = *(const float4*)&A[off];
                f1 = *(const float4*)&A[off + 4];
            }
            float fv[8] = {f0.x, f0.y, f0.z, f0.w, f1.x, f1.y, f1.z, f1.w};
            #pragma unroll
            for (int e = 0; e < 8; ++e) {
                unsigned short hh, mm, ll;
                split3(fv[e], hh, mm, ll);
                ah[mt][e] = (short)hh;
                am[mt][e] = (short)mm;
                al[mt][e] = (short)ll;
            }
        }
        #pragma unroll
        for (int nt = 0; nt < 4; ++nt) {
            const size_t off =
                ((size_t)(((n0 >> 4) + nt) * (K >> 5) + s) << 9) + lane * 8;
            bf16x8 bh = *(const bf16x8*)&Wh[off];
            bf16x8 bm = *(const bf16x8*)&Wm[off];
            bf16x8 bl = *(const bf16x8*)&Wl[off];
            #pragma unroll
            for (int mt = 0; mt < 2; ++mt) {
                acc[mt][nt] = __builtin_amdgcn_mfma_f32_16x16x32_bf16(ah[mt], bh, acc[mt][nt], 0, 0, 0);
                acc[mt][nt] = __builtin_amdgcn_mfma_f32_16x16x32_bf16(am[mt], bh, acc[mt][nt], 0, 0, 0);
                acc[mt][nt] = __builtin_amdgcn_mfma_f32_16x16x32_bf16(ah[mt], bm, acc[mt][nt], 0, 0, 0);
                acc[mt][nt] = __builtin_amdgcn_mfma_f32_16x16x32_bf16(al[mt], bh, acc[mt][nt], 0, 0, 0);
                acc[mt][nt] = __builtin_amdgcn_mfma_f32_16x16x32_bf16(am[mt], bm, acc[mt][nt], 0, 0, 0);
                acc[mt][nt] = __builtin_amdgcn_mfma_f32_16x16x32_bf16(ah[mt], bl, acc[mt][nt], 0, 0, 0);
            }
        }
    }

    #pragma unroll
    for (int nt = 0; nt < 4; ++nt) {
        const int col = n0 + nt * 16 + ln;
        const float bv = bias[col];
        #pragma unroll
        for (int mt = 0; mt < 2; ++mt) {
            #pragma unroll
            for (int r = 0; r < 4; ++r) {
                const int row = m0 + mt * 16 + grp * 4 + r;
                float v = acc[mt][nt][r] + bv;
                if (ACT == 1) v = v / (1.0f + expf(-v));
                if (CSWZ) C[swz(row, col, N)] = v;
                else      C[(size_t)row * N + col] = v;
                if (OUT2) {
                    unsigned short h, l;
                    split2(v, h, l);
                    const size_t o = swz(row, col, N);
                    Rh[o] = h;
                    Rl[o] = l;
                }
            }
        }
    }
}

// ---------------------------------------------------------------------------
// Split-precision MFMA GEMM (decoder): A,W as swizzled bf16 hi/lo planes;
// dot = hh + lh + hl (~2^-17 rel, only affects recon/loss, ~2% tolerance).
// BM=128, BN=128, K-step 32. ACT: 1=silu, 2=sigmoid.
// OUT: 0=swizzled bf16 hi/lo pair, 1=linear single bf16.
// ---------------------------------------------------------------------------
template<int N, int K, int ACT, int OUT>
__global__ __launch_bounds__(256)
void mfma_gemm_kernel(const unsigned short* __restrict__ A_hi,
                      const unsigned short* __restrict__ A_lo,
                      const unsigned short* __restrict__ W_hi,
                      const unsigned short* __restrict__ W_lo,
                      const float* __restrict__ bias,
                      unsigned short* __restrict__ C_hi,
                      unsigned short* __restrict__ C_lo)
{
    const int tid  = threadIdx.x;
    const int lane = tid & 63;
    const int w    = tid >> 6;
    const int ln   = lane & 15;
    const int grp  = lane >> 4;
    const int m0   = blockIdx.y * 128 + w * 32;
    const int n0   = blockIdx.x * 128;

    f32x4 acc[2][8] = {};

    for (int ks = 0; ks < K; ks += 32) {
        const int s = ks >> 5;
        bf16x8 ah[2], al[2];
        #pragma unroll
        for (int mt = 0; mt < 2; ++mt) {
            const size_t off =
                ((size_t)(((m0 >> 4) + mt) * (K >> 5) + s) << 9) + lane * 8;
            ah[mt] = *(const bf16x8*)&A_hi[off];
            al[mt] = *(const bf16x8*)&A_lo[off];
        }
        #pragma unroll
        for (int nt = 0; nt < 8; ++nt) {
            const size_t off =
                ((size_t)(((n0 >> 4) + nt) * (K >> 5) + s) << 9) + lane * 8;
            bf16x8 bh = *(const bf16x8*)&W_hi[off];
            bf16x8 bl = *(const bf16x8*)&W_lo[off];
            #pragma unroll
            for (int mt = 0; mt < 2; ++mt) {
                acc[mt][nt] = __builtin_amdgcn_mfma_f32_16x16x32_bf16(ah[mt], bh, acc[mt][nt], 0, 0, 0);
                acc[mt][nt] = __builtin_amdgcn_mfma_f32_16x16x32_bf16(al[mt], bh, acc[mt][nt], 0, 0, 0);
                acc[mt][nt] = __builtin_amdgcn_mfma_f32_16x16x32_bf16(ah[mt], bl, acc[mt][nt], 0, 0, 0);
            }
        }
    }

    #pragma unroll
    for (int nt = 0; nt < 8; ++nt) {
        const int col = n0 + nt * 16 + ln;
        const float bv = bias[col];
        #pragma unroll
        for (int mt = 0; mt < 2; ++mt) {
            #pragma unroll
            for (int r = 0; r < 4; ++r) {
                const int row = m0 + mt * 16 + grp * 4 + r;
                float v = acc[mt][nt][r] + bv;
                if (ACT == 1) v = v / (1.0f + expf(-v));
                if (ACT == 2) v = 1.0f / (1.0f + expf(-v));
                if (OUT == 0) {
                    unsigned short h, l;
                    split2(v, h, l);
                    const size_t o = swz(row, col, N);
                    C_hi[o] = h;
                    C_lo[o] = l;
                } else {
                    C_hi[(size_t)row * N + col] = bf16_rne(v);
                }
            }
        }
    }
}

// ---------------------------------------------------------------------------
// Per-row L2 normalize + recon partial.
// ---------------------------------------------------------------------------
__global__ __launch_bounds__(256)
void norm_recon_kernel(const unsigned short* __restrict__ xhat,
                       const float* __restrict__ x,
                       float* __restrict__ recon_row)
{
    const int b = blockIdx.x;
    const int tid = threadIdx.x;
    __shared__ float ws[4];
    __shared__ float nrm_s;

    float v[3];
    float ss = 0.0f;
    #pragma unroll
    for (int c = 0; c < 3; ++c) {
        unsigned short u = xhat[(size_t)b * 768 + tid + c * 256];
        v[c] = __uint_as_float((unsigned)u << 16);
        ss += v[c] * v[c];
    }
    for (int off = 32; off > 0; off >>= 1) ss += __shfl_down(ss, off, 64);
    if ((tid & 63) == 0) ws[tid >> 6] = ss;
    __syncthreads();
    if (tid == 0) nrm_s = fmaxf(sqrtf(ws[0] + ws[1] + ws[2] + ws[3]), 1e-12f);
    __syncthreads();
    const float inv = 1.0f / nrm_s;
    float ra = 0.0f;
    #pragma unroll
    for (int c = 0; c < 3; ++c) {
        float dx = v[c] * inv - x[(size_t)b * 768 + tid + c * 256];
        ra += dx * dx;
    }
    for (int off = 32; off > 0; off >>= 1) ra += __shfl_down(ra, off, 64);
    if ((tid & 63) == 0) ws[tid >> 6] = ra;
    __syncthreads();
    if (tid == 0) recon_row[b] = ws[0] + ws[1] + ws[2] + ws[3];
}

// ---------------------------------------------------------------------------
// Projected codebook: cbp fp32 linear + swizzled bf16 hi/lo planes + norms.
// ---------------------------------------------------------------------------
__global__ __launch_bounds__(128)
void proj_split_kernel(const float* __restrict__ cbl, const float* __restrict__ projl,
                       float* __restrict__ cbp, unsigned short* __restrict__ cbp_hi,
                       unsigned short* __restrict__ cbp_lo, float* __restrict__ cbn)
{
    __shared__ float cbs[8][128];
    __shared__ float wsum[8][2];
    const int tid = threadIdx.x;          // = d
    const int k0 = blockIdx.x * 8;

    #pragma unroll
    for (int i = 0; i < 2; ++i) {
        int idx4 = tid + i * 128;
        int r = idx4 >> 5, c4 = (idx4 & 31) * 4;
        *(float4*)&cbs[r][c4] = *(const float4*)&cbl[(size_t)(k0 + r) * 128 + c4];
    }
    __syncthreads();

    float acc[8] = {};
    for (int j4 = 0; j4 < 32; ++j4) {
        float4 pv = *(const float4*)&projl[(size_t)tid * 128 + j4 * 4];
        #pragma unroll
        for (int r = 0; r < 8; ++r) {
            float4 cv = *(float4*)&cbs[r][j4 * 4];
            acc[r] += pv.x * cv.x + pv.y * cv.y + pv.z * cv.z + pv.w * cv.w;
        }
    }
    #pragma unroll
    for (int r = 0; r < 8; ++r) {
        cbp[(size_t)(k0 + r) * 128 + tid] = acc[r];
        unsigned short h, l;
        split2(acc[r], h, l);
        const size_t o = swz(k0 + r, tid, 128);
        cbp_hi[o] = h;
        cbp_lo[o] = l;
        float v = acc[r] * acc[r];
        #pragma unroll
        for (int off = 32; off > 0; off >>= 1) v += __shfl_down(v, off, 64);
        if ((tid & 63) == 0) wsum[r][tid >> 6] = v;
    }
    __syncthreads();
    if (tid < 8) cbn[k0 + tid] = wsum[tid][0] + wsum[tid][1];
}

// ---------------------------------------------------------------------------
// MFMA distance argmin (swizzled planes; ids bit-identical to numpy).
// B (cbp hi/lo fragments) staged once per BLOCK into LDS via global_load_lds
// (double-buffered 2x32KB). STAGE(next) before compute(cur); __syncthreads()
// drains vmcnt so staging latency hides under the 192 MFMAs.
// ---------------------------------------------------------------------------
__device__ __forceinline__ unsigned int fkey(float s) {
    unsigned int u = __float_as_uint(s);
    return (u & 0x80000000u) ? ~u : (u | 0x80000000u);
}

__global__ __launch_bounds__(256, 2)
void argmin_mfma_kernel(const unsigned short* __restrict__ res_hi,
                        const unsigned short* __restrict__ res_lo,
                        const unsigned short* __restrict__ cbp_hi,
                        const unsigned short* __restrict__ cbp_lo,
                        const float* __restrict__ cbn,
                        unsigned long long* __restrict__ minkey)
{
    __shared__ unsigned short lds[32768];   // 2 buffers x 32 KB
    const int tid  = threadIdx.x;
    const int lane = tid & 63;
    const int w    = tid >> 6;
    const int ln   = lane & 15;
    const int grp  = lane >> 4;
    const int m0   = blockIdx.y * 128 + w * 32;
    const int c0b  = blockIdx.x * 256;

    // A fragments (held in registers for the whole kernel)
    bf16x8 a_hi[2][4], a_lo[2][4];
    #pragma unroll
    for (int mt = 0; mt < 2; ++mt) {
        #pragma unroll
        for (int s = 0; s < 4; ++s) {
            const size_t off =
                ((size_t)(((m0 >> 4) + mt) * 4 + s) << 9) + lane * 8;
            a_hi[mt][s] = *(const bf16x8*)&res_hi[off];
            a_lo[mt][s] = *(const bf16x8*)&res_lo[off];
        }
    }

    // Staging: per it, B data = 16 fragments x 1KB per plane. Waves 0,1 stage
    // hi halves; waves 2,3 stage lo halves; 8 x global_load_lds(16B) per wave.
    const unsigned short* splane = (w < 2) ? cbp_hi : cbp_lo;
    const unsigned lbase0 = (unsigned)((w >> 1) * 16384 + (w & 1) * 8192); // bytes

    auto STAGE = [&](int buf, int it) {
        const size_t g0 = (((size_t)(c0b >> 4) + it * 4) << 11)
                        + (w & 1) * 4096 + lane * 8;       // shorts
        const unsigned l0 = (unsigned)buf * 32768u + lbase0;  // bytes
        #pragma unroll
        for (int i = 0; i < 8; ++i) {
            __builtin_amdgcn_global_load_lds(
                (const __attribute__((address_space(1))) unsigned int*)(splane + g0 + i * 512),
                (__attribute__((address_space(3))) unsigned int*)((char*)lds + l0 + i * 1024),
                16, 0, 0);
        }
    };

    float best_s[2][4];
    int   best_c[2][4];
    #pragma unroll
    for (int mt = 0; mt < 2; ++mt)
        #pragma unroll
        for (int r = 0; r < 4; ++r) { best_s[mt][r] = 3.4e38f; best_c[mt][r] = 0; }

    STAGE(0, 0);
    __syncthreads();                        // drains vmcnt -> buf0 ready

    for (int it = 0; it < 4; ++it) {
        const int buf = it & 1;
        if (it < 3) STAGE(buf ^ 1, it + 1); // async prefetch into other buffer
        const unsigned short* lb = lds + buf * 16384;   // shorts
        const int c0 = c0b + it * 64;
        f32x4 acc[2][4] = {};
        #pragma unroll
        for (int s = 0; s < 4; ++s) {
            #pragma unroll
            for (int t = 0; t < 4; ++t) {
                const int fo = (t * 4 + s) * 512 + lane * 8;
                bf16x8 bh = *(const bf16x8*)&lb[fo];
                bf16x8 bl = *(const bf16x8*)&lb[fo + 8192];
                #pragma unroll
                for (int mt = 0; mt < 2; ++mt) {
                    acc[mt][t] = __builtin_amdgcn_mfma_f32_16x16x32_bf16(a_hi[mt][s], bh, acc[mt][t], 0, 0, 0);
                    acc[mt][t] = __builtin_amdgcn_mfma_f32_16x16x32_bf16(a_lo[mt][s], bh, acc[mt][t], 0, 0, 0);
                    acc[mt][t] = __builtin_amdgcn_mfma_f32_16x16x32_bf16(a_hi[mt][s], bl, acc[mt][t], 0, 0, 0);
                }
            }
        }
        #pragma unroll
        for (int t = 0; t < 4; ++t) {
            const int col = c0 + t * 16 + ln;
            const float cn = cbn[col];
            #pragma unroll
            for (int mt = 0; mt < 2; ++mt)
                #pragma unroll
                for (int r = 0; r < 4; ++r) {
                    float sc = fmaf(-2.0f, acc[mt][t][r], cn);
                    if (sc < best_s[mt][r]) {   // strict <: first col wins ties
                        best_s[mt][r] = sc;
                        best_c[mt][r] = col;
                    }
                }
        }
        if (it < 3) __syncthreads();        // next buf ready, cur buf free
    }

    #pragma unroll
    for (int mt = 0; mt < 2; ++mt)
        #pragma unroll
        for (int r = 0; r < 4; ++r) {
            unsigned long long b =
                ((unsigned long long)fkey(best_s[mt][r]) << 32)
                | (unsigned int)best_c[mt][r];
            #pragma unroll
            for (int off = 1; off < 16; off <<= 1) {
                unsigned lo32 = (unsigned)b, hi32 = (unsigned)(b >> 32);
                lo32 = __shfl_xor(lo32, off);
                hi32 = __shfl_xor(hi32, off);
                unsigned long long o = ((unsigned long long)hi32 << 32) | lo32;
                if (o < b) b = o;
            }
            if (ln == 0) atomicMin(&minkey[m0 + mt * 16 + grp * 4 + r], b);
        }
}

// ---------------------------------------------------------------------------
// Per-layer epilogue. layer==0 WRITES qloss/z (no memset needed); layer 2
// also emits z planes for the decoder.
// ---------------------------------------------------------------------------
__global__ __launch_bounds__(128)
void finalize_kernel(float* __restrict__ res, const float* __restrict__ cbp,
                     const unsigned long long* __restrict__ minkey,
                     float* __restrict__ qloss, float* __restrict__ z,
                     int* __restrict__ ids, float* __restrict__ embs_norm_out,
                     unsigned long long* __restrict__ keys,
                     unsigned short* __restrict__ res_hi,
                     unsigned short* __restrict__ res_lo,
                     unsigned short* __restrict__ z_hi,
                     unsigned short* __restrict__ z_lo, int layer)
{
    const int b = blockIdx.x;
    const int tid = threadIdx.x;
    const int id = (int)(minkey[b] & 0xFFFFFFFFull);
    float e = cbp[(size_t)id * 128 + tid];
    float r = res[(size_t)b * 128 + tid];
    float d = r - e;
    float v1 = d * d, v2 = e * e;
    for (int off = 32; off > 0; off >>= 1) {
        v1 += __shfl_down(v1, off, 64);
        v2 += __shfl_down(v2, off, 64);
    }
    __shared__ float ws[4];
    if ((tid & 63) == 0) { ws[(tid >> 6) * 2] = v1; ws[(tid >> 6) * 2 + 1] = v2; }
    __syncthreads();
    if (tid == 0) {
        float d2 = ws[0] + ws[2];
        float n2 = ws[1] + ws[3];
        float prev = (layer == 0) ? 0.0f : qloss[b];
        qloss[b] = prev + 1.25f * d2;           // emb_loss + 0.25*query_loss
        embs_norm_out[b * 3 + layer] = sqrtf(n2);
        ids[b * 3 + layer] = id;
        if (layer == 2) {
            keys[b] = (unsigned long long)ids[b * 3 + 0]
                    | ((unsigned long long)ids[b * 3 + 1] << 13)
                    | ((unsigned long long)id << 26);
        }
    }
    float zprev = (layer == 0) ? 0.0f : z[(size_t)b * 128 + tid];
    float nz = zprev + e;
    z[(size_t)b * 128 + tid] = nz;
    const size_t o = swz(b, tid, 128);
    if (layer == 2) {
        unsigned short zh, zl;
        split2(nz, zh, zl);
        z_hi[o] = zh;
        z_lo[o] = zl;
    }
    float nr = r - e;
    res[(size_t)b * 128 + tid] = nr;
    unsigned short h, l;
    split2(nr, h, l);
    res_hi[o] = h;
    res_lo[o] = l;
}

// ---------------------------------------------------------------------------
// Distinct-triple count via open-addressing hash set. Wave-aggregated count:
// ballot+popc -> ONE atomicAdd per wave (round 7's per-thread atomicAdd to a
// single address serialized ~7000 deep = 54 us). Deterministic (count of
// distinct keys is order-independent).
// ---------------------------------------------------------------------------
__global__ __launch_bounds__(256)
void uniq_hash_kernel(const unsigned long long* __restrict__ keys,
                      unsigned long long* __restrict__ table,
                      int* __restrict__ count)
{
    const int i = blockIdx.x * 256 + threadIdx.x;
    const unsigned long long k = keys[i];
    unsigned h = (unsigned)((k * 0x9E3779B97F4A7C15ull) >> 50);   // 14 bits
    bool ins = false;
    while (true) {
        unsigned long long old = atomicCAS(&table[h], ~0ULL, k);
        if (old == ~0ULL) { ins = true; break; }            // first insert
        if (old == k) break;                                // duplicate
        h = (h + 1) & 16383;
    }
    unsigned long long m = __ballot(ins);
    if ((threadIdx.x & 63) == 0) atomicAdd(count, (int)__popcll(m));
}

// ---------------------------------------------------------------------------
// Final scalars.
// ---------------------------------------------------------------------------
__global__ __launch_bounds__(256)
void scalars_kernel(const float* __restrict__ qloss,
                    const float* __restrict__ recon_row,
                    const int* __restrict__ count, float* __restrict__ out)
{
    const int tid = threadIdx.x;
    float qs = 0.0f, rs = 0.0f;
    for (int i = tid; i < 8192; i += 256) qs += qloss[i];
    for (int i = tid; i < 8192; i += 256) rs += recon_row[i];
    for (int off = 32; off > 0; off >>= 1) {
        qs += __shfl_down(qs, off, 64);
        rs += __shfl_down(rs, off, 64);
    }
    __shared__ float w[8];
    if ((tid & 63) == 0) { w[(tid >> 6) * 2] = qs; w[(tid >> 6) * 2 + 1] = rs; }
    __syncthreads();
    if (tid == 0) {
        float qsum = w[0] + w[2] + w[4] + w[6];
        float rsum = w[1] + w[3] + w[5] + w[7];
        float qmean = qsum / 8192.0f;
        out[0] = rsum + qmean;        // loss = (recon + qloss).mean()
        out[1] = rsum;                // recon
        out[2] = qmean;               // qloss.mean()
        out[24579] = (float)(*count) / 8192.0f;   // p_unique
    }
}

// ---------------------------------------------------------------------------
extern "C" void kernel_launch(void* const* d_in, const int* in_sizes, int n_in,
                              void* d_out, int out_size, void* d_ws, size_t ws_size,
                              hipStream_t stream)
{
    const float* x      = (const float*)d_in[0];
    const float* enc_w1 = (const float*)d_in[1];
    const float* enc_b1 = (const float*)d_in[2];
    const float* enc_w2 = (const float*)d_in[3];
    const float* enc_b2 = (const float*)d_in[4];
    const float* enc_w3 = (const float*)d_in[5];
    const float* enc_b3 = (const float*)d_in[6];
    const float* dec_w1 = (const float*)d_in[7];
    const float* dec_b1 = (const float*)d_in[8];
    const float* dec_w2 = (const float*)d_in[9];
    const float* dec_b2 = (const float*)d_in[10];
    const float* dec_w3 = (const float*)d_in[11];
    const float* dec_b3 = (const float*)d_in[12];
    const float* codebooks = (const float*)d_in[13];
    const float* projs     = (const float*)d_in[14];
    float* out = (float*)d_out;

    char* ws = (char*)d_ws;
    const size_t MB = 1024 * 1024;

    // --- region [0, 16M): encoder h1 f32 (swz) ; decoder g2_hi/g2_lo (swz)
    float* h1 = (float*)ws;                                        // 8192x512 f32
    unsigned short* g2_hi = (unsigned short*)ws;                   // 8192x512 bf16
    unsigned short* g2_lo = (unsigned short*)(ws + 8 * MB);
    // --- region [16M, 24M): encoder h2 f32 (swz) ; quant splits ; dec g1 (swz)
    float* h2 = (float*)(ws + 16 * MB);                            // 8192x256 f32
    unsigned short* res_hi = (unsigned short*)(ws + 16 * MB);      // 8192x128
    unsigned short* res_lo = (unsigned short*)(ws + 18 * MB);
    unsigned short* cbp_hi = (unsigned short*)(ws + 20 * MB);
    unsigned short* cbp_lo = (unsigned short*)(ws + 22 * MB);
    unsigned short* g1_hi  = (unsigned short*)(ws + 16 * MB);      // 8192x256 (decoder)
    unsigned short* g1_lo  = (unsigned short*)(ws + 20 * MB);
    // --- region [24M, 28M): res f32 (linear)
    float* res = (float*)(ws + 24 * MB);                           // 8192x128 f32
    // --- region [28M, 32M): cbp f32 (linear) ; decoder z_hi/z_lo (swz)
    float* cbp = (float*)(ws + 28 * MB);                           // 8192x128 f32
    unsigned short* z_hi = (unsigned short*)(ws + 28 * MB);        // 8192x128
    unsigned short* z_lo = (unsigned short*)(ws + 30 * MB);
    // --- region [32M, 36M): z f32 (linear)
    float* z = (float*)(ws + 32 * MB);                             // 8192x128 f32
    // --- region [36M, ...): weight splits (all swz) + small buffers
    char* p = ws + 36 * MB;
    unsigned short* dw1_hi = (unsigned short*)p; p += 256 * 128 * 2;
    unsigned short* dw1_lo = (unsigned short*)p; p += 256 * 128 * 2;
    unsigned short* dw2_hi = (unsigned short*)p; p += 512 * 256 * 2;
    unsigned short* dw2_lo = (unsigned short*)p; p += 512 * 256 * 2;
    unsigned short* dw3_hi = (unsigned short*)p; p += 768 * 512 * 2;
    unsigned short* dw3_lo = (unsigned short*)p; p += 768 * 512 * 2;
    unsigned short* ew1_h  = (unsigned short*)p; p += 512 * 768 * 2;
    unsigned short* ew1_m  = (unsigned short*)p; p += 512 * 768 * 2;
    unsigned short* ew1_l  = (unsigned short*)p; p += 512 * 768 * 2;
    unsigned short* ew2_h  = (unsigned short*)p; p += 256 * 512 * 2;
    unsigned short* ew2_m  = (unsigned short*)p; p += 256 * 512 * 2;
    unsigned short* ew2_l  = (unsigned short*)p; p += 256 * 512 * 2;
    unsigned short* ew3_h  = (unsigned short*)p; p += 128 * 256 * 2;
    unsigned short* ew3_m  = (unsigned short*)p; p += 128 * 256 * 2;
    unsigned short* ew3_l  = (unsigned short*)p; p += 128 * 256 * 2;
    float* cbn       = (float*)p; p += 8192 * 4;
    float* qloss     = (float*)p; p += 8192 * 4;
    float* recon_row = (float*)p; p += 8192 * 4;
    unsigned long long* minkey = (unsigned long long*)p; p += 8192 * 8;
    unsigned long long* keys   = (unsigned long long*)p; p += 8192 * 8;
    unsigned long long* table  = (unsigned long long*)p; p += 16384 * 8;
    int* ids   = (int*)p; p += 8192 * 3 * 4;
    int* count = (int*)p; p += 256;                      // pad to alignment
    unsigned short* xhat = (unsigned short*)p; p += (size_t)8192 * 768 * 2;
    // optional x swizzle buffer (24 MB) — only if workspace is big enough
    float* xs = (float*)p;
    const bool use_xs =
        ((size_t)(p - ws) + (size_t)8192 * 768 * 4) <= ws_size;

    hipMemsetAsync(count, 0, sizeof(int), stream);
    hipMemsetAsync(table, 0xFF, 16384 * sizeof(unsigned long long), stream);

    // all 6 weight splits fused into one dispatch
    prep_weights_kernel<<<4352, 256, 0, stream>>>(
        dec_w1, dec_w2, dec_w3, enc_w1, enc_w2, enc_w3,
        dw1_hi, dw1_lo, dw2_hi, dw2_lo, dw3_hi, dw3_lo,
        ew1_h, ew1_m, ew1_l, ew2_h, ew2_m, ew2_l, ew3_h, ew3_m, ew3_l);

    // encoder (exact-split MFMA, fp32-faithful); h1/h2 swizzled fp32;
    // enc3 epilogue also emits res_hi/res_lo (swz split2) directly
    if (use_xs) {
        swzf32_kernel<768><<<3072, 256, 0, stream>>>(x, xs);
        mfma_enc_kernel<512, 768, 1, 1, 1, 0><<<dim3(8, 64), 256, 0, stream>>>(
            xs, ew1_h, ew1_m, ew1_l, enc_b1, h1, nullptr, nullptr);
    } else {
        mfma_enc_kernel<512, 768, 1, 0, 1, 0><<<dim3(8, 64), 256, 0, stream>>>(
            x, ew1_h, ew1_m, ew1_l, enc_b1, h1, nullptr, nullptr);
    }
    mfma_enc_kernel<256, 512, 1, 1, 1, 0><<<dim3(4, 64), 256, 0, stream>>>(
        h1, ew2_h, ew2_m, ew2_l, enc_b2, h2, nullptr, nullptr);
    mfma_enc_kernel<128, 256, 0, 1, 0, 1><<<dim3(2, 64), 256, 0, stream>>>(
        h2, ew3_h, ew3_m, ew3_l, enc_b3, res, res_hi, res_lo);

    // residual quantization layers
    for (int l = 0; l < 3; ++l) {
        proj_split_kernel<<<1024, 128, 0, stream>>>(codebooks + (size_t)l * 8192 * 128,
                                                    projs + (size_t)l * 128 * 128,
                                                    cbp, cbp_hi, cbp_lo, cbn);
        hipMemsetAsync(minkey, 0xFF, 8192 * sizeof(unsigned long long), stream);
        argmin_mfma_kernel<<<dim3(32, 64), 256, 0, stream>>>(res_hi, res_lo,
                                                             cbp_hi, cbp_lo, cbn, minkey);
        finalize_kernel<<<8192, 128, 0, stream>>>(res, cbp, minkey, qloss, z,
                                                  ids, out + 3, keys,
                                                  res_hi, res_lo, z_hi, z_lo, l);
    }

    // decoder (split-precision MFMA, swizzled planes; z planes from finalize)
    mfma_gemm_kernel<256, 128, 1, 0><<<dim3(2, 64), 256, 0, stream>>>(
        z_hi, z_lo, dw1_hi, dw1_lo, dec_b1, g1_hi, g1_lo);
    mfma_gemm_kernel<512, 256, 1, 0><<<dim3(4, 64), 256, 0, stream>>>(
        g1_hi, g1_lo, dw2_hi, dw2_lo, dec_b2, g2_hi, g2_lo);
    mfma_gemm_kernel<768, 512, 2, 1><<<dim3(6, 64), 256, 0, stream>>>(
        g2_hi, g2_lo, dw3_hi, dw3_lo, dec_b3, xhat, nullptr);
    norm_recon_kernel<<<8192, 256, 0, stream>>>(xhat, x, recon_row);

    // diagnostics
    uniq_hash_kernel<<<32, 256, 0, stream>>>(keys, table, count);
    scalars_kernel<<<1, 256, 0, stream>>>(qloss, recon_row, count, out);
}

// Round 9
// 462.081 us; speedup vs baseline: 5.4884x; 1.1122x over previous
//
#include <hip/hip_runtime.h>
#include <hip/hip_bf16.h>
#include <math.h>

// Problem constants
#define B_  8192
#define IN_ 768
#define D_  128
#define K_  8192
#define L_  3

typedef __attribute__((ext_vector_type(8))) short bf16x8;
typedef __attribute__((ext_vector_type(4))) float f32x4;

// ---------------------------------------------------------------------------
// Fragment-major swizzled layout for a [R][C] matrix (R%16==0, C%32==0):
//   off(row,k) = ((row>>4)*(C/32) + (k>>5))*512 + ((k>>3)&3)*128 + (row&15)*8 + (k&7)
// MFMA fragment load (row-tile rt, k-slice s) for lane l is then
//   plane + ((rt*(C/32)+s)<<9) + l*8   -> fully coalesced 16B/lane (bf16).
// Fragments are contiguous 1 KB chunks -> ideal for global_load_lds staging.
// ---------------------------------------------------------------------------
__device__ __forceinline__ size_t swz(int row, int col, int C)
{
    return ((size_t)((row >> 4) * (C >> 5) + (col >> 5)) << 9)
         + (((col >> 3) & 3) << 7) + ((row & 15) << 3) + (col & 7);
}

// Split f into hi (bf16 RNE) + lo (bf16 RNE of remainder). ~2^-18 rel error.
__device__ __forceinline__ void split2(float f, unsigned short& h, unsigned short& l)
{
    unsigned u = __float_as_uint(f);
    unsigned hb = (u + 0x7FFFu + ((u >> 16) & 1u)) & 0xFFFF0000u;
    h = (unsigned short)(hb >> 16);
    float r = f - __uint_as_float(hb);
    unsigned v = __float_as_uint(r);
    l = (unsigned short)((v + 0x7FFFu + ((v >> 16) & 1u)) >> 16);
}

// Triple split: f = h + m + l, covers all 24 fp32 mantissa bits (~2^-27).
__device__ __forceinline__ void split3(float f, unsigned short& h,
                                       unsigned short& m, unsigned short& l)
{
    unsigned u = __float_as_uint(f);
    unsigned hb = (u + 0x7FFFu + ((u >> 16) & 1u)) & 0xFFFF0000u;
    h = (unsigned short)(hb >> 16);
    float r1 = f - __uint_as_float(hb);
    unsigned v = __float_as_uint(r1);
    unsigned mb = (v + 0x7FFFu + ((v >> 16) & 1u)) & 0xFFFF0000u;
    m = (unsigned short)(mb >> 16);
    float r2 = r1 - __uint_as_float(mb);
    unsigned w = __float_as_uint(r2);
    l = (unsigned short)((w + 0x7FFFu + ((w >> 16) & 1u)) >> 16);
}

__device__ __forceinline__ unsigned short bf16_rne(float f)
{
    unsigned u = __float_as_uint(f);
    return (unsigned short)((u + 0x7FFFu + ((u >> 16) & 1u)) >> 16);
}

// ---------------------------------------------------------------------------
// fp32 [R][C] linear -> swizzled permutation (pure layout; values identical).
// ---------------------------------------------------------------------------
template<int C>
__global__ __launch_bounds__(256)
void swzf32_kernel(const float* __restrict__ src, float* __restrict__ dst)
{
    const int i = blockIdx.x * 256 + threadIdx.x;
    const int row = i / (C / 8);
    const int col = (i - row * (C / 8)) * 8;
    float4 a = *(const float4*)&src[(size_t)row * C + col];
    float4 b = *(const float4*)&src[(size_t)row * C + col + 4];
    const size_t o = swz(row, col, C);
    *(float4*)&dst[o] = a;
    *(float4*)&dst[o + 4] = b;
}

// ---------------------------------------------------------------------------
// Fused weight prep: all 6 weight matrices -> swizzled bf16 planes in ONE
// dispatch. dec weights: split2 (2 planes); enc weights: split3 (3 planes).
// ---------------------------------------------------------------------------
__global__ __launch_bounds__(256)
void prep_weights_kernel(const float* __restrict__ dw1, const float* __restrict__ dw2,
                         const float* __restrict__ dw3, const float* __restrict__ ew1,
                         const float* __restrict__ ew2, const float* __restrict__ ew3,
                         unsigned short* __restrict__ dw1h, unsigned short* __restrict__ dw1l,
                         unsigned short* __restrict__ dw2h, unsigned short* __restrict__ dw2l,
                         unsigned short* __restrict__ dw3h, unsigned short* __restrict__ dw3l,
                         unsigned short* __restrict__ e1h, unsigned short* __restrict__ e1m,
                         unsigned short* __restrict__ e1l,
                         unsigned short* __restrict__ e2h, unsigned short* __restrict__ e2m,
                         unsigned short* __restrict__ e2l,
                         unsigned short* __restrict__ e3h, unsigned short* __restrict__ e3m,
                         unsigned short* __restrict__ e3l)
{
    const int b = blockIdx.x;
    const float* src;
    unsigned short *H, *M = nullptr, *L;
    int kc, idx0;
    bool three;
    if (b < 128)       { src = dw1; H = dw1h; L = dw1l; kc = 128; three = false; idx0 = b * 256; }
    else if (b < 640)  { src = dw2; H = dw2h; L = dw2l; kc = 256; three = false; idx0 = (b - 128) * 256; }
    else if (b < 2176) { src = dw3; H = dw3h; L = dw3l; kc = 512; three = false; idx0 = (b - 640) * 256; }
    else if (b < 3712) { src = ew1; H = e1h; M = e1m; L = e1l; kc = 768; three = true; idx0 = (b - 2176) * 256; }
    else if (b < 4224) { src = ew2; H = e2h; M = e2m; L = e2l; kc = 512; three = true; idx0 = (b - 3712) * 256; }
    else               { src = ew3; H = e3h; M = e3m; L = e3l; kc = 256; three = true; idx0 = (b - 4224) * 256; }

    const int idx = idx0 + threadIdx.x;
    const int row = idx / kc, col = idx - row * kc;
    const size_t o = swz(row, col, kc);
    const float f = src[idx];
    if (three) {
        unsigned short h, m, l;
        split3(f, h, m, l);
        H[o] = h; M[o] = m; L[o] = l;
    } else {
        unsigned short h, l;
        split2(f, h, l);
        H[o] = h; L[o] = l;
    }
}

// ---------------------------------------------------------------------------
// Encoder MFMA GEMM, fp32-faithful: C = act(A @ W^T + bias).
// A fp32 (linear if ASWZ=0, swizzled if 1), triple-split in-register; W in 3
// swizzled bf16 planes. 6 MFMA passes -> ~1e-6 rel error (argmin-id safe).
// BM=128 (4 waves x 2 m-tiles), BN=64 (4 n-tiles), K-step 32.
// ACT: 0=none, 1=silu. CSWZ: fp32 out linear(0)/swizzled(1).
// OUT2: additionally write split2 bf16 planes (swz) of the output (enc3).
// ---------------------------------------------------------------------------
template<int N, int K, int ACT, int ASWZ, int CSWZ, int OUT2>
__global__ __launch_bounds__(256)
void mfma_enc_kernel(const float* __restrict__ A,
                     const unsigned short* __restrict__ Wh,
                     const unsigned short* __restrict__ Wm,
                     const unsigned short* __restrict__ Wl,
                     const float* __restrict__ bias, float* __restrict__ C,
                     unsigned short* __restrict__ Rh,
                     unsigned short* __restrict__ Rl)
{
    const int tid  = threadIdx.x;
    const int lane = tid & 63;
    const int w    = tid >> 6;
    const int ln   = lane & 15;
    const int grp  = lane >> 4;
    const int m0   = blockIdx.y * 128 + w * 32;
    const int n0   = blockIdx.x * 64;

    f32x4 acc[2][4] = {};

    for (int ks = 0; ks < K; ks += 32) {
        const int s = ks >> 5;
        bf16x8 ah[2], am[2], al[2];
        #pragma unroll
        for (int mt = 0; mt < 2; ++mt) {
            float4 f0, f1;
            if (ASWZ) {
                const size_t base =
                    ((size_t)(((m0 >> 4) + mt) * (K >> 5) + s) << 9) + lane * 8;
                f0 = *(const float4*)&A[base];
                f1 = *(const float4*)&A[base + 4];
            } else {
                const size_t off = (size_t)(m0 + mt * 16 + ln) * K + ks + grp * 8;
                f0 = *(const float4*)&A[off];
                f1 = *(const float4*)&A[off + 4];
            }
            float fv[8] = {f0.x, f0.y, f0.z, f0.w, f1.x, f1.y, f1.z, f1.w};
            #pragma unroll
            for (int e = 0; e < 8; ++e) {
                unsigned short hh, mm, ll;
                split3(fv[e], hh, mm, ll);
                ah[mt][e] = (short)hh;
                am[mt][e] = (short)mm;
                al[mt][e] = (short)ll;
            }
        }
        #pragma unroll
        for (int nt = 0; nt < 4; ++nt) {
            const size_t off =
                ((size_t)(((n0 >> 4) + nt) * (K >> 5) + s) << 9) + lane * 8;
            bf16x8 bh = *(const bf16x8*)&Wh[off];
            bf16x8 bm = *(const bf16x8*)&Wm[off];
            bf16x8 bl = *(const bf16x8*)&Wl[off];
            #pragma unroll
            for (int mt = 0; mt < 2; ++mt) {
                acc[mt][nt] = __builtin_amdgcn_mfma_f32_16x16x32_bf16(ah[mt], bh, acc[mt][nt], 0, 0, 0);
                acc[mt][nt] = __builtin_amdgcn_mfma_f32_16x16x32_bf16(am[mt], bh, acc[mt][nt], 0, 0, 0);
                acc[mt][nt] = __builtin_amdgcn_mfma_f32_16x16x32_bf16(ah[mt], bm, acc[mt][nt], 0, 0, 0);
                acc[mt][nt] = __builtin_amdgcn_mfma_f32_16x16x32_bf16(al[mt], bh, acc[mt][nt], 0, 0, 0);
                acc[mt][nt] = __builtin_amdgcn_mfma_f32_16x16x32_bf16(am[mt], bm, acc[mt][nt], 0, 0, 0);
                acc[mt][nt] = __builtin_amdgcn_mfma_f32_16x16x32_bf16(ah[mt], bl, acc[mt][nt], 0, 0, 0);
            }
        }
    }

    #pragma unroll
    for (int nt = 0; nt < 4; ++nt) {
        const int col = n0 + nt * 16 + ln;
        const float bv = bias[col];
        #pragma unroll
        for (int mt = 0; mt < 2; ++mt) {
            #pragma unroll
            for (int r = 0; r < 4; ++r) {
                const int row = m0 + mt * 16 + grp * 4 + r;
                float v = acc[mt][nt][r] + bv;
                if (ACT == 1) v = v / (1.0f + expf(-v));
                if (CSWZ) C[swz(row, col, N)] = v;
                else      C[(size_t)row * N + col] = v;
                if (OUT2) {
                    unsigned short h, l;
                    split2(v, h, l);
                    const size_t o = swz(row, col, N);
                    Rh[o] = h;
                    Rl[o] = l;
                }
            }
        }
    }
}

// ---------------------------------------------------------------------------
// Split-precision MFMA GEMM (decoder): A,W as swizzled bf16 hi/lo planes;
// dot = hh + lh + hl (~2^-17 rel, only affects recon/loss, ~2% tolerance).
// BM=128, BN=128, K-step 32. ACT: 1=silu, 2=sigmoid.
// OUT: 0=swizzled bf16 hi/lo pair, 1=linear single bf16.
// ---------------------------------------------------------------------------
template<int N, int K, int ACT, int OUT>
__global__ __launch_bounds__(256)
void mfma_gemm_kernel(const unsigned short* __restrict__ A_hi,
                      const unsigned short* __restrict__ A_lo,
                      const unsigned short* __restrict__ W_hi,
                      const unsigned short* __restrict__ W_lo,
                      const float* __restrict__ bias,
                      unsigned short* __restrict__ C_hi,
                      unsigned short* __restrict__ C_lo)
{
    const int tid  = threadIdx.x;
    const int lane = tid & 63;
    const int w    = tid >> 6;
    const int ln   = lane & 15;
    const int grp  = lane >> 4;
    const int m0   = blockIdx.y * 128 + w * 32;
    const int n0   = blockIdx.x * 128;

    f32x4 acc[2][8] = {};

    for (int ks = 0; ks < K; ks += 32) {
        const int s = ks >> 5;
        bf16x8 ah[2], al[2];
        #pragma unroll
        for (int mt = 0; mt < 2; ++mt) {
            const size_t off =
                ((size_t)(((m0 >> 4) + mt) * (K >> 5) + s) << 9) + lane * 8;
            ah[mt] = *(const bf16x8*)&A_hi[off];
            al[mt] = *(const bf16x8*)&A_lo[off];
        }
        #pragma unroll
        for (int nt = 0; nt < 8; ++nt) {
            const size_t off =
                ((size_t)(((n0 >> 4) + nt) * (K >> 5) + s) << 9) + lane * 8;
            bf16x8 bh = *(const bf16x8*)&W_hi[off];
            bf16x8 bl = *(const bf16x8*)&W_lo[off];
            #pragma unroll
            for (int mt = 0; mt < 2; ++mt) {
                acc[mt][nt] = __builtin_amdgcn_mfma_f32_16x16x32_bf16(ah[mt], bh, acc[mt][nt], 0, 0, 0);
                acc[mt][nt] = __builtin_amdgcn_mfma_f32_16x16x32_bf16(al[mt], bh, acc[mt][nt], 0, 0, 0);
                acc[mt][nt] = __builtin_amdgcn_mfma_f32_16x16x32_bf16(ah[mt], bl, acc[mt][nt], 0, 0, 0);
            }
        }
    }

    #pragma unroll
    for (int nt = 0; nt < 8; ++nt) {
        const int col = n0 + nt * 16 + ln;
        const float bv = bias[col];
        #pragma unroll
        for (int mt = 0; mt < 2; ++mt) {
            #pragma unroll
            for (int r = 0; r < 4; ++r) {
                const int row = m0 + mt * 16 + grp * 4 + r;
                float v = acc[mt][nt][r] + bv;
                if (ACT == 1) v = v / (1.0f + expf(-v));
                if (ACT == 2) v = 1.0f / (1.0f + expf(-v));
                if (OUT == 0) {
                    unsigned short h, l;
                    split2(v, h, l);
                    const size_t o = swz(row, col, N);
                    C_hi[o] = h;
                    C_lo[o] = l;
                } else {
                    C_hi[(size_t)row * N + col] = bf16_rne(v);
                }
            }
        }
    }
}

// ---------------------------------------------------------------------------
// Per-row L2 normalize + recon partial.
// ---------------------------------------------------------------------------
__global__ __launch_bounds__(256)
void norm_recon_kernel(const unsigned short* __restrict__ xhat,
                       const float* __restrict__ x,
                       float* __restrict__ recon_row)
{
    const int b = blockIdx.x;
    const int tid = threadIdx.x;
    __shared__ float ws[4];
    __shared__ float nrm_s;

    float v[3];
    float ss = 0.0f;
    #pragma unroll
    for (int c = 0; c < 3; ++c) {
        unsigned short u = xhat[(size_t)b * 768 + tid + c * 256];
        v[c] = __uint_as_float((unsigned)u << 16);
        ss += v[c] * v[c];
    }
    for (int off = 32; off > 0; off >>= 1) ss += __shfl_down(ss, off, 64);
    if ((tid & 63) == 0) ws[tid >> 6] = ss;
    __syncthreads();
    if (tid == 0) nrm_s = fmaxf(sqrtf(ws[0] + ws[1] + ws[2] + ws[3]), 1e-12f);
    __syncthreads();
    const float inv = 1.0f / nrm_s;
    float ra = 0.0f;
    #pragma unroll
    for (int c = 0; c < 3; ++c) {
        float dx = v[c] * inv - x[(size_t)b * 768 + tid + c * 256];
        ra += dx * dx;
    }
    for (int off = 32; off > 0; off >>= 1) ra += __shfl_down(ra, off, 64);
    if ((tid & 63) == 0) ws[tid >> 6] = ra;
    __syncthreads();
    if (tid == 0) recon_row[b] = ws[0] + ws[1] + ws[2] + ws[3];
}

// ---------------------------------------------------------------------------
// Projected codebook: cbp fp32 linear + swizzled bf16 hi/lo planes + norms.
// ---------------------------------------------------------------------------
__global__ __launch_bounds__(128)
void proj_split_kernel(const float* __restrict__ cbl, const float* __restrict__ projl,
                       float* __restrict__ cbp, unsigned short* __restrict__ cbp_hi,
                       unsigned short* __restrict__ cbp_lo, float* __restrict__ cbn)
{
    __shared__ float cbs[8][128];
    __shared__ float wsum[8][2];
    const int tid = threadIdx.x;          // = d
    const int k0 = blockIdx.x * 8;

    #pragma unroll
    for (int i = 0; i < 2; ++i) {
        int idx4 = tid + i * 128;
        int r = idx4 >> 5, c4 = (idx4 & 31) * 4;
        *(float4*)&cbs[r][c4] = *(const float4*)&cbl[(size_t)(k0 + r) * 128 + c4];
    }
    __syncthreads();

    float acc[8] = {};
    for (int j4 = 0; j4 < 32; ++j4) {
        float4 pv = *(const float4*)&projl[(size_t)tid * 128 + j4 * 4];
        #pragma unroll
        for (int r = 0; r < 8; ++r) {
            float4 cv = *(float4*)&cbs[r][j4 * 4];
            acc[r] += pv.x * cv.x + pv.y * cv.y + pv.z * cv.z + pv.w * cv.w;
        }
    }
    #pragma unroll
    for (int r = 0; r < 8; ++r) {
        cbp[(size_t)(k0 + r) * 128 + tid] = acc[r];
        unsigned short h, l;
        split2(acc[r], h, l);
        const size_t o = swz(k0 + r, tid, 128);
        cbp_hi[o] = h;
        cbp_lo[o] = l;
        float v = acc[r] * acc[r];
        #pragma unroll
        for (int off = 32; off > 0; off >>= 1) v += __shfl_down(v, off, 64);
        if ((tid & 63) == 0) wsum[r][tid >> 6] = v;
    }
    __syncthreads();
    if (tid < 8) cbn[k0 + tid] = wsum[tid][0] + wsum[tid][1];
}

// ---------------------------------------------------------------------------
// MFMA distance argmin (swizzled planes; ids bit-identical to numpy).
// B staged per-block into LDS via global_load_lds (double-buffered 2x32KB).
// ---------------------------------------------------------------------------
__device__ __forceinline__ unsigned int fkey(float s) {
    unsigned int u = __float_as_uint(s);
    return (u & 0x80000000u) ? ~u : (u | 0x80000000u);
}

__global__ __launch_bounds__(256, 2)
void argmin_mfma_kernel(const unsigned short* __restrict__ res_hi,
                        const unsigned short* __restrict__ res_lo,
                        const unsigned short* __restrict__ cbp_hi,
                        const unsigned short* __restrict__ cbp_lo,
                        const float* __restrict__ cbn,
                        unsigned long long* __restrict__ minkey)
{
    __shared__ unsigned short lds[32768];   // 2 buffers x 32 KB
    const int tid  = threadIdx.x;
    const int lane = tid & 63;
    const int w    = tid >> 6;
    const int ln   = lane & 15;
    const int grp  = lane >> 4;
    const int m0   = blockIdx.y * 128 + w * 32;
    const int c0b  = blockIdx.x * 256;

    // A fragments (held in registers for the whole kernel)
    bf16x8 a_hi[2][4], a_lo[2][4];
    #pragma unroll
    for (int mt = 0; mt < 2; ++mt) {
        #pragma unroll
        for (int s = 0; s < 4; ++s) {
            const size_t off =
                ((size_t)(((m0 >> 4) + mt) * 4 + s) << 9) + lane * 8;
            a_hi[mt][s] = *(const bf16x8*)&res_hi[off];
            a_lo[mt][s] = *(const bf16x8*)&res_lo[off];
        }
    }

    // Staging: waves 0,1 stage hi halves; waves 2,3 stage lo halves.
    const unsigned short* splane = (w < 2) ? cbp_hi : cbp_lo;
    const unsigned lbase0 = (unsigned)((w >> 1) * 16384 + (w & 1) * 8192); // bytes

    auto STAGE = [&](int buf, int it) {
        const size_t g0 = (((size_t)(c0b >> 4) + it * 4) << 11)
                        + (w & 1) * 4096 + lane * 8;       // shorts
        const unsigned l0 = (unsigned)buf * 32768u + lbase0;  // bytes
        #pragma unroll
        for (int i = 0; i < 8; ++i) {
            __builtin_amdgcn_global_load_lds(
                (const __attribute__((address_space(1))) unsigned int*)(splane + g0 + i * 512),
                (__attribute__((address_space(3))) unsigned int*)((char*)lds + l0 + i * 1024),
                16, 0, 0);
        }
    };

    float best_s[2][4];
    int   best_c[2][4];
    #pragma unroll
    for (int mt = 0; mt < 2; ++mt)
        #pragma unroll
        for (int r = 0; r < 4; ++r) { best_s[mt][r] = 3.4e38f; best_c[mt][r] = 0; }

    STAGE(0, 0);
    __syncthreads();                        // drains vmcnt -> buf0 ready

    for (int it = 0; it < 4; ++it) {
        const int buf = it & 1;
        if (it < 3) STAGE(buf ^ 1, it + 1); // async prefetch into other buffer
        const unsigned short* lb = lds + buf * 16384;   // shorts
        const int c0 = c0b + it * 64;
        f32x4 acc[2][4] = {};
        #pragma unroll
        for (int s = 0; s < 4; ++s) {
            #pragma unroll
            for (int t = 0; t < 4; ++t) {
                const int fo = (t * 4 + s) * 512 + lane * 8;
                bf16x8 bh = *(const bf16x8*)&lb[fo];
                bf16x8 bl = *(const bf16x8*)&lb[fo + 8192];
                #pragma unroll
                for (int mt = 0; mt < 2; ++mt) {
                    acc[mt][t] = __builtin_amdgcn_mfma_f32_16x16x32_bf16(a_hi[mt][s], bh, acc[mt][t], 0, 0, 0);
                    acc[mt][t] = __builtin_amdgcn_mfma_f32_16x16x32_bf16(a_lo[mt][s], bh, acc[mt][t], 0, 0, 0);
                    acc[mt][t] = __builtin_amdgcn_mfma_f32_16x16x32_bf16(a_hi[mt][s], bl, acc[mt][t], 0, 0, 0);
                }
            }
        }
        #pragma unroll
        for (int t = 0; t < 4; ++t) {
            const int col = c0 + t * 16 + ln;
            const float cn = cbn[col];
            #pragma unroll
            for (int mt = 0; mt < 2; ++mt)
                #pragma unroll
                for (int r = 0; r < 4; ++r) {
                    float sc = fmaf(-2.0f, acc[mt][t][r], cn);
                    if (sc < best_s[mt][r]) {   // strict <: first col wins ties
                        best_s[mt][r] = sc;
                        best_c[mt][r] = col;
                    }
                }
        }
        if (it < 3) __syncthreads();        // next buf ready, cur buf free
    }

    #pragma unroll
    for (int mt = 0; mt < 2; ++mt)
        #pragma unroll
        for (int r = 0; r < 4; ++r) {
            unsigned long long b =
                ((unsigned long long)fkey(best_s[mt][r]) << 32)
                | (unsigned int)best_c[mt][r];
            #pragma unroll
            for (int off = 1; off < 16; off <<= 1) {
                unsigned lo32 = (unsigned)b, hi32 = (unsigned)(b >> 32);
                lo32 = __shfl_xor(lo32, off);
                hi32 = __shfl_xor(hi32, off);
                unsigned long long o = ((unsigned long long)hi32 << 32) | lo32;
                if (o < b) b = o;
            }
            if (ln == 0) atomicMin(&minkey[m0 + mt * 16 + grp * 4 + r], b);
        }
}

// ---------------------------------------------------------------------------
// Per-layer epilogue. layer==0 WRITES qloss/z (no memset needed); layer 2
// also emits z planes for the decoder.
// ---------------------------------------------------------------------------
__global__ __launch_bounds__(128)
void finalize_kernel(float* __restrict__ res, const float* __restrict__ cbp,
                     const unsigned long long* __restrict__ minkey,
                     float* __restrict__ qloss, float* __restrict__ z,
                     int* __restrict__ ids, float* __restrict__ embs_norm_out,
                     unsigned long long* __restrict__ keys,
                     unsigned short* __restrict__ res_hi,
                     unsigned short* __restrict__ res_lo,
                     unsigned short* __restrict__ z_hi,
                     unsigned short* __restrict__ z_lo, int layer)
{
    const int b = blockIdx.x;
    const int tid = threadIdx.x;
    const int id = (int)(minkey[b] & 0xFFFFFFFFull);
    float e = cbp[(size_t)id * 128 + tid];
    float r = res[(size_t)b * 128 + tid];
    float d = r - e;
    float v1 = d * d, v2 = e * e;
    for (int off = 32; off > 0; off >>= 1) {
        v1 += __shfl_down(v1, off, 64);
        v2 += __shfl_down(v2, off, 64);
    }
    __shared__ float ws[4];
    if ((tid & 63) == 0) { ws[(tid >> 6) * 2] = v1; ws[(tid >> 6) * 2 + 1] = v2; }
    __syncthreads();
    if (tid == 0) {
        float d2 = ws[0] + ws[2];
        float n2 = ws[1] + ws[3];
        float prev = (layer == 0) ? 0.0f : qloss[b];
        qloss[b] = prev + 1.25f * d2;           // emb_loss + 0.25*query_loss
        embs_norm_out[b * 3 + layer] = sqrtf(n2);
        ids[b * 3 + layer] = id;
        if (layer == 2) {
            keys[b] = (unsigned long long)ids[b * 3 + 0]
                    | ((unsigned long long)ids[b * 3 + 1] << 13)
                    | ((unsigned long long)id << 26);
        }
    }
    float zprev = (layer == 0) ? 0.0f : z[(size_t)b * 128 + tid];
    float nz = zprev + e;
    z[(size_t)b * 128 + tid] = nz;
    const size_t o = swz(b, tid, 128);
    if (layer == 2) {
        unsigned short zh, zl;
        split2(nz, zh, zl);
        z_hi[o] = zh;
        z_lo[o] = zl;
    }
    float nr = r - e;
    res[(size_t)b * 128 + tid] = nr;
    unsigned short h, l;
    split2(nr, h, l);
    res_hi[o] = h;
    res_lo[o] = l;
}

// ---------------------------------------------------------------------------
// Distinct-triple count. Round 8 post-mortem: nearly all rows share the same
// triple -> ~8000 same-address atomicCAS serialize at ~6.7ns = the whole
// 54us. Fix: WAVE MATCH-ANY dedup first (iterations = #distinct keys in the
// wave; ~1-2 here), then only per-wave leaders (~128, not 8192) touch the
// global table. Deterministic: count = #distinct keys, order-independent.
// ---------------------------------------------------------------------------
__global__ __launch_bounds__(256)
void uniq_hash_kernel(const unsigned long long* __restrict__ keys,
                      unsigned long long* __restrict__ table,
                      int* __restrict__ count)
{
    const int i = blockIdx.x * 256 + threadIdx.x;
    const int lane = threadIdx.x & 63;
    const unsigned long long k = keys[i];

    // wave match-any: elect one leader lane per distinct key
    bool resolved = false, leader = false;
    while (true) {
        unsigned long long unres = __ballot(!resolved);
        if (unres == 0) break;
        const int src = (int)(__ffsll((long long)unres) - 1);
        unsigned slo = __shfl((unsigned)k, src);
        unsigned shi = __shfl((unsigned)(k >> 32), src);
        unsigned long long kk = ((unsigned long long)shi << 32) | slo;
        if (!resolved && k == kk) {
            resolved = true;
            leader = (lane == src);
        }
    }

    bool ins = false;
    if (leader) {
        unsigned h = (unsigned)((k * 0x9E3779B97F4A7C15ull) >> 50);   // 14 bits
        while (true) {
            unsigned long long old = atomicCAS(&table[h], ~0ULL, k);
            if (old == ~0ULL) { ins = true; break; }        // first insert
            if (old == k) break;                            // duplicate
            h = (h + 1) & 16383;
        }
    }
    unsigned long long m = __ballot(ins);
    if (lane == 0 && m) atomicAdd(count, (int)__popcll(m));
}

// ---------------------------------------------------------------------------
// Final scalars.
// ---------------------------------------------------------------------------
__global__ __launch_bounds__(256)
void scalars_kernel(const float* __restrict__ qloss,
                    const float* __restrict__ recon_row,
                    const int* __restrict__ count, float* __restrict__ out)
{
    const int tid = threadIdx.x;
    float qs = 0.0f, rs = 0.0f;
    for (int i = tid; i < 8192; i += 256) qs += qloss[i];
    for (int i = tid; i < 8192; i += 256) rs += recon_row[i];
    for (int off = 32; off > 0; off >>= 1) {
        qs += __shfl_down(qs, off, 64);
        rs += __shfl_down(rs, off, 64);
    }
    __shared__ float w[8];
    if ((tid & 63) == 0) { w[(tid >> 6) * 2] = qs; w[(tid >> 6) * 2 + 1] = rs; }
    __syncthreads();
    if (tid == 0) {
        float qsum = w[0] + w[2] + w[4] + w[6];
        float rsum = w[1] + w[3] + w[5] + w[7];
        float qmean = qsum / 8192.0f;
        out[0] = rsum + qmean;        // loss = (recon + qloss).mean()
        out[1] = rsum;                // recon
        out[2] = qmean;               // qloss.mean()
        out[24579] = (float)(*count) / 8192.0f;   // p_unique
    }
}

// ---------------------------------------------------------------------------
extern "C" void kernel_launch(void* const* d_in, const int* in_sizes, int n_in,
                              void* d_out, int out_size, void* d_ws, size_t ws_size,
                              hipStream_t stream)
{
    const float* x      = (const float*)d_in[0];
    const float* enc_w1 = (const float*)d_in[1];
    const float* enc_b1 = (const float*)d_in[2];
    const float* enc_w2 = (const float*)d_in[3];
    const float* enc_b2 = (const float*)d_in[4];
    const float* enc_w3 = (const float*)d_in[5];
    const float* enc_b3 = (const float*)d_in[6];
    const float* dec_w1 = (const float*)d_in[7];
    const float* dec_b1 = (const float*)d_in[8];
    const float* dec_w2 = (const float*)d_in[9];
    const float* dec_b2 = (const float*)d_in[10];
    const float* dec_w3 = (const float*)d_in[11];
    const float* dec_b3 = (const float*)d_in[12];
    const float* codebooks = (const float*)d_in[13];
    const float* projs     = (const float*)d_in[14];
    float* out = (float*)d_out;

    char* ws = (char*)d_ws;
    const size_t MB = 1024 * 1024;

    // --- region [0, 16M): encoder h1 f32 (swz) ; decoder g2_hi/g2_lo (swz)
    float* h1 = (float*)ws;                                        // 8192x512 f32
    unsigned short* g2_hi = (unsigned short*)ws;                   // 8192x512 bf16
    unsigned short* g2_lo = (unsigned short*)(ws + 8 * MB);
    // --- region [16M, 24M): encoder h2 f32 (swz) ; quant splits ; dec g1 (swz)
    float* h2 = (float*)(ws + 16 * MB);                            // 8192x256 f32
    unsigned short* res_hi = (unsigned short*)(ws + 16 * MB);      // 8192x128
    unsigned short* res_lo = (unsigned short*)(ws + 18 * MB);
    unsigned short* cbp_hi = (unsigned short*)(ws + 20 * MB);
    unsigned short* cbp_lo = (unsigned short*)(ws + 22 * MB);
    unsigned short* g1_hi  = (unsigned short*)(ws + 16 * MB);      // 8192x256 (decoder)
    unsigned short* g1_lo  = (unsigned short*)(ws + 20 * MB);
    // --- region [24M, 28M): res f32 (linear)
    float* res = (float*)(ws + 24 * MB);                           // 8192x128 f32
    // --- region [28M, 32M): cbp f32 (linear) ; decoder z_hi/z_lo (swz)
    float* cbp = (float*)(ws + 28 * MB);                           // 8192x128 f32
    unsigned short* z_hi = (unsigned short*)(ws + 28 * MB);        // 8192x128
    unsigned short* z_lo = (unsigned short*)(ws + 30 * MB);
    // --- region [32M, 36M): z f32 (linear)
    float* z = (float*)(ws + 32 * MB);                             // 8192x128 f32
    // --- region [36M, ...): weight splits (all swz) + small buffers
    char* p = ws + 36 * MB;
    unsigned short* dw1_hi = (unsigned short*)p; p += 256 * 128 * 2;
    unsigned short* dw1_lo = (unsigned short*)p; p += 256 * 128 * 2;
    unsigned short* dw2_hi = (unsigned short*)p; p += 512 * 256 * 2;
    unsigned short* dw2_lo = (unsigned short*)p; p += 512 * 256 * 2;
    unsigned short* dw3_hi = (unsigned short*)p; p += 768 * 512 * 2;
    unsigned short* dw3_lo = (unsigned short*)p; p += 768 * 512 * 2;
    unsigned short* ew1_h  = (unsigned short*)p; p += 512 * 768 * 2;
    unsigned short* ew1_m  = (unsigned short*)p; p += 512 * 768 * 2;
    unsigned short* ew1_l  = (unsigned short*)p; p += 512 * 768 * 2;
    unsigned short* ew2_h  = (unsigned short*)p; p += 256 * 512 * 2;
    unsigned short* ew2_m  = (unsigned short*)p; p += 256 * 512 * 2;
    unsigned short* ew2_l  = (unsigned short*)p; p += 256 * 512 * 2;
    unsigned short* ew3_h  = (unsigned short*)p; p += 128 * 256 * 2;
    unsigned short* ew3_m  = (unsigned short*)p; p += 128 * 256 * 2;
    unsigned short* ew3_l  = (unsigned short*)p; p += 128 * 256 * 2;
    float* cbn       = (float*)p; p += 8192 * 4;
    float* qloss     = (float*)p; p += 8192 * 4;
    float* recon_row = (float*)p; p += 8192 * 4;
    unsigned long long* minkey = (unsigned long long*)p; p += 8192 * 8;
    unsigned long long* keys   = (unsigned long long*)p; p += 8192 * 8;
    unsigned long long* table  = (unsigned long long*)p; p += 16384 * 8;
    int* ids   = (int*)p; p += 8192 * 3 * 4;
    int* count = (int*)p; p += 256;                      // pad to alignment
    unsigned short* xhat = (unsigned short*)p; p += (size_t)8192 * 768 * 2;
    // optional x swizzle buffer (24 MB) — only if workspace is big enough
    float* xs = (float*)p;
    const bool use_xs =
        ((size_t)(p - ws) + (size_t)8192 * 768 * 4) <= ws_size;

    hipMemsetAsync(count, 0, sizeof(int), stream);
    hipMemsetAsync(table, 0xFF, 16384 * sizeof(unsigned long long), stream);

    // all 6 weight splits fused into one dispatch
    prep_weights_kernel<<<4352, 256, 0, stream>>>(
        dec_w1, dec_w2, dec_w3, enc_w1, enc_w2, enc_w3,
        dw1_hi, dw1_lo, dw2_hi, dw2_lo, dw3_hi, dw3_lo,
        ew1_h, ew1_m, ew1_l, ew2_h, ew2_m, ew2_l, ew3_h, ew3_m, ew3_l);

    // encoder (exact-split MFMA, fp32-faithful); h1/h2 swizzled fp32;
    // enc3 epilogue also emits res_hi/res_lo (swz split2) directly
    if (use_xs) {
        swzf32_kernel<768><<<3072, 256, 0, stream>>>(x, xs);
        mfma_enc_kernel<512, 768, 1, 1, 1, 0><<<dim3(8, 64), 256, 0, stream>>>(
            xs, ew1_h, ew1_m, ew1_l, enc_b1, h1, nullptr, nullptr);
    } else {
        mfma_enc_kernel<512, 768, 1, 0, 1, 0><<<dim3(8, 64), 256, 0, stream>>>(
            x, ew1_h, ew1_m, ew1_l, enc_b1, h1, nullptr, nullptr);
    }
    mfma_enc_kernel<256, 512, 1, 1, 1, 0><<<dim3(4, 64), 256, 0, stream>>>(
        h1, ew2_h, ew2_m, ew2_l, enc_b2, h2, nullptr, nullptr);
    mfma_enc_kernel<128, 256, 0, 1, 0, 1><<<dim3(2, 64), 256, 0, stream>>>(
        h2, ew3_h, ew3_m, ew3_l, enc_b3, res, res_hi, res_lo);

    // residual quantization layers
    for (int l = 0; l < 3; ++l) {
        proj_split_kernel<<<1024, 128, 0, stream>>>(codebooks + (size_t)l * 8192 * 128,
                                                    projs + (size_t)l * 128 * 128,
                                                    cbp, cbp_hi, cbp_lo, cbn);
        hipMemsetAsync(minkey, 0xFF, 8192 * sizeof(unsigned long long), stream);
        argmin_mfma_kernel<<<dim3(32, 64), 256, 0, stream>>>(res_hi, res_lo,
                                                             cbp_hi, cbp_lo, cbn, minkey);
        finalize_kernel<<<8192, 128, 0, stream>>>(res, cbp, minkey, qloss, z,
                                                  ids, out + 3, keys,
                                                  res_hi, res_lo, z_hi, z_lo, l);
    }

    // decoder (split-precision MFMA, swizzled planes; z planes from finalize)
    mfma_gemm_kernel<256, 128, 1, 0><<<dim3(2, 64), 256, 0, stream>>>(
        z_hi, z_lo, dw1_hi, dw1_lo, dec_b1, g1_hi, g1_lo);
    mfma_gemm_kernel<512, 256, 1, 0><<<dim3(4, 64), 256, 0, stream>>>(
        g1_hi, g1_lo, dw2_hi, dw2_lo, dec_b2, g2_hi, g2_lo);
    mfma_gemm_kernel<768, 512, 2, 1><<<dim3(6, 64), 256, 0, stream>>>(
        g2_hi, g2_lo, dw3_hi, dw3_lo, dec_b3, xhat, nullptr);
    norm_recon_kernel<<<8192, 256, 0, stream>>>(xhat, x, recon_row);

    // diagnostics
    uniq_hash_kernel<<<32, 256, 0, stream>>>(keys, table, count);
    scalars_kernel<<<1, 256, 0, stream>>>(qloss, recon_row, count, out);
}

// Round 10
// 449.054 us; speedup vs baseline: 5.6476x; 1.0290x over previous
//
#include <hip/hip_runtime.h>
#include <hip/hip_bf16.h>
#include <math.h>

// Problem constants
#define B_  8192
#define IN_ 768
#define D_  128
#define K_  8192
#define L_  3

typedef __attribute__((ext_vector_type(8))) short bf16x8;
typedef __attribute__((ext_vector_type(4))) float f32x4;

// ---------------------------------------------------------------------------
// Fragment-major swizzled layout for a [R][C] matrix (R%16==0, C%32==0):
//   off(row,k) = ((row>>4)*(C/32) + (k>>5))*512 + ((k>>3)&3)*128 + (row&15)*8 + (k&7)
// MFMA fragment load (row-tile rt, k-slice s) for lane l is then
//   plane + ((rt*(C/32)+s)<<9) + l*8   -> fully coalesced 16B/lane (bf16).
// Fragments are contiguous 1 KB chunks -> ideal for global_load_lds staging.
// ---------------------------------------------------------------------------
__device__ __forceinline__ size_t swz(int row, int col, int C)
{
    return ((size_t)((row >> 4) * (C >> 5) + (col >> 5)) << 9)
         + (((col >> 3) & 3) << 7) + ((row & 15) << 3) + (col & 7);
}

// Split f into hi (bf16 RNE) + lo (bf16 RNE of remainder). ~2^-18 rel error.
__device__ __forceinline__ void split2(float f, unsigned short& h, unsigned short& l)
{
    unsigned u = __float_as_uint(f);
    unsigned hb = (u + 0x7FFFu + ((u >> 16) & 1u)) & 0xFFFF0000u;
    h = (unsigned short)(hb >> 16);
    float r = f - __uint_as_float(hb);
    unsigned v = __float_as_uint(r);
    l = (unsigned short)((v + 0x7FFFu + ((v >> 16) & 1u)) >> 16);
}

// Triple split: f = h + m + l, covers all 24 fp32 mantissa bits (~2^-27).
__device__ __forceinline__ void split3(float f, unsigned short& h,
                                       unsigned short& m, unsigned short& l)
{
    unsigned u = __float_as_uint(f);
    unsigned hb = (u + 0x7FFFu + ((u >> 16) & 1u)) & 0xFFFF0000u;
    h = (unsigned short)(hb >> 16);
    float r1 = f - __uint_as_float(hb);
    unsigned v = __float_as_uint(r1);
    unsigned mb = (v + 0x7FFFu + ((v >> 16) & 1u)) & 0xFFFF0000u;
    m = (unsigned short)(mb >> 16);
    float r2 = r1 - __uint_as_float(mb);
    unsigned w = __float_as_uint(r2);
    l = (unsigned short)((w + 0x7FFFu + ((w >> 16) & 1u)) >> 16);
}

__device__ __forceinline__ unsigned short bf16_rne(float f)
{
    unsigned u = __float_as_uint(f);
    return (unsigned short)((u + 0x7FFFu + ((u >> 16) & 1u)) >> 16);
}

// ---------------------------------------------------------------------------
// fp32 [R][C] linear -> swizzled permutation (pure layout; values identical).
// ---------------------------------------------------------------------------
template<int C>
__global__ __launch_bounds__(256)
void swzf32_kernel(const float* __restrict__ src, float* __restrict__ dst)
{
    const int i = blockIdx.x * 256 + threadIdx.x;
    const int row = i / (C / 8);
    const int col = (i - row * (C / 8)) * 8;
    float4 a = *(const float4*)&src[(size_t)row * C + col];
    float4 b = *(const float4*)&src[(size_t)row * C + col + 4];
    const size_t o = swz(row, col, C);
    *(float4*)&dst[o] = a;
    *(float4*)&dst[o + 4] = b;
}

// ---------------------------------------------------------------------------
// Fused weight prep: all 6 weight matrices -> swizzled bf16 planes in ONE
// dispatch. dec weights: split2 (2 planes); enc weights: split3 (3 planes).
// ---------------------------------------------------------------------------
__global__ __launch_bounds__(256)
void prep_weights_kernel(const float* __restrict__ dw1, const float* __restrict__ dw2,
                         const float* __restrict__ dw3, const float* __restrict__ ew1,
                         const float* __restrict__ ew2, const float* __restrict__ ew3,
                         unsigned short* __restrict__ dw1h, unsigned short* __restrict__ dw1l,
                         unsigned short* __restrict__ dw2h, unsigned short* __restrict__ dw2l,
                         unsigned short* __restrict__ dw3h, unsigned short* __restrict__ dw3l,
                         unsigned short* __restrict__ e1h, unsigned short* __restrict__ e1m,
                         unsigned short* __restrict__ e1l,
                         unsigned short* __restrict__ e2h, unsigned short* __restrict__ e2m,
                         unsigned short* __restrict__ e2l,
                         unsigned short* __restrict__ e3h, unsigned short* __restrict__ e3m,
                         unsigned short* __restrict__ e3l)
{
    const int b = blockIdx.x;
    const float* src;
    unsigned short *H, *M = nullptr, *L;
    int kc, idx0;
    bool three;
    if (b < 128)       { src = dw1; H = dw1h; L = dw1l; kc = 128; three = false; idx0 = b * 256; }
    else if (b < 640)  { src = dw2; H = dw2h; L = dw2l; kc = 256; three = false; idx0 = (b - 128) * 256; }
    else if (b < 2176) { src = dw3; H = dw3h; L = dw3l; kc = 512; three = false; idx0 = (b - 640) * 256; }
    else if (b < 3712) { src = ew1; H = e1h; M = e1m; L = e1l; kc = 768; three = true; idx0 = (b - 2176) * 256; }
    else if (b < 4224) { src = ew2; H = e2h; M = e2m; L = e2l; kc = 512; three = true; idx0 = (b - 3712) * 256; }
    else               { src = ew3; H = e3h; M = e3m; L = e3l; kc = 256; three = true; idx0 = (b - 4224) * 256; }

    const int idx = idx0 + threadIdx.x;
    const int row = idx / kc, col = idx - row * kc;
    const size_t o = swz(row, col, kc);
    const float f = src[idx];
    if (three) {
        unsigned short h, m, l;
        split3(f, h, m, l);
        H[o] = h; M[o] = m; L[o] = l;
    } else {
        unsigned short h, l;
        split2(f, h, l);
        H[o] = h; L[o] = l;
    }
}

// ---------------------------------------------------------------------------
// Encoder MFMA GEMM, fp32-faithful: C = act(A @ W^T + bias).
// A fp32 (linear if ASWZ=0, swizzled if 1), triple-split in-register; W in 3
// swizzled bf16 planes. 6 MFMA passes -> ~1e-6 rel error (argmin-id safe).
// BM=128 (4 waves x 2 m-tiles), BN=64 (4 n-tiles), K-step 32.
// ACT: 0=none, 1=silu. CSWZ: fp32 out linear(0)/swizzled(1).
// OUT2: additionally write split2 bf16 planes (swz) of the output (enc3).
// ---------------------------------------------------------------------------
template<int N, int K, int ACT, int ASWZ, int CSWZ, int OUT2>
__global__ __launch_bounds__(256)
void mfma_enc_kernel(const float* __restrict__ A,
                     const unsigned short* __restrict__ Wh,
                     const unsigned short* __restrict__ Wm,
                     const unsigned short* __restrict__ Wl,
                     const float* __restrict__ bias, float* __restrict__ C,
                     unsigned short* __restrict__ Rh,
                     unsigned short* __restrict__ Rl)
{
    const int tid  = threadIdx.x;
    const int lane = tid & 63;
    const int w    = tid >> 6;
    const int ln   = lane & 15;
    const int grp  = lane >> 4;
    const int m0   = blockIdx.y * 128 + w * 32;
    const int n0   = blockIdx.x * 64;

    f32x4 acc[2][4] = {};

    for (int ks = 0; ks < K; ks += 32) {
        const int s = ks >> 5;
        bf16x8 ah[2], am[2], al[2];
        #pragma unroll
        for (int mt = 0; mt < 2; ++mt) {
            float4 f0, f1;
            if (ASWZ) {
                const size_t base =
                    ((size_t)(((m0 >> 4) + mt) * (K >> 5) + s) << 9) + lane * 8;
                f0 = *(const float4*)&A[base];
                f1 = *(const float4*)&A[base + 4];
            } else {
                const size_t off = (size_t)(m0 + mt * 16 + ln) * K + ks + grp * 8;
                f0 = *(const float4*)&A[off];
                f1 = *(const float4*)&A[off + 4];
            }
            float fv[8] = {f0.x, f0.y, f0.z, f0.w, f1.x, f1.y, f1.z, f1.w};
            #pragma unroll
            for (int e = 0; e < 8; ++e) {
                unsigned short hh, mm, ll;
                split3(fv[e], hh, mm, ll);
                ah[mt][e] = (short)hh;
                am[mt][e] = (short)mm;
                al[mt][e] = (short)ll;
            }
        }
        #pragma unroll
        for (int nt = 0; nt < 4; ++nt) {
            const size_t off =
                ((size_t)(((n0 >> 4) + nt) * (K >> 5) + s) << 9) + lane * 8;
            bf16x8 bh = *(const bf16x8*)&Wh[off];
            bf16x8 bm = *(const bf16x8*)&Wm[off];
            bf16x8 bl = *(const bf16x8*)&Wl[off];
            #pragma unroll
            for (int mt = 0; mt < 2; ++mt) {
                acc[mt][nt] = __builtin_amdgcn_mfma_f32_16x16x32_bf16(ah[mt], bh, acc[mt][nt], 0, 0, 0);
                acc[mt][nt] = __builtin_amdgcn_mfma_f32_16x16x32_bf16(am[mt], bh, acc[mt][nt], 0, 0, 0);
                acc[mt][nt] = __builtin_amdgcn_mfma_f32_16x16x32_bf16(ah[mt], bm, acc[mt][nt], 0, 0, 0);
                acc[mt][nt] = __builtin_amdgcn_mfma_f32_16x16x32_bf16(al[mt], bh, acc[mt][nt], 0, 0, 0);
                acc[mt][nt] = __builtin_amdgcn_mfma_f32_16x16x32_bf16(am[mt], bm, acc[mt][nt], 0, 0, 0);
                acc[mt][nt] = __builtin_amdgcn_mfma_f32_16x16x32_bf16(ah[mt], bl, acc[mt][nt], 0, 0, 0);
            }
        }
    }

    #pragma unroll
    for (int nt = 0; nt < 4; ++nt) {
        const int col = n0 + nt * 16 + ln;
        const float bv = bias[col];
        #pragma unroll
        for (int mt = 0; mt < 2; ++mt) {
            #pragma unroll
            for (int r = 0; r < 4; ++r) {
                const int row = m0 + mt * 16 + grp * 4 + r;
                float v = acc[mt][nt][r] + bv;
                if (ACT == 1) v = v / (1.0f + expf(-v));
                if (CSWZ) C[swz(row, col, N)] = v;
                else      C[(size_t)row * N + col] = v;
                if (OUT2) {
                    unsigned short h, l;
                    split2(v, h, l);
                    const size_t o = swz(row, col, N);
                    Rh[o] = h;
                    Rl[o] = l;
                }
            }
        }
    }
}

// ---------------------------------------------------------------------------
// Split-precision MFMA GEMM (decoder): A,W as swizzled bf16 hi/lo planes;
// dot = hh + lh + hl (~2^-17 rel, only affects recon/loss, ~2% tolerance).
// BM=128, BN=128, K-step 32. ACT: 1=silu, 2=sigmoid.
// OUT: 0=swizzled bf16 hi/lo pair, 1=linear single bf16.
// ---------------------------------------------------------------------------
template<int N, int K, int ACT, int OUT>
__global__ __launch_bounds__(256)
void mfma_gemm_kernel(const unsigned short* __restrict__ A_hi,
                      const unsigned short* __restrict__ A_lo,
                      const unsigned short* __restrict__ W_hi,
                      const unsigned short* __restrict__ W_lo,
                      const float* __restrict__ bias,
                      unsigned short* __restrict__ C_hi,
                      unsigned short* __restrict__ C_lo)
{
    const int tid  = threadIdx.x;
    const int lane = tid & 63;
    const int w    = tid >> 6;
    const int ln   = lane & 15;
    const int grp  = lane >> 4;
    const int m0   = blockIdx.y * 128 + w * 32;
    const int n0   = blockIdx.x * 128;

    f32x4 acc[2][8] = {};

    for (int ks = 0; ks < K; ks += 32) {
        const int s = ks >> 5;
        bf16x8 ah[2], al[2];
        #pragma unroll
        for (int mt = 0; mt < 2; ++mt) {
            const size_t off =
                ((size_t)(((m0 >> 4) + mt) * (K >> 5) + s) << 9) + lane * 8;
            ah[mt] = *(const bf16x8*)&A_hi[off];
            al[mt] = *(const bf16x8*)&A_lo[off];
        }
        #pragma unroll
        for (int nt = 0; nt < 8; ++nt) {
            const size_t off =
                ((size_t)(((n0 >> 4) + nt) * (K >> 5) + s) << 9) + lane * 8;
            bf16x8 bh = *(const bf16x8*)&W_hi[off];
            bf16x8 bl = *(const bf16x8*)&W_lo[off];
            #pragma unroll
            for (int mt = 0; mt < 2; ++mt) {
                acc[mt][nt] = __builtin_amdgcn_mfma_f32_16x16x32_bf16(ah[mt], bh, acc[mt][nt], 0, 0, 0);
                acc[mt][nt] = __builtin_amdgcn_mfma_f32_16x16x32_bf16(al[mt], bh, acc[mt][nt], 0, 0, 0);
                acc[mt][nt] = __builtin_amdgcn_mfma_f32_16x16x32_bf16(ah[mt], bl, acc[mt][nt], 0, 0, 0);
            }
        }
    }

    #pragma unroll
    for (int nt = 0; nt < 8; ++nt) {
        const int col = n0 + nt * 16 + ln;
        const float bv = bias[col];
        #pragma unroll
        for (int mt = 0; mt < 2; ++mt) {
            #pragma unroll
            for (int r = 0; r < 4; ++r) {
                const int row = m0 + mt * 16 + grp * 4 + r;
                float v = acc[mt][nt][r] + bv;
                if (ACT == 1) v = v / (1.0f + expf(-v));
                if (ACT == 2) v = 1.0f / (1.0f + expf(-v));
                if (OUT == 0) {
                    unsigned short h, l;
                    split2(v, h, l);
                    const size_t o = swz(row, col, N);
                    C_hi[o] = h;
                    C_lo[o] = l;
                } else {
                    C_hi[(size_t)row * N + col] = bf16_rne(v);
                }
            }
        }
    }
}

// ---------------------------------------------------------------------------
// Per-row L2 normalize + recon partial.
// ---------------------------------------------------------------------------
__global__ __launch_bounds__(256)
void norm_recon_kernel(const unsigned short* __restrict__ xhat,
                       const float* __restrict__ x,
                       float* __restrict__ recon_row)
{
    const int b = blockIdx.x;
    const int tid = threadIdx.x;
    __shared__ float ws[4];
    __shared__ float nrm_s;

    float v[3];
    float ss = 0.0f;
    #pragma unroll
    for (int c = 0; c < 3; ++c) {
        unsigned short u = xhat[(size_t)b * 768 + tid + c * 256];
        v[c] = __uint_as_float((unsigned)u << 16);
        ss += v[c] * v[c];
    }
    for (int off = 32; off > 0; off >>= 1) ss += __shfl_down(ss, off, 64);
    if ((tid & 63) == 0) ws[tid >> 6] = ss;
    __syncthreads();
    if (tid == 0) nrm_s = fmaxf(sqrtf(ws[0] + ws[1] + ws[2] + ws[3]), 1e-12f);
    __syncthreads();
    const float inv = 1.0f / nrm_s;
    float ra = 0.0f;
    #pragma unroll
    for (int c = 0; c < 3; ++c) {
        float dx = v[c] * inv - x[(size_t)b * 768 + tid + c * 256];
        ra += dx * dx;
    }
    for (int off = 32; off > 0; off >>= 1) ra += __shfl_down(ra, off, 64);
    if ((tid & 63) == 0) ws[tid >> 6] = ra;
    __syncthreads();
    if (tid == 0) recon_row[b] = ws[0] + ws[1] + ws[2] + ws[3];
}

// ---------------------------------------------------------------------------
// Projected codebook: cbp fp32 linear + swizzled bf16 hi/lo planes + norms.
// ---------------------------------------------------------------------------
__global__ __launch_bounds__(128)
void proj_split_kernel(const float* __restrict__ cbl, const float* __restrict__ projl,
                       float* __restrict__ cbp, unsigned short* __restrict__ cbp_hi,
                       unsigned short* __restrict__ cbp_lo, float* __restrict__ cbn)
{
    __shared__ float cbs[8][128];
    __shared__ float wsum[8][2];
    const int tid = threadIdx.x;          // = d
    const int k0 = blockIdx.x * 8;

    #pragma unroll
    for (int i = 0; i < 2; ++i) {
        int idx4 = tid + i * 128;
        int r = idx4 >> 5, c4 = (idx4 & 31) * 4;
        *(float4*)&cbs[r][c4] = *(const float4*)&cbl[(size_t)(k0 + r) * 128 + c4];
    }
    __syncthreads();

    float acc[8] = {};
    for (int j4 = 0; j4 < 32; ++j4) {
        float4 pv = *(const float4*)&projl[(size_t)tid * 128 + j4 * 4];
        #pragma unroll
        for (int r = 0; r < 8; ++r) {
            float4 cv = *(float4*)&cbs[r][j4 * 4];
            acc[r] += pv.x * cv.x + pv.y * cv.y + pv.z * cv.z + pv.w * cv.w;
        }
    }
    #pragma unroll
    for (int r = 0; r < 8; ++r) {
        cbp[(size_t)(k0 + r) * 128 + tid] = acc[r];
        unsigned short h, l;
        split2(acc[r], h, l);
        const size_t o = swz(k0 + r, tid, 128);
        cbp_hi[o] = h;
        cbp_lo[o] = l;
        float v = acc[r] * acc[r];
        #pragma unroll
        for (int off = 32; off > 0; off >>= 1) v += __shfl_down(v, off, 64);
        if ((tid & 63) == 0) wsum[r][tid >> 6] = v;
    }
    __syncthreads();
    if (tid < 8) cbn[k0 + tid] = wsum[tid][0] + wsum[tid][1];
}

// ---------------------------------------------------------------------------
// MFMA distance argmin (swizzled planes; ids bit-identical to numpy).
// Round 10: BM=256 (4 m-tiles/wave = 64 rows) -> each staged B-fragment feeds
// 2x the rows, halving both LDS reads (1.05M -> 524K ds_read_b128) and global
// B staging traffic. 32-col tiles x 8 its, double-buffered 2x16KB LDS.
// Arithmetic order per (row,col) unchanged -> scores/ids bit-identical.
// ---------------------------------------------------------------------------
__device__ __forceinline__ unsigned int fkey(float s) {
    unsigned int u = __float_as_uint(s);
    return (u & 0x80000000u) ? ~u : (u | 0x80000000u);
}

__global__ __launch_bounds__(256, 2)
void argmin_mfma_kernel(const unsigned short* __restrict__ res_hi,
                        const unsigned short* __restrict__ res_lo,
                        const unsigned short* __restrict__ cbp_hi,
                        const unsigned short* __restrict__ cbp_lo,
                        const float* __restrict__ cbn,
                        unsigned long long* __restrict__ minkey)
{
    __shared__ unsigned short lds[16384];   // 2 buffers x 16 KB
    const int tid  = threadIdx.x;
    const int lane = tid & 63;
    const int w    = tid >> 6;
    const int ln   = lane & 15;
    const int grp  = lane >> 4;
    const int m0   = blockIdx.y * 256 + w * 64;
    const int c0b  = blockIdx.x * 256;

    // A fragments: 64 rows/wave (4 m-tiles), held in registers (~128 VGPR)
    bf16x8 a_hi[4][4], a_lo[4][4];
    #pragma unroll
    for (int mt = 0; mt < 4; ++mt) {
        #pragma unroll
        for (int s = 0; s < 4; ++s) {
            const size_t off =
                ((size_t)(((m0 >> 4) + mt) * 4 + s) << 9) + lane * 8;
            a_hi[mt][s] = *(const bf16x8*)&res_hi[off];
            a_lo[mt][s] = *(const bf16x8*)&res_lo[off];
        }
    }

    // Per it: B tile = 32 cols x 128 k x 2 planes = 16 KB = 16 frags of 1KB.
    // Wave w stages 4 frags: plane = w>>1 (0=hi,1=lo), g = (w&1)*4 + i.
    const unsigned short* splane = (w < 2) ? cbp_hi : cbp_lo;
    const unsigned lbase = (unsigned)((w >> 1) * 8192 + (w & 1) * 4096); // bytes

    auto STAGE = [&](int buf, int it) {
        const size_t g0 = ((size_t)(c0b >> 4) * 4 + it * 8 + (w & 1) * 4) * 512
                        + lane * 8;                           // shorts
        const unsigned l0 = (unsigned)buf * 16384u + lbase;   // bytes
        #pragma unroll
        for (int i = 0; i < 4; ++i) {
            __builtin_amdgcn_global_load_lds(
                (const __attribute__((address_space(1))) unsigned int*)(splane + g0 + i * 512),
                (__attribute__((address_space(3))) unsigned int*)((char*)lds + l0 + i * 1024),
                16, 0, 0);
        }
    };

    float best_s[4][4];
    int   best_c[4][4];
    #pragma unroll
    for (int mt = 0; mt < 4; ++mt)
        #pragma unroll
        for (int r = 0; r < 4; ++r) { best_s[mt][r] = 3.4e38f; best_c[mt][r] = 0; }

    STAGE(0, 0);
    __syncthreads();                        // drains vmcnt -> buf0 ready

    for (int it = 0; it < 8; ++it) {
        const int buf = it & 1;
        if (it < 7) STAGE(buf ^ 1, it + 1); // async prefetch into other buffer
        const unsigned short* lb = lds + buf * 8192;   // shorts
        const int c0 = c0b + it * 32;
        f32x4 acc[4][2] = {};
        #pragma unroll
        for (int s = 0; s < 4; ++s) {
            #pragma unroll
            for (int t = 0; t < 2; ++t) {
                const int fo = (t * 4 + s) * 512 + lane * 8;
                bf16x8 bh = *(const bf16x8*)&lb[fo];
                bf16x8 bl = *(const bf16x8*)&lb[fo + 4096];
                #pragma unroll
                for (int mt = 0; mt < 4; ++mt) {
                    acc[mt][t] = __builtin_amdgcn_mfma_f32_16x16x32_bf16(a_hi[mt][s], bh, acc[mt][t], 0, 0, 0);
                    acc[mt][t] = __builtin_amdgcn_mfma_f32_16x16x32_bf16(a_lo[mt][s], bh, acc[mt][t], 0, 0, 0);
                    acc[mt][t] = __builtin_amdgcn_mfma_f32_16x16x32_bf16(a_hi[mt][s], bl, acc[mt][t], 0, 0, 0);
                }
            }
        }
        #pragma unroll
        for (int t = 0; t < 2; ++t) {
            const int col = c0 + t * 16 + ln;
            const float cn = cbn[col];
            #pragma unroll
            for (int mt = 0; mt < 4; ++mt)
                #pragma unroll
                for (int r = 0; r < 4; ++r) {
                    float sc = fmaf(-2.0f, acc[mt][t][r], cn);
                    if (sc < best_s[mt][r]) {   // strict <: first col wins ties
                        best_s[mt][r] = sc;
                        best_c[mt][r] = col;
                    }
                }
        }
        if (it < 7) __syncthreads();        // next buf ready, cur buf free
    }

    #pragma unroll
    for (int mt = 0; mt < 4; ++mt)
        #pragma unroll
        for (int r = 0; r < 4; ++r) {
            unsigned long long b =
                ((unsigned long long)fkey(best_s[mt][r]) << 32)
                | (unsigned int)best_c[mt][r];
            #pragma unroll
            for (int off = 1; off < 16; off <<= 1) {
                unsigned lo32 = (unsigned)b, hi32 = (unsigned)(b >> 32);
                lo32 = __shfl_xor(lo32, off);
                hi32 = __shfl_xor(hi32, off);
                unsigned long long o = ((unsigned long long)hi32 << 32) | lo32;
                if (o < b) b = o;
            }
            if (ln == 0) atomicMin(&minkey[m0 + mt * 16 + grp * 4 + r], b);
        }
}

// ---------------------------------------------------------------------------
// Per-layer epilogue. layer==0 WRITES qloss/z (no memset needed); layer 2
// also emits z planes for the decoder.
// ---------------------------------------------------------------------------
__global__ __launch_bounds__(128)
void finalize_kernel(float* __restrict__ res, const float* __restrict__ cbp,
                     const unsigned long long* __restrict__ minkey,
                     float* __restrict__ qloss, float* __restrict__ z,
                     int* __restrict__ ids, float* __restrict__ embs_norm_out,
                     unsigned long long* __restrict__ keys,
                     unsigned short* __restrict__ res_hi,
                     unsigned short* __restrict__ res_lo,
                     unsigned short* __restrict__ z_hi,
                     unsigned short* __restrict__ z_lo, int layer)
{
    const int b = blockIdx.x;
    const int tid = threadIdx.x;
    const int id = (int)(minkey[b] & 0xFFFFFFFFull);
    float e = cbp[(size_t)id * 128 + tid];
    float r = res[(size_t)b * 128 + tid];
    float d = r - e;
    float v1 = d * d, v2 = e * e;
    for (int off = 32; off > 0; off >>= 1) {
        v1 += __shfl_down(v1, off, 64);
        v2 += __shfl_down(v2, off, 64);
    }
    __shared__ float ws[4];
    if ((tid & 63) == 0) { ws[(tid >> 6) * 2] = v1; ws[(tid >> 6) * 2 + 1] = v2; }
    __syncthreads();
    if (tid == 0) {
        float d2 = ws[0] + ws[2];
        float n2 = ws[1] + ws[3];
        float prev = (layer == 0) ? 0.0f : qloss[b];
        qloss[b] = prev + 1.25f * d2;           // emb_loss + 0.25*query_loss
        embs_norm_out[b * 3 + layer] = sqrtf(n2);
        ids[b * 3 + layer] = id;
        if (layer == 2) {
            keys[b] = (unsigned long long)ids[b * 3 + 0]
                    | ((unsigned long long)ids[b * 3 + 1] << 13)
                    | ((unsigned long long)id << 26);
        }
    }
    float zprev = (layer == 0) ? 0.0f : z[(size_t)b * 128 + tid];
    float nz = zprev + e;
    z[(size_t)b * 128 + tid] = nz;
    const size_t o = swz(b, tid, 128);
    if (layer == 2) {
        unsigned short zh, zl;
        split2(nz, zh, zl);
        z_hi[o] = zh;
        z_lo[o] = zl;
    }
    float nr = r - e;
    res[(size_t)b * 128 + tid] = nr;
    unsigned short h, l;
    split2(nr, h, l);
    res_hi[o] = h;
    res_lo[o] = l;
}

// ---------------------------------------------------------------------------
// Distinct-triple count: wave match-any dedup (leaders only touch the global
// table) then per-wave aggregated count. Deterministic.
// ---------------------------------------------------------------------------
__global__ __launch_bounds__(256)
void uniq_hash_kernel(const unsigned long long* __restrict__ keys,
                      unsigned long long* __restrict__ table,
                      int* __restrict__ count)
{
    const int i = blockIdx.x * 256 + threadIdx.x;
    const int lane = threadIdx.x & 63;
    const unsigned long long k = keys[i];

    // wave match-any: elect one leader lane per distinct key
    bool resolved = false, leader = false;
    while (true) {
        unsigned long long unres = __ballot(!resolved);
        if (unres == 0) break;
        const int src = (int)(__ffsll((long long)unres) - 1);
        unsigned slo = __shfl((unsigned)k, src);
        unsigned shi = __shfl((unsigned)(k >> 32), src);
        unsigned long long kk = ((unsigned long long)shi << 32) | slo;
        if (!resolved && k == kk) {
            resolved = true;
            leader = (lane == src);
        }
    }

    bool ins = false;
    if (leader) {
        unsigned h = (unsigned)((k * 0x9E3779B97F4A7C15ull) >> 50);   // 14 bits
        while (true) {
            unsigned long long old = atomicCAS(&table[h], ~0ULL, k);
            if (old == ~0ULL) { ins = true; break; }        // first insert
            if (old == k) break;                            // duplicate
            h = (h + 1) & 16383;
        }
    }
    unsigned long long m = __ballot(ins);
    if (lane == 0 && m) atomicAdd(count, (int)__popcll(m));
}

// ---------------------------------------------------------------------------
// Final scalars.
// ---------------------------------------------------------------------------
__global__ __launch_bounds__(256)
void scalars_kernel(const float* __restrict__ qloss,
                    const float* __restrict__ recon_row,
                    const int* __restrict__ count, float* __restrict__ out)
{
    const int tid = threadIdx.x;
    float qs = 0.0f, rs = 0.0f;
    for (int i = tid; i < 8192; i += 256) qs += qloss[i];
    for (int i = tid; i < 8192; i += 256) rs += recon_row[i];
    for (int off = 32; off > 0; off >>= 1) {
        qs += __shfl_down(qs, off, 64);
        rs += __shfl_down(rs, off, 64);
    }
    __shared__ float w[8];
    if ((tid & 63) == 0) { w[(tid >> 6) * 2] = qs; w[(tid >> 6) * 2 + 1] = rs; }
    __syncthreads();
    if (tid == 0) {
        float qsum = w[0] + w[2] + w[4] + w[6];
        float rsum = w[1] + w[3] + w[5] + w[7];
        float qmean = qsum / 8192.0f;
        out[0] = rsum + qmean;        // loss = (recon + qloss).mean()
        out[1] = rsum;                // recon
        out[2] = qmean;               // qloss.mean()
        out[24579] = (float)(*count) / 8192.0f;   // p_unique
    }
}

// ---------------------------------------------------------------------------
extern "C" void kernel_launch(void* const* d_in, const int* in_sizes, int n_in,
                              void* d_out, int out_size, void* d_ws, size_t ws_size,
                              hipStream_t stream)
{
    const float* x      = (const float*)d_in[0];
    const float* enc_w1 = (const float*)d_in[1];
    const float* enc_b1 = (const float*)d_in[2];
    const float* enc_w2 = (const float*)d_in[3];
    const float* enc_b2 = (const float*)d_in[4];
    const float* enc_w3 = (const float*)d_in[5];
    const float* enc_b3 = (const float*)d_in[6];
    const float* dec_w1 = (const float*)d_in[7];
    const float* dec_b1 = (const float*)d_in[8];
    const float* dec_w2 = (const float*)d_in[9];
    const float* dec_b2 = (const float*)d_in[10];
    const float* dec_w3 = (const float*)d_in[11];
    const float* dec_b3 = (const float*)d_in[12];
    const float* codebooks = (const float*)d_in[13];
    const float* projs     = (const float*)d_in[14];
    float* out = (float*)d_out;

    char* ws = (char*)d_ws;
    const size_t MB = 1024 * 1024;

    // --- region [0, 16M): encoder h1 f32 (swz) ; decoder g2_hi/g2_lo (swz)
    float* h1 = (float*)ws;                                        // 8192x512 f32
    unsigned short* g2_hi = (unsigned short*)ws;                   // 8192x512 bf16
    unsigned short* g2_lo = (unsigned short*)(ws + 8 * MB);
    // --- region [16M, 24M): encoder h2 f32 (swz) ; quant splits ; dec g1 (swz)
    float* h2 = (float*)(ws + 16 * MB);                            // 8192x256 f32
    unsigned short* res_hi = (unsigned short*)(ws + 16 * MB);      // 8192x128
    unsigned short* res_lo = (unsigned short*)(ws + 18 * MB);
    unsigned short* cbp_hi = (unsigned short*)(ws + 20 * MB);
    unsigned short* cbp_lo = (unsigned short*)(ws + 22 * MB);
    unsigned short* g1_hi  = (unsigned short*)(ws + 16 * MB);      // 8192x256 (decoder)
    unsigned short* g1_lo  = (unsigned short*)(ws + 20 * MB);
    // --- region [24M, 28M): res f32 (linear)
    float* res = (float*)(ws + 24 * MB);                           // 8192x128 f32
    // --- region [28M, 32M): cbp f32 (linear) ; decoder z_hi/z_lo (swz)
    float* cbp = (float*)(ws + 28 * MB);                           // 8192x128 f32
    unsigned short* z_hi = (unsigned short*)(ws + 28 * MB);        // 8192x128
    unsigned short* z_lo = (unsigned short*)(ws + 30 * MB);
    // --- region [32M, 36M): z f32 (linear)
    float* z = (float*)(ws + 32 * MB);                             // 8192x128 f32
    // --- region [36M, ...): weight splits (all swz) + small buffers
    char* p = ws + 36 * MB;
    unsigned short* dw1_hi = (unsigned short*)p; p += 256 * 128 * 2;
    unsigned short* dw1_lo = (unsigned short*)p; p += 256 * 128 * 2;
    unsigned short* dw2_hi = (unsigned short*)p; p += 512 * 256 * 2;
    unsigned short* dw2_lo = (unsigned short*)p; p += 512 * 256 * 2;
    unsigned short* dw3_hi = (unsigned short*)p; p += 768 * 512 * 2;
    unsigned short* dw3_lo = (unsigned short*)p; p += 768 * 512 * 2;
    unsigned short* ew1_h  = (unsigned short*)p; p += 512 * 768 * 2;
    unsigned short* ew1_m  = (unsigned short*)p; p += 512 * 768 * 2;
    unsigned short* ew1_l  = (unsigned short*)p; p += 512 * 768 * 2;
    unsigned short* ew2_h  = (unsigned short*)p; p += 256 * 512 * 2;
    unsigned short* ew2_m  = (unsigned short*)p; p += 256 * 512 * 2;
    unsigned short* ew2_l  = (unsigned short*)p; p += 256 * 512 * 2;
    unsigned short* ew3_h  = (unsigned short*)p; p += 128 * 256 * 2;
    unsigned short* ew3_m  = (unsigned short*)p; p += 128 * 256 * 2;
    unsigned short* ew3_l  = (unsigned short*)p; p += 128 * 256 * 2;
    float* cbn       = (float*)p; p += 8192 * 4;
    float* qloss     = (float*)p; p += 8192 * 4;
    float* recon_row = (float*)p; p += 8192 * 4;
    unsigned long long* minkey = (unsigned long long*)p; p += 8192 * 8;
    unsigned long long* keys   = (unsigned long long*)p; p += 8192 * 8;
    unsigned long long* table  = (unsigned long long*)p; p += 16384 * 8;
    int* ids   = (int*)p; p += 8192 * 3 * 4;
    int* count = (int*)p; p += 256;                      // pad to alignment
    unsigned short* xhat = (unsigned short*)p; p += (size_t)8192 * 768 * 2;
    // optional x swizzle buffer (24 MB) — only if workspace is big enough
    float* xs = (float*)p;
    const bool use_xs =
        ((size_t)(p - ws) + (size_t)8192 * 768 * 4) <= ws_size;

    hipMemsetAsync(count, 0, sizeof(int), stream);
    hipMemsetAsync(table, 0xFF, 16384 * sizeof(unsigned long long), stream);

    // all 6 weight splits fused into one dispatch
    prep_weights_kernel<<<4352, 256, 0, stream>>>(
        dec_w1, dec_w2, dec_w3, enc_w1, enc_w2, enc_w3,
        dw1_hi, dw1_lo, dw2_hi, dw2_lo, dw3_hi, dw3_lo,
        ew1_h, ew1_m, ew1_l, ew2_h, ew2_m, ew2_l, ew3_h, ew3_m, ew3_l);

    // encoder (exact-split MFMA, fp32-faithful); h1/h2 swizzled fp32;
    // enc3 epilogue also emits res_hi/res_lo (swz split2) directly
    if (use_xs) {
        swzf32_kernel<768><<<3072, 256, 0, stream>>>(x, xs);
        mfma_enc_kernel<512, 768, 1, 1, 1, 0><<<dim3(8, 64), 256, 0, stream>>>(
            xs, ew1_h, ew1_m, ew1_l, enc_b1, h1, nullptr, nullptr);
    } else {
        mfma_enc_kernel<512, 768, 1, 0, 1, 0><<<dim3(8, 64), 256, 0, stream>>>(
            x, ew1_h, ew1_m, ew1_l, enc_b1, h1, nullptr, nullptr);
    }
    mfma_enc_kernel<256, 512, 1, 1, 1, 0><<<dim3(4, 64), 256, 0, stream>>>(
        h1, ew2_h, ew2_m, ew2_l, enc_b2, h2, nullptr, nullptr);
    mfma_enc_kernel<128, 256, 0, 1, 0, 1><<<dim3(2, 64), 256, 0, stream>>>(
        h2, ew3_h, ew3_m, ew3_l, enc_b3, res, res_hi, res_lo);

    // residual quantization layers
    for (int l = 0; l < 3; ++l) {
        proj_split_kernel<<<1024, 128, 0, stream>>>(codebooks + (size_t)l * 8192 * 128,
                                                    projs + (size_t)l * 128 * 128,
                                                    cbp, cbp_hi, cbp_lo, cbn);
        hipMemsetAsync(minkey, 0xFF, 8192 * sizeof(unsigned long long), stream);
        argmin_mfma_kernel<<<dim3(32, 32), 256, 0, stream>>>(res_hi, res_lo,
                                                             cbp_hi, cbp_lo, cbn, minkey);
        finalize_kernel<<<8192, 128, 0, stream>>>(res, cbp, minkey, qloss, z,
                                                  ids, out + 3, keys,
                                                  res_hi, res_lo, z_hi, z_lo, l);
    }

    // decoder (split-precision MFMA, swizzled planes; z planes from finalize)
    mfma_gemm_kernel<256, 128, 1, 0><<<dim3(2, 64), 256, 0, stream>>>(
        z_hi, z_lo, dw1_hi, dw1_lo, dec_b1, g1_hi, g1_lo);
    mfma_gemm_kernel<512, 256, 1, 0><<<dim3(4, 64), 256, 0, stream>>>(
        g1_hi, g1_lo, dw2_hi, dw2_lo, dec_b2, g2_hi, g2_lo);
    mfma_gemm_kernel<768, 512, 2, 1><<<dim3(6, 64), 256, 0, stream>>>(
        g2_hi, g2_lo, dw3_hi, dw3_lo, dec_b3, xhat, nullptr);
    norm_recon_kernel<<<8192, 256, 0, stream>>>(xhat, x, recon_row);

    // diagnostics
    uniq_hash_kernel<<<32, 256, 0, stream>>>(keys, table, count);
    scalars_kernel<<<1, 256, 0, stream>>>(qloss, recon_row, count, out);
}